// Round 1
// baseline (750.454 us; speedup 1.0000x reference)
//
#include <hip/hip_runtime.h>

typedef unsigned short u16;
typedef __attribute__((ext_vector_type(8))) short short8;
typedef __attribute__((ext_vector_type(4))) short shortv4;
typedef __attribute__((ext_vector_type(4))) float floatx4;

__device__ inline float bf2f(u16 v){ union { unsigned int i; float f; } u; u.i = ((unsigned int)v) << 16; return u.f; }
__device__ inline u16 f2bf(float f){ union { float ff; unsigned int i; } u; u.ff = f; unsigned int r = u.i + 0x7fffu + ((u.i >> 16) & 1u); return (u16)(r >> 16); }
__device__ inline float sigmf(float x){ return 1.f/(1.f + __expf(-x)); }
__device__ inline float tanhfast(float x){ float e = __expf(-2.f*fabsf(x)); float t = (1.f-e)/(1.f+e); return x>=0.f? t : -t; }
__device__ inline float wred(float x){ for (int o = 32; o; o >>= 1) x += __shfl_xor(x, o); return x; }

// dual-dtype scalar load: fl==1 -> buffer is float32, else bf16(u16)
__device__ inline float ldf(const void* p, long i, int fl){
  return fl ? ((const float*)p)[i] : bf2f(((const u16*)p)[i]);
}
// 8-element load -> bf16 frag. mode: 0=bf16 buffer, 1=follow fl, 2=f32 buffer
__device__ inline short8 ld8m(const void* p, long i, int mode, int fl){
  int isf = (mode == 2) || (mode == 1 && fl);
  if (!isf) return *(const short8*)((const u16*)p + i);
  const float* f = (const float*)p + i;
  float4 x = *(const float4*)f;
  float4 y = *(const float4*)(f + 4);
  short8 r;
  r[0]=(short)f2bf(x.x); r[1]=(short)f2bf(x.y); r[2]=(short)f2bf(x.z); r[3]=(short)f2bf(x.w);
  r[4]=(short)f2bf(y.x); r[5]=(short)f2bf(y.y); r[6]=(short)f2bf(y.z); r[7]=(short)f2bf(y.w);
  return r;
}

#define MFMA(a,b,c) __builtin_amdgcn_mfma_f32_16x16x32_bf16(a,b,c,0,0,0)

// ---------------------------------------------------------------------------
__global__ void detect_kernel(const u16* __restrict__ w, int* __restrict__ flag){
  __shared__ int cnt[256];
  int t = threadIdx.x, c = 0;
  for (int i = t; i < 4096; i += 256){ u16 v = w[i]; if ((v & 0x7fff) >= 0x4200) c++; }
  cnt[t] = c; __syncthreads();
  for (int s = 128; s; s >>= 1){ if (t < s) cnt[t] += cnt[t + s]; __syncthreads(); }
  if (t == 0) *flag = (cnt[0] > 16) ? 1 : 0;
}

// ---------------------------------------------------------------------------
// coalesced tiled transpose with K-pad + row offset: out[n][k] = (k<K)? in[ro+k][n] : 0
__global__ __launch_bounds__(256) void transpose_tiled_kernel(
    const void* __restrict__ in, int ldin, int ro, int K, int N, int Kpad,
    u16* __restrict__ out, const int* __restrict__ flg)
{
  const int fl = *flg;
  __shared__ float tile[32][33];
  int k0 = blockIdx.y*32, n0 = blockIdx.x*32;
  int tx = threadIdx.x & 31, ty = threadIdx.x >> 5;   // 32 x 8
  for (int i = ty; i < 32; i += 8){
    int k = k0 + i, n = n0 + tx;
    tile[i][tx] = (k < K && n < N) ? ldf(in, (long)(ro + k)*ldin + n, fl) : 0.f;
  }
  __syncthreads();
  for (int i = ty; i < 32; i += 8){
    int n = n0 + i, k = k0 + tx;
    if (n < N && k < Kpad) out[(long)n*Kpad + k] = f2bf(tile[tx][i]);
  }
}

// ---------------------------------------------------------------------------
// U [192,128] bf16: rows 0..63 = Wak, 64 = bak, 65..129 = Wek, 130 = bek, rest 0
__global__ void build_u_kernel(const void* __restrict__ Wak, const void* __restrict__ bak,
                               const void* __restrict__ Wek, const void* __restrict__ bek,
                               u16* __restrict__ U, const int* __restrict__ flg)
{
  const int fl = *flg;
  int idx = blockIdx.x*256 + threadIdx.x;
  if (idx >= 192*128) return;
  int c = idx >> 7, a = idx & 127;
  float v = 0.f;
  if (c < 64)       v = ldf(Wak, (long)c*128 + a, fl);
  else if (c == 64) v = ldf(bak, a, fl);
  else if (c < 130) v = ldf(Wek, (long)(c-65)*128 + a, fl);
  else if (c == 130) v = ldf(bek, a, fl);
  U[idx] = f2bf(v);
}

// bG[c] = bq . U[c,:]
__global__ void bg_kernel(const u16* __restrict__ U, const void* __restrict__ bq,
                          float* __restrict__ bG, const int* __restrict__ flg)
{
  const int fl = *flg;
  int c = threadIdx.x;
  if (c >= 192) return;
  float acc = 0.f;
  for (int a = 0; a < 128; a++) acc = fmaf(ldf(bq, a, fl), bf2f(U[c*128 + a]), acc);
  bG[c] = acc;
}

// bc[j] = ba1[j] + sum_c be2[c] * Wa1[c, j]  (top half of Wa1, direct ext read)
__global__ void bc_kernel(const void* __restrict__ Wa1, const void* __restrict__ be2,
                          const void* __restrict__ ba1, float* __restrict__ bc,
                          const int* __restrict__ flg)
{
  const int fl = *flg;
  int j = blockIdx.x*256 + threadIdx.x;
  if (j >= 512) return;
  float acc = ldf(ba1, j, fl);
  for (int c = 0; c < 512; c++) acc = fmaf(ldf(be2, c, fl), ldf(Wa1, (long)c*512 + j, fl), acc);
  bc[j] = acc;
}

// ---------------------------------------------------------------------------
// Generic MFMA GEMM: out[r, ocol+col] = A[M,K(lda)] @ B[N,K]^T + bias, bf16 out
__global__ __launch_bounds__(256) void gemm_nk_kernel(
    const void* __restrict__ A, int lda, const void* __restrict__ Bm,
    const float* __restrict__ bias, u16* __restrict__ outp, int ldout, int ocol,
    int K, const int* __restrict__ flg, int amode, int bmode)
{
  const int fl = *flg;
  __shared__ __align__(16) short Al[64*32];
  __shared__ __align__(16) short Bl[64*32];
  const int t = threadIdx.x, lane = t & 63, w = t >> 6;
  const int m0 = blockIdx.x*64, n0 = blockIdx.y*64;
  floatx4 acc[4] = {};
  const int row = t >> 2, seg = t & 3;
  for (int kt = 0; kt < K; kt += 32){
    __syncthreads();
    *(short8*)(Al + row*32 + seg*8) = ld8m(A,  (long)(m0 + row)*lda + kt + seg*8, amode, fl);
    *(short8*)(Bl + row*32 + seg*8) = ld8m(Bm, (long)(n0 + row)*K   + kt + seg*8, bmode, fl);
    __syncthreads();
    short8 a = *(const short8*)(Al + (w*16 + (lane & 15))*32 + ((lane >> 4)*8));
    #pragma unroll
    for (int nt = 0; nt < 4; nt++){
      short8 b = *(const short8*)(Bl + (nt*16 + (lane & 15))*32 + ((lane >> 4)*8));
      acc[nt] = MFMA(a, b, acc[nt]);
    }
  }
  #pragma unroll
  for (int nt = 0; nt < 4; nt++){
    int col = n0 + nt*16 + (lane & 15);
    float bb = bias ? bias[col] : 0.f;
    #pragma unroll
    for (int i = 0; i < 4; i++){
      int r = m0 + w*16 + (lane >> 4)*4 + i;
      outp[(long)r*ldout + ocol + col] = f2bf(acc[nt][i] + bb);
    }
  }
}

// ---------------------------------------------------------------------------
// Attention: one wave per batch row. G[b,0:64]=qka, 64=sa, 65:130=qke, 130=se.
__global__ __launch_bounds__(256) void attn_kernel(
    const u16* __restrict__ G, const void* __restrict__ af, const void* __restrict__ ef,
    u16* __restrict__ mixbuf, const int* __restrict__ flg)
{
  const int fl = *flg;
  __shared__ float gsh[4][192];
  __shared__ float attw[4][32];
  const int lane = threadIdx.x & 63, wv = threadIdx.x >> 6;
  const long b = blockIdx.x*4 + wv;
  const float rsA = 0.08838834764831845f;  // 1/sqrt(128)

  for (int c = lane; c < 192; c += 64) gsh[wv][c] = bf2f(G[b*192 + c]);
  __syncthreads();

  // ---- allies ----
  float qa = gsh[wv][lane];
  float sa = gsh[wv][64];
  float myE = -1e30f;
  for (int n = 0; n < 31; n++){
    float e = wred(ldf(af, ((long)n*4096 + b)*64 + lane, fl) * qa);
    e = (e + sa) * rsA;
    if (lane == n) myE = e;
  }
  {
    float m = myE;
    for (int o = 32; o; o >>= 1) m = fmaxf(m, __shfl_xor(m, o));
    float p = (lane < 31) ? __expf(myE - m) : 0.f;
    float s = wred(p);
    if (lane < 32) attw[wv][lane] = p / s;
  }
  __syncthreads();
  {
    float acc = 0.f;
    for (int n = 0; n < 31; n++)
      acc = fmaf(attw[wv][n], ldf(af, ((long)n*4096 + b)*64 + lane, fl), acc);
    mixbuf[b*160 + lane] = f2bf(acc);
  }
  __syncthreads();

  // ---- enemies (65 dims) ----
  float qe = gsh[wv][65 + lane];
  float qe64 = gsh[wv][129];
  float se = gsh[wv][130];
  myE = -1e30f;
  for (int n = 0; n < 32; n++){
    long base = ((long)n*4096 + b)*65;
    float prod = ldf(ef, base + lane, fl) * qe;
    if (lane == 0) prod = fmaf(ldf(ef, base + 64, fl), qe64, prod);
    float e = (wred(prod) + se) * rsA;
    if (lane == n) myE = e;
  }
  {
    float m = myE;
    for (int o = 32; o; o >>= 1) m = fmaxf(m, __shfl_xor(m, o));
    float p = (lane < 32) ? __expf(myE - m) : 0.f;
    float s = wred(p);
    if (lane < 32) attw[wv][lane] = p / s;
  }
  __syncthreads();
  {
    float acc = 0.f, acc64 = 0.f;
    for (int n = 0; n < 32; n++){
      long base = ((long)n*4096 + b)*65;
      float w = attw[wv][n];
      acc = fmaf(w, ldf(ef, base + lane, fl), acc);
      if (lane == 0) acc64 = fmaf(w, ldf(ef, base + 64, fl), acc64);
    }
    mixbuf[b*160 + 64 + lane] = f2bf(acc);
    if (lane == 0) mixbuf[b*160 + 128] = f2bf(acc64);
    if (lane >= 1 && lane < 32) mixbuf[b*160 + 128 + lane] = 0;
  }
}

// ---------------------------------------------------------------------------
// GRU: block = 128 batch rows x 64 hidden cols (512 thr); h (f32) -> d_out.
__global__ __launch_bounds__(512) void gru_kernel(
    const u16* __restrict__ tot, const void* __restrict__ hprev,
    const void* __restrict__ w_ih, const void* __restrict__ w_hh,
    const void* __restrict__ b_ih, const void* __restrict__ b_hh,
    float* __restrict__ h_out, const int* __restrict__ flg)
{
  const int fl = *flg;
  __shared__ __align__(16) short At[128*32], Ah[128*32];
  __shared__ __align__(16) short Bi[3][64*32], Bh[3][64*32];
  const int t = threadIdx.x, lane = t & 63, w = t >> 6;
  const int b0 = blockIdx.x*128, j0 = blockIdx.y*64;
  floatx4 ai[3][4] = {}; floatx4 ah[3][4] = {};
  const int row = t >> 2, seg = t & 3;
  for (int kt = 0; kt < 768; kt += 32){
    __syncthreads();
    *(short8*)(At + row*32 + seg*8) = *(const short8*)(tot + (long)(b0 + row)*768 + kt + seg*8);
    if (kt < 512)
      *(short8*)(Ah + row*32 + seg*8) = ld8m(hprev, (long)(b0 + row)*512 + kt + seg*8, 1, fl);
    if (t < 256){
      int rb = t >> 2, sb = t & 3;
      #pragma unroll
      for (int p = 0; p < 3; p++)
        *(short8*)(Bi[p] + rb*32 + sb*8) = ld8m(w_ih, (long)(p*512 + j0 + rb)*768 + kt + sb*8, 1, fl);
    } else if (kt < 512){
      int t2 = t - 256, rb = t2 >> 2, sb = t2 & 3;
      #pragma unroll
      for (int p = 0; p < 3; p++)
        *(short8*)(Bh[p] + rb*32 + sb*8) = ld8m(w_hh, (long)(p*512 + j0 + rb)*512 + kt + sb*8, 1, fl);
    }
    __syncthreads();
    short8 a = *(const short8*)(At + (w*16 + (lane & 15))*32 + ((lane >> 4)*8));
    #pragma unroll
    for (int p = 0; p < 3; p++){
      #pragma unroll
      for (int nt = 0; nt < 4; nt++){
        short8 b = *(const short8*)(Bi[p] + (nt*16 + (lane & 15))*32 + ((lane >> 4)*8));
        ai[p][nt] = MFMA(a, b, ai[p][nt]);
      }
    }
    if (kt < 512){
      short8 a2 = *(const short8*)(Ah + (w*16 + (lane & 15))*32 + ((lane >> 4)*8));
      #pragma unroll
      for (int p = 0; p < 3; p++){
        #pragma unroll
        for (int nt = 0; nt < 4; nt++){
          short8 b = *(const short8*)(Bh[p] + (nt*16 + (lane & 15))*32 + ((lane >> 4)*8));
          ah[p][nt] = MFMA(a2, b, ah[p][nt]);
        }
      }
    }
  }
  #pragma unroll
  for (int nt = 0; nt < 4; nt++){
    int colH = j0 + nt*16 + (lane & 15);
    float bir = ldf(b_ih, colH, fl),        bhr = ldf(b_hh, colH, fl);
    float biz = ldf(b_ih, 512 + colH, fl),  bhz = ldf(b_hh, 512 + colH, fl);
    float bin = ldf(b_ih, 1024 + colH, fl), bhn = ldf(b_hh, 1024 + colH, fl);
    #pragma unroll
    for (int i = 0; i < 4; i++){
      int r = b0 + w*16 + (lane >> 4)*4 + i;
      float rg = sigmf(ai[0][nt][i] + bir + ah[0][nt][i] + bhr);
      float zg = sigmf(ai[1][nt][i] + biz + ah[1][nt][i] + bhz);
      float ng = tanhfast(ai[2][nt][i] + bin + rg*(ah[2][nt][i] + bhn));
      float hp = ldf(hprev, (long)r*512 + colH, fl);
      h_out[(long)r*512 + colH] = (1.f - zg)*ng + zg*hp;
    }
  }
}

// ---------------------------------------------------------------------------
// wo_q = h @ Wwo + bwo -> out[:, 0:6]   (h f32 in d_out)
__global__ __launch_bounds__(256) void wo_kernel(
    const float* __restrict__ h, const void* __restrict__ Wwo,
    const void* __restrict__ bwo, float* __restrict__ out, const int* __restrict__ flg)
{
  const int fl = *flg;
  __shared__ float red[64][4][6];
  const int t = threadIdx.x, r = t >> 2, kq = t & 3;
  const int b = blockIdx.x*64 + r;
  float acc[6] = {};
  for (int k = kq*128; k < kq*128 + 128; k++){
    float hv = h[(long)b*512 + k];
    #pragma unroll
    for (int j = 0; j < 6; j++) acc[j] = fmaf(hv, ldf(Wwo, (long)k*6 + j, fl), acc[j]);
  }
  #pragma unroll
  for (int j = 0; j < 6; j++) red[r][kq][j] = acc[j];
  __syncthreads();
  if (kq == 0){
    #pragma unroll
    for (int j = 0; j < 6; j++)
      out[(long)b*38 + j] = red[r][0][j] + red[r][1][j] + red[r][2][j] + red[r][3][j] + ldf(bwo, j, fl);
  }
}

// ---------------------------------------------------------------------------
// Head: block = (64 b-rows, ONE enemy n=blockIdx.y). LDS = 64KB r1 + 12.5KB
// pool (efl/part time-shared) = 78.3KB -> 2 blocks/CU (vs 1 before).
// Phase 1 uses swapped-operand MFMA so each lane owns 4 consecutive r1
// COLUMNS of one row -> single packed ds_write_b64 into the XOR-swizzled
// buffer (was 4 conflicted b16 writes). efl padded 96->100 shorts to kill
// the 16-lane staging-read bank alias. aq -> out[:, 6+n]  (f32)
__global__ __launch_bounds__(512, 4) void head_kernel(
    const void* __restrict__ ef_g, const u16* __restrict__ We1T,
    const void* __restrict__ be1, const u16* __restrict__ WcT,
    const u16* __restrict__ u_b, const void* __restrict__ wa2,
    const void* __restrict__ ba2, float* __restrict__ out, const int* __restrict__ flg)
{
  const int fl = *flg;
  __shared__ __align__(16) short r1s[64*512];   // XOR-swizzled: (row, chunk^(row&7))
  __shared__ __align__(16) char pool[64*100*2]; // efl [64][100] (phase1) / part [64][9] f32 (epilogue)
  short* efl = (short*)pool;
  float (*part)[9] = (float(*)[9])pool;
  const int t = threadIdx.x, lane = t & 63, w = t >> 6;
  const int m = lane & 15, q = lane >> 4;
  const int n = blockIdx.y, b0 = blockIdx.x*64;

  // ---- phase 1: stage enemy features (stride 100 shorts: conflict-free reads)
  for (int idx = t; idx < 64*100; idx += 512){
    int r = idx / 100, d = idx - r*100;
    u16 v = 0;
    if (d < 65) v = f2bf(ldf(ef_g, ((long)n*4096 + b0 + r)*65 + d, fl));
    efl[idx] = (short)v;
  }
  __syncthreads();

  // r1 = relu(ef @ We1^T + be1). Swapped operands: D[we1col][efrow], so lane
  // (m,q) accumulates cols cb+q*4..+3 of row rt*16+m -> packed b64 write.
  #pragma unroll
  for (int jt4 = 0; jt4 < 4; jt4++){
    const int cb = (w*4 + jt4)*16;
    short8 bfr[3];
    #pragma unroll
    for (int k3 = 0; k3 < 3; k3++)
      bfr[k3] = *(const short8*)(We1T + (cb + m)*96 + k3*32 + q*8);
    float be[4];
    #pragma unroll
    for (int i = 0; i < 4; i++) be[i] = ldf(be1, cb + q*4 + i, fl);
    #pragma unroll
    for (int rt = 0; rt < 4; rt++){
      floatx4 acc = {0.f, 0.f, 0.f, 0.f};
      #pragma unroll
      for (int k3 = 0; k3 < 3; k3++){
        short8 a = *(const short8*)(efl + (rt*16 + m)*100 + k3*32 + q*8);
        acc = MFMA(bfr[k3], a, acc);
      }
      const int row = rt*16 + m;
      const int cbl = cb + q*4;
      shortv4 pk;
      #pragma unroll
      for (int i = 0; i < 4; i++){
        float v = acc[i] + be[i];
        pk[i] = (short)f2bf(v > 0.f ? v : 0.f);
      }
      *(shortv4*)(r1s + row*512 + ((((cbl >> 3) ^ (row & 7)) << 3) | (cbl & 7))) = pk;
    }
  }
  __syncthreads();

  // ---- phase 2: wave w -> output cols [w*64, w*64+64); B-frag reused 4x (rt)
  floatx4 acc[4][4] = {};
  for (int kt = 0; kt < 512; kt += 32){
    short8 b[4];
    #pragma unroll
    for (int js = 0; js < 4; js++)
      b[js] = *(const short8*)(WcT + (long)(w*64 + js*16 + m)*512 + kt + q*8);
    const int ch = (((kt >> 3) + q) ^ (m & 7)) << 3;
    #pragma unroll
    for (int rt = 0; rt < 4; rt++){
      short8 a = *(const short8*)(r1s + (rt*16 + m)*512 + ch);
      #pragma unroll
      for (int js = 0; js < 4; js++)
        acc[rt][js] = MFMA(a, b[js], acc[rt][js]);
    }
  }

  // ---- epilogue: relu(r2 + u_b) . wa2
  float pr[4][4] = {};
  #pragma unroll
  for (int js = 0; js < 4; js++){
    int col = w*64 + js*16 + m;
    float wv = ldf(wa2, col, fl);
    #pragma unroll
    for (int rt = 0; rt < 4; rt++){
      #pragma unroll
      for (int i = 0; i < 4; i++){
        int grow = b0 + rt*16 + q*4 + i;
        float u = bf2f(u_b[(long)grow*512 + col]);
        float s = acc[rt][js][i] + u;
        pr[rt][i] += (s > 0.f ? s : 0.f) * wv;
      }
    }
  }
  #pragma unroll
  for (int o = 1; o < 16; o <<= 1)
    #pragma unroll
    for (int rt = 0; rt < 4; rt++)
      #pragma unroll
      for (int i = 0; i < 4; i++)
        pr[rt][i] += __shfl_xor(pr[rt][i], o);
  if (m == 0){
    #pragma unroll
    for (int rt = 0; rt < 4; rt++)
      #pragma unroll
      for (int i = 0; i < 4; i++)
        part[rt*16 + q*4 + i][w] = pr[rt][i];
  }
  __syncthreads();
  if (t < 64){
    float s = ldf(ba2, 0, fl);
    #pragma unroll
    for (int ww = 0; ww < 8; ww++) s += part[t][ww];
    out[(long)(b0 + t)*38 + 6 + n] = s;
  }
}

// ---------------------------------------------------------------------------
extern "C" void kernel_launch(void* const* d_in, const int* in_sizes, int n_in,
                              void* d_out, int out_size, void* d_ws, size_t ws_size,
                              hipStream_t stream)
{
  (void)in_sizes; (void)n_in; (void)out_size; (void)ws_size;
  const void* own  = d_in[0];
  const void* af   = d_in[1];
  const void* ef   = d_in[2];
  const void* hid  = d_in[3];
  const void* Wq   = d_in[4];
  const void* bq   = d_in[5];
  const void* Wak  = d_in[6];
  const void* bak  = d_in[7];
  const void* Wav  = d_in[8];
  const void* Wek  = d_in[10];
  const void* bek  = d_in[11];
  const void* Wev  = d_in[12];
  const void* Wov  = d_in[14];
  const void* w_ih = d_in[16];
  const void* w_hh = d_in[17];
  const void* b_ih = d_in[18];
  const void* b_hh = d_in[19];
  const void* Wwo  = d_in[20];
  const void* bwo  = d_in[21];
  const void* We1  = d_in[22];
  const void* be1  = d_in[23];
  const void* We2  = d_in[24];
  const void* be2  = d_in[25];
  const void* Wa1  = d_in[26];
  const void* ba1  = d_in[27];
  const void* Wa2  = d_in[28];
  const void* ba2  = d_in[29];
  float* out   = (float*)d_out;                 // q [4096,38] f32
  float* h_out = out + (long)4096*38;           // h [4096,512] f32

  // ---- workspace (7.76 MB peak, time-phased aliasing) ----
  char* ws = (char*)d_ws;
  u16*   tot    = (u16*)(ws + 0);               // [4096,768] bf16 = 6,291,456
  u16*   G      = (u16*)(ws + 0);               // [4096,192] bf16 (alias, dead before tot)
  u16*   u_b    = (u16*)(ws + 0);               // [4096,512] bf16 (alias, after gru)
  char*  mz     = ws + 6291456;                 // 1,310,720 multi-phase zone
  u16*   mixbuf = (u16*)mz;                     // [4096,160] bf16 (attention phase)
  u16*   U      = (u16*)mz;                     // [192,128] bf16 (prep phase)
  u16*   WGT    = (u16*)(mz + 49152);           // [192,128] bf16 (prep phase)
  u16*   Wa1bT  = (u16*)mz;                     // [512,512] bf16 (post-tot phase)
  u16*   Wa1tT  = (u16*)mz;                     // [512,512] bf16 (post-u phase)
  u16*   WcT    = (u16*)(mz + 524288);          // [512,512] bf16 (post-u phase)
  u16*   We1T   = (u16*)(mz + 1048576);         // [512,96]  bf16 (post-u phase)
  char*  P      = ws + 7602176;                 // persistent small zone
  u16*   WovT   = (u16*)(P + 0);                // [256,128] bf16
  u16*   WavT   = (u16*)(P + 65536);            // [256,64]  bf16
  u16*   WevT   = (u16*)(P + 98304);            // [256,96]  bf16
  float* bc     = (float*)(P + 147456);         // [512] f32
  float* bG     = (float*)(P + 149504);         // [192] f32
  int*   flg    = (int*)(P + 150528);

  detect_kernel<<<1, 256, 0, stream>>>((const u16*)w_ih, flg);

  // prep: V-projection weights + combined query weights
  transpose_tiled_kernel<<<dim3(8, 4), 256, 0, stream>>>(Wov, 256, 0, 128, 256, 128, WovT, flg);
  transpose_tiled_kernel<<<dim3(8, 2), 256, 0, stream>>>(Wav, 256, 0,  64, 256,  64, WavT, flg);
  transpose_tiled_kernel<<<dim3(8, 3), 256, 0, stream>>>(Wev, 256, 0,  65, 256,  96, WevT, flg);
  build_u_kernel<<<96, 256, 0, stream>>>(Wak, bak, Wek, bek, U, flg);
  bg_kernel<<<1, 256, 0, stream>>>(U, bq, bG, flg);
  bc_kernel<<<2, 256, 0, stream>>>(Wa1, be2, ba1, bc, flg);
  // WGT[c,d] = sum_a U[c,a] * Wq[d,a]
  gemm_nk_kernel<<<dim3(3, 2), 256, 0, stream>>>(U, 128, Wq, nullptr, WGT, 128, 0, 128, flg, 0, 1);
  // G = own @ WGT^T + bG   [4096,192]
  gemm_nk_kernel<<<dim3(64, 3), 256, 0, stream>>>(own, 128, WGT, bG, G, 192, 0, 128, flg, 1, 0);
  // attention -> mixbuf (clobbers U/WGT; G still live in tot region)
  attn_kernel<<<1024, 256, 0, stream>>>(G, af, ef, mixbuf, flg);
  // tot = [own@Wov | mix_a@Wav | mix_e@Wev]  (overwrites G)
  gemm_nk_kernel<<<dim3(64, 4), 256, 0, stream>>>(own, 128, WovT, nullptr, tot, 768, 0, 128, flg, 1, 0);
  gemm_nk_kernel<<<dim3(64, 4), 256, 0, stream>>>(mixbuf, 160, WavT, nullptr, tot, 768, 256, 64, flg, 0, 0);
  gemm_nk_kernel<<<dim3(64, 4), 256, 0, stream>>>(mixbuf + 64, 160, WevT, nullptr, tot, 768, 512, 96, flg, 0, 0);
  // GRU -> h (f32 in d_out)
  gru_kernel<<<dim3(32, 8), 512, 0, stream>>>(tot, hid, w_ih, w_hh, b_ih, b_hh, h_out, flg);
  // Wa1 bottom transpose (mixbuf dead) ; u = h @ Wa1_bot + bc -> u_b (overwrites tot)
  transpose_tiled_kernel<<<dim3(16, 16), 256, 0, stream>>>(Wa1, 512, 512, 512, 512, 512, Wa1bT, flg);
  gemm_nk_kernel<<<dim3(64, 8), 256, 0, stream>>>(h_out, 512, Wa1bT, bc, u_b, 512, 0, 512, flg, 2, 0);
  // Wc = We2 @ Wa1_top  (Wa1tT clobbers Wa1bT)
  transpose_tiled_kernel<<<dim3(16, 16), 256, 0, stream>>>(Wa1, 512, 0, 512, 512, 512, Wa1tT, flg);
  gemm_nk_kernel<<<dim3(8, 8), 256, 0, stream>>>(Wa1tT, 512, We2, nullptr, WcT, 512, 0, 512, flg, 0, 1);
  transpose_tiled_kernel<<<dim3(16, 3), 256, 0, stream>>>(We1, 512, 0, 65, 512, 96, We1T, flg);
  // heads
  wo_kernel<<<64, 256, 0, stream>>>(h_out, Wwo, bwo, out, flg);
  head_kernel<<<dim3(64, 32), 512, 0, stream>>>(ef, We1T, be1, WcT, u_b, Wa2, ba2, out, flg);
}

// Round 2
// 745.393 us; speedup vs baseline: 1.0068x; 1.0068x over previous
//
#include <hip/hip_runtime.h>

typedef unsigned short u16;
typedef __attribute__((ext_vector_type(8))) short short8;
typedef __attribute__((ext_vector_type(4))) short shortv4;
typedef __attribute__((ext_vector_type(4))) float floatx4;

__device__ inline float bf2f(u16 v){ union { unsigned int i; float f; } u; u.i = ((unsigned int)v) << 16; return u.f; }
__device__ inline u16 f2bf(float f){ union { float ff; unsigned int i; } u; u.ff = f; unsigned int r = u.i + 0x7fffu + ((u.i >> 16) & 1u); return (u16)(r >> 16); }
__device__ inline float sigmf(float x){ return 1.f/(1.f + __expf(-x)); }
__device__ inline float tanhfast(float x){ float e = __expf(-2.f*fabsf(x)); float t = (1.f-e)/(1.f+e); return x>=0.f? t : -t; }
__device__ inline float wred(float x){ for (int o = 32; o; o >>= 1) x += __shfl_xor(x, o); return x; }

// dual-dtype scalar load: fl==1 -> buffer is float32, else bf16(u16)
__device__ inline float ldf(const void* p, long i, int fl){
  return fl ? ((const float*)p)[i] : bf2f(((const u16*)p)[i]);
}
// 8-element load -> bf16 frag. mode: 0=bf16 buffer, 1=follow fl, 2=f32 buffer
__device__ inline short8 ld8m(const void* p, long i, int mode, int fl){
  int isf = (mode == 2) || (mode == 1 && fl);
  if (!isf) return *(const short8*)((const u16*)p + i);
  const float* f = (const float*)p + i;
  float4 x = *(const float4*)f;
  float4 y = *(const float4*)(f + 4);
  short8 r;
  r[0]=(short)f2bf(x.x); r[1]=(short)f2bf(x.y); r[2]=(short)f2bf(x.z); r[3]=(short)f2bf(x.w);
  r[4]=(short)f2bf(y.x); r[5]=(short)f2bf(y.y); r[6]=(short)f2bf(y.z); r[7]=(short)f2bf(y.w);
  return r;
}

#define MFMA(a,b,c) __builtin_amdgcn_mfma_f32_16x16x32_bf16(a,b,c,0,0,0)

// ---------------------------------------------------------------------------
__global__ void detect_kernel(const u16* __restrict__ w, int* __restrict__ flag){
  __shared__ int cnt[256];
  int t = threadIdx.x, c = 0;
  for (int i = t; i < 4096; i += 256){ u16 v = w[i]; if ((v & 0x7fff) >= 0x4200) c++; }
  cnt[t] = c; __syncthreads();
  for (int s = 128; s; s >>= 1){ if (t < s) cnt[t] += cnt[t + s]; __syncthreads(); }
  if (t == 0) *flag = (cnt[0] > 16) ? 1 : 0;
}

// ---------------------------------------------------------------------------
// coalesced tiled transpose with K-pad + row offset: out[n][k] = (k<K)? in[ro+k][n] : 0
__global__ __launch_bounds__(256) void transpose_tiled_kernel(
    const void* __restrict__ in, int ldin, int ro, int K, int N, int Kpad,
    u16* __restrict__ out, const int* __restrict__ flg)
{
  const int fl = *flg;
  __shared__ float tile[32][33];
  int k0 = blockIdx.y*32, n0 = blockIdx.x*32;
  int tx = threadIdx.x & 31, ty = threadIdx.x >> 5;   // 32 x 8
  for (int i = ty; i < 32; i += 8){
    int k = k0 + i, n = n0 + tx;
    tile[i][tx] = (k < K && n < N) ? ldf(in, (long)(ro + k)*ldin + n, fl) : 0.f;
  }
  __syncthreads();
  for (int i = ty; i < 32; i += 8){
    int n = n0 + i, k = k0 + tx;
    if (n < N && k < Kpad) out[(long)n*Kpad + k] = f2bf(tile[tx][i]);
  }
}

// ---------------------------------------------------------------------------
// U [192,128] bf16: rows 0..63 = Wak, 64 = bak, 65..129 = Wek, 130 = bek, rest 0
__global__ void build_u_kernel(const void* __restrict__ Wak, const void* __restrict__ bak,
                               const void* __restrict__ Wek, const void* __restrict__ bek,
                               u16* __restrict__ U, const int* __restrict__ flg)
{
  const int fl = *flg;
  int idx = blockIdx.x*256 + threadIdx.x;
  if (idx >= 192*128) return;
  int c = idx >> 7, a = idx & 127;
  float v = 0.f;
  if (c < 64)       v = ldf(Wak, (long)c*128 + a, fl);
  else if (c == 64) v = ldf(bak, a, fl);
  else if (c < 130) v = ldf(Wek, (long)(c-65)*128 + a, fl);
  else if (c == 130) v = ldf(bek, a, fl);
  U[idx] = f2bf(v);
}

// bG[c] = bq . U[c,:]
__global__ void bg_kernel(const u16* __restrict__ U, const void* __restrict__ bq,
                          float* __restrict__ bG, const int* __restrict__ flg)
{
  const int fl = *flg;
  int c = threadIdx.x;
  if (c >= 192) return;
  float acc = 0.f;
  for (int a = 0; a < 128; a++) acc = fmaf(ldf(bq, a, fl), bf2f(U[c*128 + a]), acc);
  bG[c] = acc;
}

// bc[j] = ba1[j] + sum_c be2[c] * Wa1[c, j]  (top half of Wa1, direct ext read)
__global__ void bc_kernel(const void* __restrict__ Wa1, const void* __restrict__ be2,
                          const void* __restrict__ ba1, float* __restrict__ bc,
                          const int* __restrict__ flg)
{
  const int fl = *flg;
  int j = blockIdx.x*256 + threadIdx.x;
  if (j >= 512) return;
  float acc = ldf(ba1, j, fl);
  for (int c = 0; c < 512; c++) acc = fmaf(ldf(be2, c, fl), ldf(Wa1, (long)c*512 + j, fl), acc);
  bc[j] = acc;
}

// ---------------------------------------------------------------------------
// Generic MFMA GEMM: out[r, ocol+col] = A[M,K(lda)] @ B[N,K]^T + bias, bf16 out
__global__ __launch_bounds__(256) void gemm_nk_kernel(
    const void* __restrict__ A, int lda, const void* __restrict__ Bm,
    const float* __restrict__ bias, u16* __restrict__ outp, int ldout, int ocol,
    int K, const int* __restrict__ flg, int amode, int bmode)
{
  const int fl = *flg;
  __shared__ __align__(16) short Al[64*32];
  __shared__ __align__(16) short Bl[64*32];
  const int t = threadIdx.x, lane = t & 63, w = t >> 6;
  const int m0 = blockIdx.x*64, n0 = blockIdx.y*64;
  floatx4 acc[4] = {};
  const int row = t >> 2, seg = t & 3;
  for (int kt = 0; kt < K; kt += 32){
    __syncthreads();
    *(short8*)(Al + row*32 + seg*8) = ld8m(A,  (long)(m0 + row)*lda + kt + seg*8, amode, fl);
    *(short8*)(Bl + row*32 + seg*8) = ld8m(Bm, (long)(n0 + row)*K   + kt + seg*8, bmode, fl);
    __syncthreads();
    short8 a = *(const short8*)(Al + (w*16 + (lane & 15))*32 + ((lane >> 4)*8));
    #pragma unroll
    for (int nt = 0; nt < 4; nt++){
      short8 b = *(const short8*)(Bl + (nt*16 + (lane & 15))*32 + ((lane >> 4)*8));
      acc[nt] = MFMA(a, b, acc[nt]);
    }
  }
  #pragma unroll
  for (int nt = 0; nt < 4; nt++){
    int col = n0 + nt*16 + (lane & 15);
    float bb = bias ? bias[col] : 0.f;
    #pragma unroll
    for (int i = 0; i < 4; i++){
      int r = m0 + w*16 + (lane >> 4)*4 + i;
      outp[(long)r*ldout + ocol + col] = f2bf(acc[nt][i] + bb);
    }
  }
}

// ---------------------------------------------------------------------------
// Attention: one wave per batch row. G[b,0:64]=qka, 64=sa, 65:130=qke, 130=se.
__global__ __launch_bounds__(256) void attn_kernel(
    const u16* __restrict__ G, const void* __restrict__ af, const void* __restrict__ ef,
    u16* __restrict__ mixbuf, const int* __restrict__ flg)
{
  const int fl = *flg;
  __shared__ float gsh[4][192];
  __shared__ float attw[4][32];
  const int lane = threadIdx.x & 63, wv = threadIdx.x >> 6;
  const long b = blockIdx.x*4 + wv;
  const float rsA = 0.08838834764831845f;  // 1/sqrt(128)

  for (int c = lane; c < 192; c += 64) gsh[wv][c] = bf2f(G[b*192 + c]);
  __syncthreads();

  // ---- allies ----
  float qa = gsh[wv][lane];
  float sa = gsh[wv][64];
  float myE = -1e30f;
  for (int n = 0; n < 31; n++){
    float e = wred(ldf(af, ((long)n*4096 + b)*64 + lane, fl) * qa);
    e = (e + sa) * rsA;
    if (lane == n) myE = e;
  }
  {
    float m = myE;
    for (int o = 32; o; o >>= 1) m = fmaxf(m, __shfl_xor(m, o));
    float p = (lane < 31) ? __expf(myE - m) : 0.f;
    float s = wred(p);
    if (lane < 32) attw[wv][lane] = p / s;
  }
  __syncthreads();
  {
    float acc = 0.f;
    for (int n = 0; n < 31; n++)
      acc = fmaf(attw[wv][n], ldf(af, ((long)n*4096 + b)*64 + lane, fl), acc);
    mixbuf[b*160 + lane] = f2bf(acc);
  }
  __syncthreads();

  // ---- enemies (65 dims) ----
  float qe = gsh[wv][65 + lane];
  float qe64 = gsh[wv][129];
  float se = gsh[wv][130];
  myE = -1e30f;
  for (int n = 0; n < 32; n++){
    long base = ((long)n*4096 + b)*65;
    float prod = ldf(ef, base + lane, fl) * qe;
    if (lane == 0) prod = fmaf(ldf(ef, base + 64, fl), qe64, prod);
    float e = (wred(prod) + se) * rsA;
    if (lane == n) myE = e;
  }
  {
    float m = myE;
    for (int o = 32; o; o >>= 1) m = fmaxf(m, __shfl_xor(m, o));
    float p = (lane < 32) ? __expf(myE - m) : 0.f;
    float s = wred(p);
    if (lane < 32) attw[wv][lane] = p / s;
  }
  __syncthreads();
  {
    float acc = 0.f, acc64 = 0.f;
    for (int n = 0; n < 32; n++){
      long base = ((long)n*4096 + b)*65;
      float w = attw[wv][n];
      acc = fmaf(w, ldf(ef, base + lane, fl), acc);
      if (lane == 0) acc64 = fmaf(w, ldf(ef, base + 64, fl), acc64);
    }
    mixbuf[b*160 + 64 + lane] = f2bf(acc);
    if (lane == 0) mixbuf[b*160 + 128] = f2bf(acc64);
    if (lane >= 1 && lane < 32) mixbuf[b*160 + 128 + lane] = 0;
  }
}

// ---------------------------------------------------------------------------
// GRU: block = 128 batch rows x 64 hidden cols (512 thr); h (f32) -> d_out.
__global__ __launch_bounds__(512) void gru_kernel(
    const u16* __restrict__ tot, const void* __restrict__ hprev,
    const void* __restrict__ w_ih, const void* __restrict__ w_hh,
    const void* __restrict__ b_ih, const void* __restrict__ b_hh,
    float* __restrict__ h_out, const int* __restrict__ flg)
{
  const int fl = *flg;
  __shared__ __align__(16) short At[128*32], Ah[128*32];
  __shared__ __align__(16) short Bi[3][64*32], Bh[3][64*32];
  const int t = threadIdx.x, lane = t & 63, w = t >> 6;
  const int b0 = blockIdx.x*128, j0 = blockIdx.y*64;
  floatx4 ai[3][4] = {}; floatx4 ah[3][4] = {};
  const int row = t >> 2, seg = t & 3;
  for (int kt = 0; kt < 768; kt += 32){
    __syncthreads();
    *(short8*)(At + row*32 + seg*8) = *(const short8*)(tot + (long)(b0 + row)*768 + kt + seg*8);
    if (kt < 512)
      *(short8*)(Ah + row*32 + seg*8) = ld8m(hprev, (long)(b0 + row)*512 + kt + seg*8, 1, fl);
    if (t < 256){
      int rb = t >> 2, sb = t & 3;
      #pragma unroll
      for (int p = 0; p < 3; p++)
        *(short8*)(Bi[p] + rb*32 + sb*8) = ld8m(w_ih, (long)(p*512 + j0 + rb)*768 + kt + sb*8, 1, fl);
    } else if (kt < 512){
      int t2 = t - 256, rb = t2 >> 2, sb = t2 & 3;
      #pragma unroll
      for (int p = 0; p < 3; p++)
        *(short8*)(Bh[p] + rb*32 + sb*8) = ld8m(w_hh, (long)(p*512 + j0 + rb)*512 + kt + sb*8, 1, fl);
    }
    __syncthreads();
    short8 a = *(const short8*)(At + (w*16 + (lane & 15))*32 + ((lane >> 4)*8));
    #pragma unroll
    for (int p = 0; p < 3; p++){
      #pragma unroll
      for (int nt = 0; nt < 4; nt++){
        short8 b = *(const short8*)(Bi[p] + (nt*16 + (lane & 15))*32 + ((lane >> 4)*8));
        ai[p][nt] = MFMA(a, b, ai[p][nt]);
      }
    }
    if (kt < 512){
      short8 a2 = *(const short8*)(Ah + (w*16 + (lane & 15))*32 + ((lane >> 4)*8));
      #pragma unroll
      for (int p = 0; p < 3; p++){
        #pragma unroll
        for (int nt = 0; nt < 4; nt++){
          short8 b = *(const short8*)(Bh[p] + (nt*16 + (lane & 15))*32 + ((lane >> 4)*8));
          ah[p][nt] = MFMA(a2, b, ah[p][nt]);
        }
      }
    }
  }
  #pragma unroll
  for (int nt = 0; nt < 4; nt++){
    int colH = j0 + nt*16 + (lane & 15);
    float bir = ldf(b_ih, colH, fl),        bhr = ldf(b_hh, colH, fl);
    float biz = ldf(b_ih, 512 + colH, fl),  bhz = ldf(b_hh, 512 + colH, fl);
    float bin = ldf(b_ih, 1024 + colH, fl), bhn = ldf(b_hh, 1024 + colH, fl);
    #pragma unroll
    for (int i = 0; i < 4; i++){
      int r = b0 + w*16 + (lane >> 4)*4 + i;
      float rg = sigmf(ai[0][nt][i] + bir + ah[0][nt][i] + bhr);
      float zg = sigmf(ai[1][nt][i] + biz + ah[1][nt][i] + bhz);
      float ng = tanhfast(ai[2][nt][i] + bin + rg*(ah[2][nt][i] + bhn));
      float hp = ldf(hprev, (long)r*512 + colH, fl);
      h_out[(long)r*512 + colH] = (1.f - zg)*ng + zg*hp;
    }
  }
}

// ---------------------------------------------------------------------------
// wo_q = h @ Wwo + bwo -> out[:, 0:6]   (h f32 in d_out)
__global__ __launch_bounds__(256) void wo_kernel(
    const float* __restrict__ h, const void* __restrict__ Wwo,
    const void* __restrict__ bwo, float* __restrict__ out, const int* __restrict__ flg)
{
  const int fl = *flg;
  __shared__ float red[64][4][6];
  const int t = threadIdx.x, r = t >> 2, kq = t & 3;
  const int b = blockIdx.x*64 + r;
  float acc[6] = {};
  for (int k = kq*128; k < kq*128 + 128; k++){
    float hv = h[(long)b*512 + k];
    #pragma unroll
    for (int j = 0; j < 6; j++) acc[j] = fmaf(hv, ldf(Wwo, (long)k*6 + j, fl), acc[j]);
  }
  #pragma unroll
  for (int j = 0; j < 6; j++) red[r][kq][j] = acc[j];
  __syncthreads();
  if (kq == 0){
    #pragma unroll
    for (int j = 0; j < 6; j++)
      out[(long)b*38 + j] = red[r][0][j] + red[r][1][j] + red[r][2][j] + red[r][3][j] + ldf(bwo, j, fl);
  }
}

// ---------------------------------------------------------------------------
// Head: block = (64 b-rows, ONE enemy n=blockIdx.y). LDS = 64KB r1 + 12.5KB
// pool (efl/part time-shared) = 78.3KB -> 2 blocks/CU.
// NOTE: plain __launch_bounds__(512) — adding a min-waves arg of 4 capped
// VGPRs at 64 and spilled the 64-float accumulator to scratch (WRITE_SIZE
// 1.3MB -> 186MB, 1.6x slowdown). At the natural ~120 VGPR the HW still
// fits 4 waves/SIMD, so LDS (2x78KB) is the binding occupancy limit.
// Phase 1 uses swapped-operand MFMA so each lane owns 4 consecutive r1
// COLUMNS of one row -> single packed ds_write_b64 into the XOR-swizzled
// buffer. efl padded 96->100 shorts to kill the staging-read bank alias.
__global__ __launch_bounds__(512) void head_kernel(
    const void* __restrict__ ef_g, const u16* __restrict__ We1T,
    const void* __restrict__ be1, const u16* __restrict__ WcT,
    const u16* __restrict__ u_b, const void* __restrict__ wa2,
    const void* __restrict__ ba2, float* __restrict__ out, const int* __restrict__ flg)
{
  const int fl = *flg;
  __shared__ __align__(16) short r1s[64*512];   // XOR-swizzled: (row, chunk^(row&7))
  __shared__ __align__(16) char pool[64*100*2]; // efl [64][100] (phase1) / part [64][9] f32 (epilogue)
  short* efl = (short*)pool;
  float (*part)[9] = (float(*)[9])pool;
  const int t = threadIdx.x, lane = t & 63, w = t >> 6;
  const int m = lane & 15, q = lane >> 4;
  const int n = blockIdx.y, b0 = blockIdx.x*64;

  // ---- phase 1: stage enemy features (stride 100 shorts: conflict-free reads)
  for (int idx = t; idx < 64*100; idx += 512){
    int r = idx / 100, d = idx - r*100;
    u16 v = 0;
    if (d < 65) v = f2bf(ldf(ef_g, ((long)n*4096 + b0 + r)*65 + d, fl));
    efl[idx] = (short)v;
  }
  __syncthreads();

  // r1 = relu(ef @ We1^T + be1). Swapped operands: D[we1col][efrow], so lane
  // (m,q) accumulates cols cb+q*4..+3 of row rt*16+m -> packed b64 write.
  #pragma unroll
  for (int jt4 = 0; jt4 < 4; jt4++){
    const int cb = (w*4 + jt4)*16;
    short8 bfr[3];
    #pragma unroll
    for (int k3 = 0; k3 < 3; k3++)
      bfr[k3] = *(const short8*)(We1T + (cb + m)*96 + k3*32 + q*8);
    float be[4];
    #pragma unroll
    for (int i = 0; i < 4; i++) be[i] = ldf(be1, cb + q*4 + i, fl);
    #pragma unroll
    for (int rt = 0; rt < 4; rt++){
      floatx4 acc = {0.f, 0.f, 0.f, 0.f};
      #pragma unroll
      for (int k3 = 0; k3 < 3; k3++){
        short8 a = *(const short8*)(efl + (rt*16 + m)*100 + k3*32 + q*8);
        acc = MFMA(bfr[k3], a, acc);
      }
      const int row = rt*16 + m;
      const int cbl = cb + q*4;
      shortv4 pk;
      #pragma unroll
      for (int i = 0; i < 4; i++){
        float v = acc[i] + be[i];
        pk[i] = (short)f2bf(v > 0.f ? v : 0.f);
      }
      *(shortv4*)(r1s + row*512 + ((((cbl >> 3) ^ (row & 7)) << 3) | (cbl & 7))) = pk;
    }
  }
  __syncthreads();

  // ---- phase 2: wave w -> output cols [w*64, w*64+64); B-frag reused 4x (rt)
  floatx4 acc[4][4] = {};
  for (int kt = 0; kt < 512; kt += 32){
    short8 b[4];
    #pragma unroll
    for (int js = 0; js < 4; js++)
      b[js] = *(const short8*)(WcT + (long)(w*64 + js*16 + m)*512 + kt + q*8);
    const int ch = (((kt >> 3) + q) ^ (m & 7)) << 3;
    #pragma unroll
    for (int rt = 0; rt < 4; rt++){
      short8 a = *(const short8*)(r1s + (rt*16 + m)*512 + ch);
      #pragma unroll
      for (int js = 0; js < 4; js++)
        acc[rt][js] = MFMA(a, b[js], acc[rt][js]);
    }
  }

  // ---- epilogue: relu(r2 + u_b) . wa2
  float pr[4][4] = {};
  #pragma unroll
  for (int js = 0; js < 4; js++){
    int col = w*64 + js*16 + m;
    float wv = ldf(wa2, col, fl);
    #pragma unroll
    for (int rt = 0; rt < 4; rt++){
      #pragma unroll
      for (int i = 0; i < 4; i++){
        int grow = b0 + rt*16 + q*4 + i;
        float u = bf2f(u_b[(long)grow*512 + col]);
        float s = acc[rt][js][i] + u;
        pr[rt][i] += (s > 0.f ? s : 0.f) * wv;
      }
    }
  }
  #pragma unroll
  for (int o = 1; o < 16; o <<= 1)
    #pragma unroll
    for (int rt = 0; rt < 4; rt++)
      #pragma unroll
      for (int i = 0; i < 4; i++)
        pr[rt][i] += __shfl_xor(pr[rt][i], o);
  if (m == 0){
    #pragma unroll
    for (int rt = 0; rt < 4; rt++)
      #pragma unroll
      for (int i = 0; i < 4; i++)
        part[rt*16 + q*4 + i][w] = pr[rt][i];
  }
  __syncthreads();
  if (t < 64){
    float s = ldf(ba2, 0, fl);
    #pragma unroll
    for (int ww = 0; ww < 8; ww++) s += part[t][ww];
    out[(long)(b0 + t)*38 + 6 + n] = s;
  }
}

// ---------------------------------------------------------------------------
extern "C" void kernel_launch(void* const* d_in, const int* in_sizes, int n_in,
                              void* d_out, int out_size, void* d_ws, size_t ws_size,
                              hipStream_t stream)
{
  (void)in_sizes; (void)n_in; (void)out_size; (void)ws_size;
  const void* own  = d_in[0];
  const void* af   = d_in[1];
  const void* ef   = d_in[2];
  const void* hid  = d_in[3];
  const void* Wq   = d_in[4];
  const void* bq   = d_in[5];
  const void* Wak  = d_in[6];
  const void* bak  = d_in[7];
  const void* Wav  = d_in[8];
  const void* Wek  = d_in[10];
  const void* bek  = d_in[11];
  const void* Wev  = d_in[12];
  const void* Wov  = d_in[14];
  const void* w_ih = d_in[16];
  const void* w_hh = d_in[17];
  const void* b_ih = d_in[18];
  const void* b_hh = d_in[19];
  const void* Wwo  = d_in[20];
  const void* bwo  = d_in[21];
  const void* We1  = d_in[22];
  const void* be1  = d_in[23];
  const void* We2  = d_in[24];
  const void* be2  = d_in[25];
  const void* Wa1  = d_in[26];
  const void* ba1  = d_in[27];
  const void* Wa2  = d_in[28];
  const void* ba2  = d_in[29];
  float* out   = (float*)d_out;                 // q [4096,38] f32
  float* h_out = out + (long)4096*38;           // h [4096,512] f32

  // ---- workspace (7.76 MB peak, time-phased aliasing) ----
  char* ws = (char*)d_ws;
  u16*   tot    = (u16*)(ws + 0);               // [4096,768] bf16 = 6,291,456
  u16*   G      = (u16*)(ws + 0);               // [4096,192] bf16 (alias, dead before tot)
  u16*   u_b    = (u16*)(ws + 0);               // [4096,512] bf16 (alias, after gru)
  char*  mz     = ws + 6291456;                 // 1,310,720 multi-phase zone
  u16*   mixbuf = (u16*)mz;                     // [4096,160] bf16 (attention phase)
  u16*   U      = (u16*)mz;                     // [192,128] bf16 (prep phase)
  u16*   WGT    = (u16*)(mz + 49152);           // [192,128] bf16 (prep phase)
  u16*   Wa1bT  = (u16*)mz;                     // [512,512] bf16 (post-tot phase)
  u16*   Wa1tT  = (u16*)mz;                     // [512,512] bf16 (post-u phase)
  u16*   WcT    = (u16*)(mz + 524288);          // [512,512] bf16 (post-u phase)
  u16*   We1T   = (u16*)(mz + 1048576);         // [512,96]  bf16 (post-u phase)
  char*  P      = ws + 7602176;                 // persistent small zone
  u16*   WovT   = (u16*)(P + 0);                // [256,128] bf16
  u16*   WavT   = (u16*)(P + 65536);            // [256,64]  bf16
  u16*   WevT   = (u16*)(P + 98304);            // [256,96]  bf16
  float* bc     = (float*)(P + 147456);         // [512] f32
  float* bG     = (float*)(P + 149504);         // [192] f32
  int*   flg    = (int*)(P + 150528);

  detect_kernel<<<1, 256, 0, stream>>>((const u16*)w_ih, flg);

  // prep: V-projection weights + combined query weights
  transpose_tiled_kernel<<<dim3(8, 4), 256, 0, stream>>>(Wov, 256, 0, 128, 256, 128, WovT, flg);
  transpose_tiled_kernel<<<dim3(8, 2), 256, 0, stream>>>(Wav, 256, 0,  64, 256,  64, WavT, flg);
  transpose_tiled_kernel<<<dim3(8, 3), 256, 0, stream>>>(Wev, 256, 0,  65, 256,  96, WevT, flg);
  build_u_kernel<<<96, 256, 0, stream>>>(Wak, bak, Wek, bek, U, flg);
  bg_kernel<<<1, 256, 0, stream>>>(U, bq, bG, flg);
  bc_kernel<<<2, 256, 0, stream>>>(Wa1, be2, ba1, bc, flg);
  // WGT[c,d] = sum_a U[c,a] * Wq[d,a]
  gemm_nk_kernel<<<dim3(3, 2), 256, 0, stream>>>(U, 128, Wq, nullptr, WGT, 128, 0, 128, flg, 0, 1);
  // G = own @ WGT^T + bG   [4096,192]
  gemm_nk_kernel<<<dim3(64, 3), 256, 0, stream>>>(own, 128, WGT, bG, G, 192, 0, 128, flg, 1, 0);
  // attention -> mixbuf (clobbers U/WGT; G still live in tot region)
  attn_kernel<<<1024, 256, 0, stream>>>(G, af, ef, mixbuf, flg);
  // tot = [own@Wov | mix_a@Wav | mix_e@Wev]  (overwrites G)
  gemm_nk_kernel<<<dim3(64, 4), 256, 0, stream>>>(own, 128, WovT, nullptr, tot, 768, 0, 128, flg, 1, 0);
  gemm_nk_kernel<<<dim3(64, 4), 256, 0, stream>>>(mixbuf, 160, WavT, nullptr, tot, 768, 256, 64, flg, 0, 0);
  gemm_nk_kernel<<<dim3(64, 4), 256, 0, stream>>>(mixbuf + 64, 160, WevT, nullptr, tot, 768, 512, 96, flg, 0, 0);
  // GRU -> h (f32 in d_out)
  gru_kernel<<<dim3(32, 8), 512, 0, stream>>>(tot, hid, w_ih, w_hh, b_ih, b_hh, h_out, flg);
  // Wa1 bottom transpose (mixbuf dead) ; u = h @ Wa1_bot + bc -> u_b (overwrites tot)
  transpose_tiled_kernel<<<dim3(16, 16), 256, 0, stream>>>(Wa1, 512, 512, 512, 512, 512, Wa1bT, flg);
  gemm_nk_kernel<<<dim3(64, 8), 256, 0, stream>>>(h_out, 512, Wa1bT, bc, u_b, 512, 0, 512, flg, 2, 0);
  // Wc = We2 @ Wa1_top  (Wa1tT clobbers Wa1bT)
  transpose_tiled_kernel<<<dim3(16, 16), 256, 0, stream>>>(Wa1, 512, 0, 512, 512, 512, Wa1tT, flg);
  gemm_nk_kernel<<<dim3(8, 8), 256, 0, stream>>>(Wa1tT, 512, We2, nullptr, WcT, 512, 0, 512, flg, 0, 1);
  transpose_tiled_kernel<<<dim3(16, 3), 256, 0, stream>>>(We1, 512, 0, 65, 512, 96, We1T, flg);
  // heads
  wo_kernel<<<64, 256, 0, stream>>>(h_out, Wwo, bwo, out, flg);
  head_kernel<<<dim3(64, 32), 512, 0, stream>>>(ef, We1T, be1, WcT, u_b, Wa2, ba2, out, flg);
}

// Round 3
// 720.386 us; speedup vs baseline: 1.0417x; 1.0347x over previous
//
#include <hip/hip_runtime.h>

typedef unsigned short u16;
typedef __attribute__((ext_vector_type(8))) short short8;
typedef __attribute__((ext_vector_type(4))) short shortv4;
typedef __attribute__((ext_vector_type(4))) float floatx4;

__device__ inline float bf2f(u16 v){ union { unsigned int i; float f; } u; u.i = ((unsigned int)v) << 16; return u.f; }
__device__ inline u16 f2bf(float f){ union { float ff; unsigned int i; } u; u.ff = f; unsigned int r = u.i + 0x7fffu + ((u.i >> 16) & 1u); return (u16)(r >> 16); }
__device__ inline float sigmf(float x){ return 1.f/(1.f + __expf(-x)); }
__device__ inline float tanhfast(float x){ float e = __expf(-2.f*fabsf(x)); float t = (1.f-e)/(1.f+e); return x>=0.f? t : -t; }
__device__ inline float wred(float x){ for (int o = 32; o; o >>= 1) x += __shfl_xor(x, o); return x; }

// dual-dtype scalar load: fl==1 -> buffer is float32, else bf16(u16)
__device__ inline float ldf(const void* p, long i, int fl){
  return fl ? ((const float*)p)[i] : bf2f(((const u16*)p)[i]);
}
// 8-element load -> bf16 frag. mode: 0=bf16 buffer, 1=follow fl, 2=f32 buffer
__device__ inline short8 ld8m(const void* p, long i, int mode, int fl){
  int isf = (mode == 2) || (mode == 1 && fl);
  if (!isf) return *(const short8*)((const u16*)p + i);
  const float* f = (const float*)p + i;
  float4 x = *(const float4*)f;
  float4 y = *(const float4*)(f + 4);
  short8 r;
  r[0]=(short)f2bf(x.x); r[1]=(short)f2bf(x.y); r[2]=(short)f2bf(x.z); r[3]=(short)f2bf(x.w);
  r[4]=(short)f2bf(y.x); r[5]=(short)f2bf(y.y); r[6]=(short)f2bf(y.z); r[7]=(short)f2bf(y.w);
  return r;
}

#define MFMA(a,b,c) __builtin_amdgcn_mfma_f32_16x16x32_bf16(a,b,c,0,0,0)

// ---------------------------------------------------------------------------
__global__ void detect_kernel(const u16* __restrict__ w, int* __restrict__ flag){
  __shared__ int cnt[256];
  int t = threadIdx.x, c = 0;
  for (int i = t; i < 4096; i += 256){ u16 v = w[i]; if ((v & 0x7fff) >= 0x4200) c++; }
  cnt[t] = c; __syncthreads();
  for (int s = 128; s; s >>= 1){ if (t < s) cnt[t] += cnt[t + s]; __syncthreads(); }
  if (t == 0) *flag = (cnt[0] > 16) ? 1 : 0;
}

// ---------------------------------------------------------------------------
// coalesced tiled transpose with K-pad + row offset: out[n][k] = (k<K)? in[ro+k][n] : 0
__global__ __launch_bounds__(256) void transpose_tiled_kernel(
    const void* __restrict__ in, int ldin, int ro, int K, int N, int Kpad,
    u16* __restrict__ out, const int* __restrict__ flg)
{
  const int fl = *flg;
  __shared__ float tile[32][33];
  int k0 = blockIdx.y*32, n0 = blockIdx.x*32;
  int tx = threadIdx.x & 31, ty = threadIdx.x >> 5;   // 32 x 8
  for (int i = ty; i < 32; i += 8){
    int k = k0 + i, n = n0 + tx;
    tile[i][tx] = (k < K && n < N) ? ldf(in, (long)(ro + k)*ldin + n, fl) : 0.f;
  }
  __syncthreads();
  for (int i = ty; i < 32; i += 8){
    int n = n0 + i, k = k0 + tx;
    if (n < N && k < Kpad) out[(long)n*Kpad + k] = f2bf(tile[tx][i]);
  }
}

// ---------------------------------------------------------------------------
// U [192,128] bf16: rows 0..63 = Wak, 64 = bak, 65..129 = Wek, 130 = bek, rest 0
__global__ void build_u_kernel(const void* __restrict__ Wak, const void* __restrict__ bak,
                               const void* __restrict__ Wek, const void* __restrict__ bek,
                               u16* __restrict__ U, const int* __restrict__ flg)
{
  const int fl = *flg;
  int idx = blockIdx.x*256 + threadIdx.x;
  if (idx >= 192*128) return;
  int c = idx >> 7, a = idx & 127;
  float v = 0.f;
  if (c < 64)       v = ldf(Wak, (long)c*128 + a, fl);
  else if (c == 64) v = ldf(bak, a, fl);
  else if (c < 130) v = ldf(Wek, (long)(c-65)*128 + a, fl);
  else if (c == 130) v = ldf(bek, a, fl);
  U[idx] = f2bf(v);
}

// bG[c] = bq . U[c,:]
__global__ void bg_kernel(const u16* __restrict__ U, const void* __restrict__ bq,
                          float* __restrict__ bG, const int* __restrict__ flg)
{
  const int fl = *flg;
  int c = threadIdx.x;
  if (c >= 192) return;
  float acc = 0.f;
  for (int a = 0; a < 128; a++) acc = fmaf(ldf(bq, a, fl), bf2f(U[c*128 + a]), acc);
  bG[c] = acc;
}

// bc[j] = ba1[j] + sum_c be2[c] * Wa1[c, j]  (top half of Wa1)
// 32 blocks x 256 thr: block owns 16 j-cols, 16-way c-slice reduction.
// (was 2 blocks with 512 serial loads/thread -> only 2 CUs streaming 1MB)
__global__ __launch_bounds__(256) void bc_kernel(
    const void* __restrict__ Wa1, const void* __restrict__ be2,
    const void* __restrict__ ba1, float* __restrict__ bc,
    const int* __restrict__ flg)
{
  const int fl = *flg;
  __shared__ float red[16][17];
  const int t = threadIdx.x;
  const int jj = t & 15, cs = t >> 4;
  const int j = blockIdx.x*16 + jj;
  float acc = 0.f;
  for (int c = cs*32; c < cs*32 + 32; c++)
    acc = fmaf(ldf(be2, c, fl), ldf(Wa1, (long)c*512 + j, fl), acc);
  red[jj][cs] = acc;
  __syncthreads();
  if (t < 16){
    float s = ldf(ba1, blockIdx.x*16 + t, fl);
    #pragma unroll
    for (int k = 0; k < 16; k++) s += red[t][k];
    bc[blockIdx.x*16 + t] = s;
  }
}

// ---------------------------------------------------------------------------
// Generic MFMA GEMM: out[r, ocol+col] = A[M,K(lda)] @ B[N,K]^T + bias, bf16 out
__global__ __launch_bounds__(256) void gemm_nk_kernel(
    const void* __restrict__ A, int lda, const void* __restrict__ Bm,
    const float* __restrict__ bias, u16* __restrict__ outp, int ldout, int ocol,
    int K, const int* __restrict__ flg, int amode, int bmode)
{
  const int fl = *flg;
  __shared__ __align__(16) short Al[64*32];
  __shared__ __align__(16) short Bl[64*32];
  const int t = threadIdx.x, lane = t & 63, w = t >> 6;
  const int m0 = blockIdx.x*64, n0 = blockIdx.y*64;
  floatx4 acc[4] = {};
  const int row = t >> 2, seg = t & 3;
  for (int kt = 0; kt < K; kt += 32){
    __syncthreads();
    *(short8*)(Al + row*32 + seg*8) = ld8m(A,  (long)(m0 + row)*lda + kt + seg*8, amode, fl);
    *(short8*)(Bl + row*32 + seg*8) = ld8m(Bm, (long)(n0 + row)*K   + kt + seg*8, bmode, fl);
    __syncthreads();
    short8 a = *(const short8*)(Al + (w*16 + (lane & 15))*32 + ((lane >> 4)*8));
    #pragma unroll
    for (int nt = 0; nt < 4; nt++){
      short8 b = *(const short8*)(Bl + (nt*16 + (lane & 15))*32 + ((lane >> 4)*8));
      acc[nt] = MFMA(a, b, acc[nt]);
    }
  }
  #pragma unroll
  for (int nt = 0; nt < 4; nt++){
    int col = n0 + nt*16 + (lane & 15);
    float bb = bias ? bias[col] : 0.f;
    #pragma unroll
    for (int i = 0; i < 4; i++){
      int r = m0 + w*16 + (lane >> 4)*4 + i;
      outp[(long)r*ldout + ocol + col] = f2bf(acc[nt][i] + bb);
    }
  }
}

// ---------------------------------------------------------------------------
// Attention: one wave per batch row. G[b,0:64]=qka, 64=sa, 65:130=qke, 130=se.
__global__ __launch_bounds__(256) void attn_kernel(
    const u16* __restrict__ G, const void* __restrict__ af, const void* __restrict__ ef,
    u16* __restrict__ mixbuf, const int* __restrict__ flg)
{
  const int fl = *flg;
  __shared__ float gsh[4][192];
  __shared__ float attw[4][32];
  const int lane = threadIdx.x & 63, wv = threadIdx.x >> 6;
  const long b = blockIdx.x*4 + wv;
  const float rsA = 0.08838834764831845f;  // 1/sqrt(128)

  for (int c = lane; c < 192; c += 64) gsh[wv][c] = bf2f(G[b*192 + c]);
  __syncthreads();

  // ---- allies ----
  float qa = gsh[wv][lane];
  float sa = gsh[wv][64];
  float myE = -1e30f;
  for (int n = 0; n < 31; n++){
    float e = wred(ldf(af, ((long)n*4096 + b)*64 + lane, fl) * qa);
    e = (e + sa) * rsA;
    if (lane == n) myE = e;
  }
  {
    float m = myE;
    for (int o = 32; o; o >>= 1) m = fmaxf(m, __shfl_xor(m, o));
    float p = (lane < 31) ? __expf(myE - m) : 0.f;
    float s = wred(p);
    if (lane < 32) attw[wv][lane] = p / s;
  }
  __syncthreads();
  {
    float acc = 0.f;
    for (int n = 0; n < 31; n++)
      acc = fmaf(attw[wv][n], ldf(af, ((long)n*4096 + b)*64 + lane, fl), acc);
    mixbuf[b*160 + lane] = f2bf(acc);
  }
  __syncthreads();

  // ---- enemies (65 dims) ----
  float qe = gsh[wv][65 + lane];
  float qe64 = gsh[wv][129];
  float se = gsh[wv][130];
  myE = -1e30f;
  for (int n = 0; n < 32; n++){
    long base = ((long)n*4096 + b)*65;
    float prod = ldf(ef, base + lane, fl) * qe;
    if (lane == 0) prod = fmaf(ldf(ef, base + 64, fl), qe64, prod);
    float e = (wred(prod) + se) * rsA;
    if (lane == n) myE = e;
  }
  {
    float m = myE;
    for (int o = 32; o; o >>= 1) m = fmaxf(m, __shfl_xor(m, o));
    float p = (lane < 32) ? __expf(myE - m) : 0.f;
    float s = wred(p);
    if (lane < 32) attw[wv][lane] = p / s;
  }
  __syncthreads();
  {
    float acc = 0.f, acc64 = 0.f;
    for (int n = 0; n < 32; n++){
      long base = ((long)n*4096 + b)*65;
      float w = attw[wv][n];
      acc = fmaf(w, ldf(ef, base + lane, fl), acc);
      if (lane == 0) acc64 = fmaf(w, ldf(ef, base + 64, fl), acc64);
    }
    mixbuf[b*160 + 64 + lane] = f2bf(acc);
    if (lane == 0) mixbuf[b*160 + 128] = f2bf(acc64);
    if (lane >= 1 && lane < 32) mixbuf[b*160 + 128 + lane] = 0;
  }
}

// ---------------------------------------------------------------------------
// GRU: block = 128 batch rows x 64 hidden cols (512 thr); h (f32) -> d_out.
__global__ __launch_bounds__(512) void gru_kernel(
    const u16* __restrict__ tot, const void* __restrict__ hprev,
    const void* __restrict__ w_ih, const void* __restrict__ w_hh,
    const void* __restrict__ b_ih, const void* __restrict__ b_hh,
    float* __restrict__ h_out, const int* __restrict__ flg)
{
  const int fl = *flg;
  __shared__ __align__(16) short At[128*32], Ah[128*32];
  __shared__ __align__(16) short Bi[3][64*32], Bh[3][64*32];
  const int t = threadIdx.x, lane = t & 63, w = t >> 6;
  const int b0 = blockIdx.x*128, j0 = blockIdx.y*64;
  floatx4 ai[3][4] = {}; floatx4 ah[3][4] = {};
  const int row = t >> 2, seg = t & 3;
  for (int kt = 0; kt < 768; kt += 32){
    __syncthreads();
    *(short8*)(At + row*32 + seg*8) = *(const short8*)(tot + (long)(b0 + row)*768 + kt + seg*8);
    if (kt < 512)
      *(short8*)(Ah + row*32 + seg*8) = ld8m(hprev, (long)(b0 + row)*512 + kt + seg*8, 1, fl);
    if (t < 256){
      int rb = t >> 2, sb = t & 3;
      #pragma unroll
      for (int p = 0; p < 3; p++)
        *(short8*)(Bi[p] + rb*32 + sb*8) = ld8m(w_ih, (long)(p*512 + j0 + rb)*768 + kt + sb*8, 1, fl);
    } else if (kt < 512){
      int t2 = t - 256, rb = t2 >> 2, sb = t2 & 3;
      #pragma unroll
      for (int p = 0; p < 3; p++)
        *(short8*)(Bh[p] + rb*32 + sb*8) = ld8m(w_hh, (long)(p*512 + j0 + rb)*512 + kt + sb*8, 1, fl);
    }
    __syncthreads();
    short8 a = *(const short8*)(At + (w*16 + (lane & 15))*32 + ((lane >> 4)*8));
    #pragma unroll
    for (int p = 0; p < 3; p++){
      #pragma unroll
      for (int nt = 0; nt < 4; nt++){
        short8 b = *(const short8*)(Bi[p] + (nt*16 + (lane & 15))*32 + ((lane >> 4)*8));
        ai[p][nt] = MFMA(a, b, ai[p][nt]);
      }
    }
    if (kt < 512){
      short8 a2 = *(const short8*)(Ah + (w*16 + (lane & 15))*32 + ((lane >> 4)*8));
      #pragma unroll
      for (int p = 0; p < 3; p++){
        #pragma unroll
        for (int nt = 0; nt < 4; nt++){
          short8 b = *(const short8*)(Bh[p] + (nt*16 + (lane & 15))*32 + ((lane >> 4)*8));
          ah[p][nt] = MFMA(a2, b, ah[p][nt]);
        }
      }
    }
  }
  #pragma unroll
  for (int nt = 0; nt < 4; nt++){
    int colH = j0 + nt*16 + (lane & 15);
    float bir = ldf(b_ih, colH, fl),        bhr = ldf(b_hh, colH, fl);
    float biz = ldf(b_ih, 512 + colH, fl),  bhz = ldf(b_hh, 512 + colH, fl);
    float bin = ldf(b_ih, 1024 + colH, fl), bhn = ldf(b_hh, 1024 + colH, fl);
    #pragma unroll
    for (int i = 0; i < 4; i++){
      int r = b0 + w*16 + (lane >> 4)*4 + i;
      float rg = sigmf(ai[0][nt][i] + bir + ah[0][nt][i] + bhr);
      float zg = sigmf(ai[1][nt][i] + biz + ah[1][nt][i] + bhz);
      float ng = tanhfast(ai[2][nt][i] + bin + rg*(ah[2][nt][i] + bhn));
      float hp = ldf(hprev, (long)r*512 + colH, fl);
      h_out[(long)r*512 + colH] = (1.f - zg)*ng + zg*hp;
    }
  }
}

// ---------------------------------------------------------------------------
// wo_q = h @ Wwo + bwo -> out[:, 0:6]   (h f32 in d_out)
__global__ __launch_bounds__(256) void wo_kernel(
    const float* __restrict__ h, const void* __restrict__ Wwo,
    const void* __restrict__ bwo, float* __restrict__ out, const int* __restrict__ flg)
{
  const int fl = *flg;
  __shared__ float red[64][4][6];
  const int t = threadIdx.x, r = t >> 2, kq = t & 3;
  const int b = blockIdx.x*64 + r;
  float acc[6] = {};
  for (int k = kq*128; k < kq*128 + 128; k++){
    float hv = h[(long)b*512 + k];
    #pragma unroll
    for (int j = 0; j < 6; j++) acc[j] = fmaf(hv, ldf(Wwo, (long)k*6 + j, fl), acc[j]);
  }
  #pragma unroll
  for (int j = 0; j < 6; j++) red[r][kq][j] = acc[j];
  __syncthreads();
  if (kq == 0){
    #pragma unroll
    for (int j = 0; j < 6; j++)
      out[(long)b*38 + j] = red[r][0][j] + red[r][1][j] + red[r][2][j] + red[r][3][j] + ldf(bwo, j, fl);
  }
}

// ---------------------------------------------------------------------------
// Head: block = (64 b-rows, ONE enemy n=blockIdx.y). LDS 78.3KB -> 2 blocks/CU.
// Occupancy model (unified VGPR+AGPR file): Round-2's acc[4][4] = 64 AGPR +
// 88 arch = 152 unified -> only 3 waves/SIMD -> 2nd block can't co-reside.
// Fix: phase 2 in TWO 32-col passes (acc[4][2] = 32 AGPR, b[2]) with the
// partial epilogue folded into persistent pr[4][4]. Unified ~112 <= 128 ->
// launch_bounds(512,4) is slack (no spill) and 2 blocks/CU fit.
// Staging loop fully unrolled (13 predicated iters) so the 13 HBM loads
// pipeline over one latency instead of serializing.
__global__ __launch_bounds__(512, 4) void head_kernel(
    const void* __restrict__ ef_g, const u16* __restrict__ We1T,
    const void* __restrict__ be1, const u16* __restrict__ WcT,
    const u16* __restrict__ u_b, const void* __restrict__ wa2,
    const void* __restrict__ ba2, float* __restrict__ out, const int* __restrict__ flg)
{
  const int fl = *flg;
  __shared__ __align__(16) short r1s[64*512];   // XOR-swizzled: (row, chunk^(row&7))
  __shared__ __align__(16) char pool[64*100*2]; // efl [64][100] (phase1) / part [64][9] f32 (epilogue)
  short* efl = (short*)pool;
  float (*part)[9] = (float(*)[9])pool;
  const int t = threadIdx.x, lane = t & 63, w = t >> 6;
  const int m = lane & 15, q = lane >> 4;
  const int n = blockIdx.y, b0 = blockIdx.x*64;

  // ---- phase 1: stage enemy features (stride 100 shorts: conflict-free reads)
  #pragma unroll
  for (int it = 0; it < 13; it++){
    int idx = t + it*512;
    if (idx < 64*100){
      int r = idx / 100, d = idx - r*100;
      u16 v = 0;
      if (d < 65) v = f2bf(ldf(ef_g, ((long)n*4096 + b0 + r)*65 + d, fl));
      efl[idx] = (short)v;
    }
  }
  __syncthreads();

  // r1 = relu(ef @ We1^T + be1). Swapped operands: D[we1col][efrow], so lane
  // (m,q) accumulates cols cb+q*4..+3 of row rt*16+m -> packed b64 write.
  #pragma unroll
  for (int jt4 = 0; jt4 < 4; jt4++){
    const int cb = (w*4 + jt4)*16;
    short8 bfr[3];
    #pragma unroll
    for (int k3 = 0; k3 < 3; k3++)
      bfr[k3] = *(const short8*)(We1T + (cb + m)*96 + k3*32 + q*8);
    float be[4];
    #pragma unroll
    for (int i = 0; i < 4; i++) be[i] = ldf(be1, cb + q*4 + i, fl);
    #pragma unroll
    for (int rt = 0; rt < 4; rt++){
      floatx4 acc = {0.f, 0.f, 0.f, 0.f};
      #pragma unroll
      for (int k3 = 0; k3 < 3; k3++){
        short8 a = *(const short8*)(efl + (rt*16 + m)*100 + k3*32 + q*8);
        acc = MFMA(bfr[k3], a, acc);
      }
      const int row = rt*16 + m;
      const int cbl = cb + q*4;
      shortv4 pk;
      #pragma unroll
      for (int i = 0; i < 4; i++){
        float v = acc[i] + be[i];
        pk[i] = (short)f2bf(v > 0.f ? v : 0.f);
      }
      *(shortv4*)(r1s + row*512 + ((((cbl >> 3) ^ (row & 7)) << 3) | (cbl & 7))) = pk;
    }
  }
  __syncthreads();

  // ---- phase 2: wave w -> cols [w*64, +64) in TWO 32-col passes (reg diet)
  float pr[4][4] = {};
  #pragma unroll
  for (int p = 0; p < 2; p++){
    floatx4 acc[4][2] = {};
    for (int kt = 0; kt < 512; kt += 32){
      short8 b[2];
      #pragma unroll
      for (int js = 0; js < 2; js++)
        b[js] = *(const short8*)(WcT + (long)(w*64 + p*32 + js*16 + m)*512 + kt + q*8);
      const int ch = (((kt >> 3) + q) ^ (m & 7)) << 3;
      #pragma unroll
      for (int rt = 0; rt < 4; rt++){
        short8 a = *(const short8*)(r1s + (rt*16 + m)*512 + ch);
        #pragma unroll
        for (int js = 0; js < 2; js++)
          acc[rt][js] = MFMA(a, b[js], acc[rt][js]);
      }
    }
    // partial epilogue for these 32 cols: relu(r2 + u_b) . wa2
    #pragma unroll
    for (int js = 0; js < 2; js++){
      int col = w*64 + p*32 + js*16 + m;
      float wv = ldf(wa2, col, fl);
      #pragma unroll
      for (int rt = 0; rt < 4; rt++){
        #pragma unroll
        for (int i = 0; i < 4; i++){
          int grow = b0 + rt*16 + q*4 + i;
          float u = bf2f(u_b[(long)grow*512 + col]);
          float s = acc[rt][js][i] + u;
          pr[rt][i] += (s > 0.f ? s : 0.f) * wv;
        }
      }
    }
  }

  // ---- reduce across the 16 m-lanes, then across waves
  #pragma unroll
  for (int o = 1; o < 16; o <<= 1)
    #pragma unroll
    for (int rt = 0; rt < 4; rt++)
      #pragma unroll
      for (int i = 0; i < 4; i++)
        pr[rt][i] += __shfl_xor(pr[rt][i], o);
  if (m == 0){
    #pragma unroll
    for (int rt = 0; rt < 4; rt++)
      #pragma unroll
      for (int i = 0; i < 4; i++)
        part[rt*16 + q*4 + i][w] = pr[rt][i];
  }
  __syncthreads();
  if (t < 64){
    float s = ldf(ba2, 0, fl);
    #pragma unroll
    for (int ww = 0; ww < 8; ww++) s += part[t][ww];
    out[(long)(b0 + t)*38 + 6 + n] = s;
  }
}

// ---------------------------------------------------------------------------
extern "C" void kernel_launch(void* const* d_in, const int* in_sizes, int n_in,
                              void* d_out, int out_size, void* d_ws, size_t ws_size,
                              hipStream_t stream)
{
  (void)in_sizes; (void)n_in; (void)out_size; (void)ws_size;
  const void* own  = d_in[0];
  const void* af   = d_in[1];
  const void* ef   = d_in[2];
  const void* hid  = d_in[3];
  const void* Wq   = d_in[4];
  const void* bq   = d_in[5];
  const void* Wak  = d_in[6];
  const void* bak  = d_in[7];
  const void* Wav  = d_in[8];
  const void* Wek  = d_in[10];
  const void* bek  = d_in[11];
  const void* Wev  = d_in[12];
  const void* Wov  = d_in[14];
  const void* w_ih = d_in[16];
  const void* w_hh = d_in[17];
  const void* b_ih = d_in[18];
  const void* b_hh = d_in[19];
  const void* Wwo  = d_in[20];
  const void* bwo  = d_in[21];
  const void* We1  = d_in[22];
  const void* be1  = d_in[23];
  const void* We2  = d_in[24];
  const void* be2  = d_in[25];
  const void* Wa1  = d_in[26];
  const void* ba1  = d_in[27];
  const void* Wa2  = d_in[28];
  const void* ba2  = d_in[29];
  float* out   = (float*)d_out;                 // q [4096,38] f32
  float* h_out = out + (long)4096*38;           // h [4096,512] f32

  // ---- workspace (7.76 MB peak, time-phased aliasing) ----
  char* ws = (char*)d_ws;
  u16*   tot    = (u16*)(ws + 0);               // [4096,768] bf16 = 6,291,456
  u16*   G      = (u16*)(ws + 0);               // [4096,192] bf16 (alias, dead before tot)
  u16*   u_b    = (u16*)(ws + 0);               // [4096,512] bf16 (alias, after gru)
  char*  mz     = ws + 6291456;                 // 1,310,720 multi-phase zone
  u16*   mixbuf = (u16*)mz;                     // [4096,160] bf16 (attention phase)
  u16*   U      = (u16*)mz;                     // [192,128] bf16 (prep phase)
  u16*   WGT    = (u16*)(mz + 49152);           // [192,128] bf16 (prep phase)
  u16*   Wa1bT  = (u16*)mz;                     // [512,512] bf16 (post-tot phase)
  u16*   Wa1tT  = (u16*)mz;                     // [512,512] bf16 (post-u phase)
  u16*   WcT    = (u16*)(mz + 524288);          // [512,512] bf16 (post-u phase)
  u16*   We1T   = (u16*)(mz + 1048576);         // [512,96]  bf16 (post-u phase)
  char*  P      = ws + 7602176;                 // persistent small zone
  u16*   WovT   = (u16*)(P + 0);                // [256,128] bf16
  u16*   WavT   = (u16*)(P + 65536);            // [256,64]  bf16
  u16*   WevT   = (u16*)(P + 98304);            // [256,96]  bf16
  float* bc     = (float*)(P + 147456);         // [512] f32
  float* bG     = (float*)(P + 149504);         // [192] f32
  int*   flg    = (int*)(P + 150528);

  detect_kernel<<<1, 256, 0, stream>>>((const u16*)w_ih, flg);

  // prep: V-projection weights + combined query weights
  transpose_tiled_kernel<<<dim3(8, 4), 256, 0, stream>>>(Wov, 256, 0, 128, 256, 128, WovT, flg);
  transpose_tiled_kernel<<<dim3(8, 2), 256, 0, stream>>>(Wav, 256, 0,  64, 256,  64, WavT, flg);
  transpose_tiled_kernel<<<dim3(8, 3), 256, 0, stream>>>(Wev, 256, 0,  65, 256,  96, WevT, flg);
  build_u_kernel<<<96, 256, 0, stream>>>(Wak, bak, Wek, bek, U, flg);
  bg_kernel<<<1, 256, 0, stream>>>(U, bq, bG, flg);
  bc_kernel<<<32, 256, 0, stream>>>(Wa1, be2, ba1, bc, flg);
  // WGT[c,d] = sum_a U[c,a] * Wq[d,a]
  gemm_nk_kernel<<<dim3(3, 2), 256, 0, stream>>>(U, 128, Wq, nullptr, WGT, 128, 0, 128, flg, 0, 1);
  // G = own @ WGT^T + bG   [4096,192]
  gemm_nk_kernel<<<dim3(64, 3), 256, 0, stream>>>(own, 128, WGT, bG, G, 192, 0, 128, flg, 1, 0);
  // attention -> mixbuf (clobbers U/WGT; G still live in tot region)
  attn_kernel<<<1024, 256, 0, stream>>>(G, af, ef, mixbuf, flg);
  // tot = [own@Wov | mix_a@Wav | mix_e@Wev]  (overwrites G)
  gemm_nk_kernel<<<dim3(64, 4), 256, 0, stream>>>(own, 128, WovT, nullptr, tot, 768, 0, 128, flg, 1, 0);
  gemm_nk_kernel<<<dim3(64, 4), 256, 0, stream>>>(mixbuf, 160, WavT, nullptr, tot, 768, 256, 64, flg, 0, 0);
  gemm_nk_kernel<<<dim3(64, 4), 256, 0, stream>>>(mixbuf + 64, 160, WevT, nullptr, tot, 768, 512, 96, flg, 0, 0);
  // GRU -> h (f32 in d_out)
  gru_kernel<<<dim3(32, 8), 512, 0, stream>>>(tot, hid, w_ih, w_hh, b_ih, b_hh, h_out, flg);
  // Wa1 bottom transpose (mixbuf dead) ; u = h @ Wa1_bot + bc -> u_b (overwrites tot)
  transpose_tiled_kernel<<<dim3(16, 16), 256, 0, stream>>>(Wa1, 512, 512, 512, 512, 512, Wa1bT, flg);
  gemm_nk_kernel<<<dim3(64, 8), 256, 0, stream>>>(h_out, 512, Wa1bT, bc, u_b, 512, 0, 512, flg, 2, 0);
  // Wc = We2 @ Wa1_top  (Wa1tT clobbers Wa1bT)
  transpose_tiled_kernel<<<dim3(16, 16), 256, 0, stream>>>(Wa1, 512, 0, 512, 512, 512, Wa1tT, flg);
  gemm_nk_kernel<<<dim3(8, 8), 256, 0, stream>>>(Wa1tT, 512, We2, nullptr, WcT, 512, 0, 512, flg, 0, 1);
  transpose_tiled_kernel<<<dim3(16, 3), 256, 0, stream>>>(We1, 512, 0, 65, 512, 96, We1T, flg);
  // heads
  wo_kernel<<<64, 256, 0, stream>>>(h_out, Wwo, bwo, out, flg);
  head_kernel<<<dim3(64, 32), 512, 0, stream>>>(ef, We1T, be1, WcT, u_b, Wa2, ba2, out, flg);
}

// Round 4
// 569.475 us; speedup vs baseline: 1.3178x; 1.2650x over previous
//
#include <hip/hip_runtime.h>

typedef unsigned short u16;
typedef __attribute__((ext_vector_type(8))) short short8;
typedef __attribute__((ext_vector_type(4))) short shortv4;
typedef __attribute__((ext_vector_type(4))) float floatx4;

__device__ inline float bf2f(u16 v){ union { unsigned int i; float f; } u; u.i = ((unsigned int)v) << 16; return u.f; }
__device__ inline u16 f2bf(float f){ union { float ff; unsigned int i; } u; u.ff = f; unsigned int r = u.i + 0x7fffu + ((u.i >> 16) & 1u); return (u16)(r >> 16); }
__device__ inline float sigmf(float x){ return 1.f/(1.f + __expf(-x)); }
__device__ inline float tanhfast(float x){ float e = __expf(-2.f*fabsf(x)); float t = (1.f-e)/(1.f+e); return x>=0.f? t : -t; }
__device__ inline float wred(float x){ for (int o = 32; o; o >>= 1) x += __shfl_xor(x, o); return x; }

// dual-dtype scalar load: fl==1 -> buffer is float32, else bf16(u16)
__device__ inline float ldf(const void* p, long i, int fl){
  return fl ? ((const float*)p)[i] : bf2f(((const u16*)p)[i]);
}
// 8-element load -> bf16 frag. mode: 0=bf16 buffer, 1=follow fl, 2=f32 buffer
__device__ inline short8 ld8m(const void* p, long i, int mode, int fl){
  int isf = (mode == 2) || (mode == 1 && fl);
  if (!isf) return *(const short8*)((const u16*)p + i);
  const float* f = (const float*)p + i;
  float4 x = *(const float4*)f;
  float4 y = *(const float4*)(f + 4);
  short8 r;
  r[0]=(short)f2bf(x.x); r[1]=(short)f2bf(x.y); r[2]=(short)f2bf(x.z); r[3]=(short)f2bf(x.w);
  r[4]=(short)f2bf(y.x); r[5]=(short)f2bf(y.y); r[6]=(short)f2bf(y.z); r[7]=(short)f2bf(y.w);
  return r;
}

#define MFMA(a,b,c) __builtin_amdgcn_mfma_f32_16x16x32_bf16(a,b,c,0,0,0)

// ---------------------------------------------------------------------------
__global__ void detect_kernel(const u16* __restrict__ w, int* __restrict__ flag){
  __shared__ int cnt[256];
  int t = threadIdx.x, c = 0;
  for (int i = t; i < 4096; i += 256){ u16 v = w[i]; if ((v & 0x7fff) >= 0x4200) c++; }
  cnt[t] = c; __syncthreads();
  for (int s = 128; s; s >>= 1){ if (t < s) cnt[t] += cnt[t + s]; __syncthreads(); }
  if (t == 0) *flag = (cnt[0] > 16) ? 1 : 0;
}

// ---------------------------------------------------------------------------
// shared transpose tile body: out[n][k] = (k<K)? in[ro+k][n] : 0
__device__ inline void tbody(float (*tile)[33], const void* in, int ldin, int ro,
                             int K, int N, int Kpad, u16* out, int fl, int k0, int n0)
{
  int tx = threadIdx.x & 31, ty = threadIdx.x >> 5;   // 32 x 8
  for (int i = ty; i < 32; i += 8){
    int k = k0 + i, n = n0 + tx;
    tile[i][tx] = (k < K && n < N) ? ldf(in, (long)(ro + k)*ldin + n, fl) : 0.f;
  }
  __syncthreads();
  for (int i = ty; i < 32; i += 8){
    int n = n0 + i, k = k0 + tx;
    if (n < N && k < Kpad) out[(long)n*Kpad + k] = f2bf(tile[tx][i]);
  }
}

// early fused transpose: Wov (y<4), Wav (y<6), Wev (else). grid (8,9)
__global__ __launch_bounds__(256) void transpose3a_kernel(
    const void* __restrict__ Wov, const void* __restrict__ Wav, const void* __restrict__ Wev,
    u16* __restrict__ WovT, u16* __restrict__ WavT, u16* __restrict__ WevT,
    const int* __restrict__ flg)
{
  const int fl = *flg;
  __shared__ float tile[32][33];
  int y = blockIdx.y, n0 = blockIdx.x*32;
  if (y < 4)      tbody(tile, Wov, 256, 0, 128, 256, 128, WovT, fl, y*32, n0);
  else if (y < 6) tbody(tile, Wav, 256, 0,  64, 256,  64, WavT, fl, (y-4)*32, n0);
  else            tbody(tile, Wev, 256, 0,  65, 256,  96, WevT, fl, (y-6)*32, n0);
}

// late fused transpose: Wa1 bottom (y<16), Wa1 top (y<32), We1 (else). grid (16,35)
__global__ __launch_bounds__(256) void transpose3b_kernel(
    const void* __restrict__ Wa1, const void* __restrict__ We1,
    u16* __restrict__ Wa1bT, u16* __restrict__ Wa1tT, u16* __restrict__ We1T,
    const int* __restrict__ flg)
{
  const int fl = *flg;
  __shared__ float tile[32][33];
  int y = blockIdx.y, n0 = blockIdx.x*32;
  if (y < 16)      tbody(tile, Wa1, 512, 512, 512, 512, 512, Wa1bT, fl, y*32, n0);
  else if (y < 32) tbody(tile, Wa1, 512, 0,   512, 512, 512, Wa1tT, fl, (y-16)*32, n0);
  else             tbody(tile, We1, 512, 0,    65, 512,  96, We1T,  fl, (y-32)*32, n0);
}

// ---------------------------------------------------------------------------
// U [192,128] bf16 rows: 0..63=Wak, 64=bak, 65..129=Wek, 130=bek, rest 0.
// Fused bG[c] = bq . U[c,:] reduction (same bf16-rounded values as before).
// grid 192 x 128 thr.
__global__ __launch_bounds__(128) void build_u_bg_kernel(
    const void* __restrict__ Wak, const void* __restrict__ bak,
    const void* __restrict__ Wek, const void* __restrict__ bek,
    const void* __restrict__ bq, u16* __restrict__ U, float* __restrict__ bG,
    const int* __restrict__ flg)
{
  const int fl = *flg;
  __shared__ float pp[2];
  int c = blockIdx.x, a = threadIdx.x;
  float v = 0.f;
  if (c < 64)       v = ldf(Wak, (long)c*128 + a, fl);
  else if (c == 64) v = ldf(bak, a, fl);
  else if (c < 130) v = ldf(Wek, (long)(c-65)*128 + a, fl);
  else if (c == 130) v = ldf(bek, a, fl);
  u16 vb = f2bf(v);
  U[c*128 + a] = vb;
  float p = ldf(bq, a, fl) * bf2f(vb);   // match original bg numerics (rounded U)
  p = wred(p);
  if ((a & 63) == 0) pp[a >> 6] = p;
  __syncthreads();
  if (a == 0) bG[c] = pp[0] + pp[1];
}

// bc[j] = ba1[j] + sum_c be2[c] * Wa1[c, j]  (top half of Wa1)
// 32 blocks x 256 thr: block owns 16 j-cols, 16-way c-slice reduction.
__global__ __launch_bounds__(256) void bc_kernel(
    const void* __restrict__ Wa1, const void* __restrict__ be2,
    const void* __restrict__ ba1, float* __restrict__ bc,
    const int* __restrict__ flg)
{
  const int fl = *flg;
  __shared__ float red[16][17];
  const int t = threadIdx.x;
  const int jj = t & 15, cs = t >> 4;
  const int j = blockIdx.x*16 + jj;
  float acc = 0.f;
  for (int c = cs*32; c < cs*32 + 32; c++)
    acc = fmaf(ldf(be2, c, fl), ldf(Wa1, (long)c*512 + j, fl), acc);
  red[jj][cs] = acc;
  __syncthreads();
  if (t < 16){
    float s = ldf(ba1, blockIdx.x*16 + t, fl);
    #pragma unroll
    for (int k = 0; k < 16; k++) s += red[t][k];
    bc[blockIdx.x*16 + t] = s;
  }
}

// ---------------------------------------------------------------------------
// Generic MFMA GEMM: out[r, ocol+col] = A[M,K(lda)] @ B[N,K]^T + bias, bf16 out
__global__ __launch_bounds__(256) void gemm_nk_kernel(
    const void* __restrict__ A, int lda, const void* __restrict__ Bm,
    const float* __restrict__ bias, u16* __restrict__ outp, int ldout, int ocol,
    int K, const int* __restrict__ flg, int amode, int bmode)
{
  const int fl = *flg;
  __shared__ __align__(16) short Al[64*32];
  __shared__ __align__(16) short Bl[64*32];
  const int t = threadIdx.x, lane = t & 63, w = t >> 6;
  const int m0 = blockIdx.x*64, n0 = blockIdx.y*64;
  floatx4 acc[4] = {};
  const int row = t >> 2, seg = t & 3;
  for (int kt = 0; kt < K; kt += 32){
    __syncthreads();
    *(short8*)(Al + row*32 + seg*8) = ld8m(A,  (long)(m0 + row)*lda + kt + seg*8, amode, fl);
    *(short8*)(Bl + row*32 + seg*8) = ld8m(Bm, (long)(n0 + row)*K   + kt + seg*8, bmode, fl);
    __syncthreads();
    short8 a = *(const short8*)(Al + (w*16 + (lane & 15))*32 + ((lane >> 4)*8));
    #pragma unroll
    for (int nt = 0; nt < 4; nt++){
      short8 b = *(const short8*)(Bl + (nt*16 + (lane & 15))*32 + ((lane >> 4)*8));
      acc[nt] = MFMA(a, b, acc[nt]);
    }
  }
  #pragma unroll
  for (int nt = 0; nt < 4; nt++){
    int col = n0 + nt*16 + (lane & 15);
    float bb = bias ? bias[col] : 0.f;
    #pragma unroll
    for (int i = 0; i < 4; i++){
      int r = m0 + w*16 + (lane >> 4)*4 + i;
      outp[(long)r*ldout + ocol + col] = f2bf(acc[nt][i] + bb);
    }
  }
}

// fused tot builder: z=0 own@WovT (K=128), z=1 mixa@WavT (K=64), z=2 mixe@WevT (K=96)
// grid (64,4,3); saves 2 serial launches and overlaps tails.
__global__ __launch_bounds__(256) void gemm_tot_kernel(
    const void* __restrict__ own, const u16* __restrict__ mixbuf,
    const u16* __restrict__ WovT, const u16* __restrict__ WavT, const u16* __restrict__ WevT,
    u16* __restrict__ tot, const int* __restrict__ flg)
{
  const int fl = *flg;
  __shared__ __align__(16) short Al[64*32];
  __shared__ __align__(16) short Bl[64*32];
  const void* A; const u16* Bm; int lda, K, ocol, amode;
  if (blockIdx.z == 0){ A = own;         lda = 128; Bm = WovT; K = 128; ocol = 0;   amode = 1; }
  else if (blockIdx.z == 1){ A = mixbuf; lda = 160; Bm = WavT; K = 64;  ocol = 256; amode = 0; }
  else { A = mixbuf + 64;                lda = 160; Bm = WevT; K = 96;  ocol = 512; amode = 0; }
  const int t = threadIdx.x, lane = t & 63, w = t >> 6;
  const int m0 = blockIdx.x*64, n0 = blockIdx.y*64;
  floatx4 acc[4] = {};
  const int row = t >> 2, seg = t & 3;
  for (int kt = 0; kt < K; kt += 32){
    __syncthreads();
    *(short8*)(Al + row*32 + seg*8) = ld8m(A,  (long)(m0 + row)*lda + kt + seg*8, amode, fl);
    *(short8*)(Bl + row*32 + seg*8) = *(const short8*)(Bm + (long)(n0 + row)*K + kt + seg*8);
    __syncthreads();
    short8 a = *(const short8*)(Al + (w*16 + (lane & 15))*32 + ((lane >> 4)*8));
    #pragma unroll
    for (int nt = 0; nt < 4; nt++){
      short8 b = *(const short8*)(Bl + (nt*16 + (lane & 15))*32 + ((lane >> 4)*8));
      acc[nt] = MFMA(a, b, acc[nt]);
    }
  }
  #pragma unroll
  for (int nt = 0; nt < 4; nt++){
    int col = n0 + nt*16 + (lane & 15);
    #pragma unroll
    for (int i = 0; i < 4; i++){
      int r = m0 + w*16 + (lane >> 4)*4 + i;
      tot[(long)r*768 + ocol + col] = f2bf(acc[nt][i]);
    }
  }
}

// ---------------------------------------------------------------------------
// Attention: one wave per batch row. G[b,0:64]=qka, 64=sa, 65:130=qke, 130=se.
__global__ __launch_bounds__(256) void attn_kernel(
    const u16* __restrict__ G, const void* __restrict__ af, const void* __restrict__ ef,
    u16* __restrict__ mixbuf, const int* __restrict__ flg)
{
  const int fl = *flg;
  __shared__ float gsh[4][192];
  __shared__ float attw[4][32];
  const int lane = threadIdx.x & 63, wv = threadIdx.x >> 6;
  const long b = blockIdx.x*4 + wv;
  const float rsA = 0.08838834764831845f;  // 1/sqrt(128)

  for (int c = lane; c < 192; c += 64) gsh[wv][c] = bf2f(G[b*192 + c]);
  __syncthreads();

  // ---- allies ----
  float qa = gsh[wv][lane];
  float sa = gsh[wv][64];
  float myE = -1e30f;
  for (int n = 0; n < 31; n++){
    float e = wred(ldf(af, ((long)n*4096 + b)*64 + lane, fl) * qa);
    e = (e + sa) * rsA;
    if (lane == n) myE = e;
  }
  {
    float m = myE;
    for (int o = 32; o; o >>= 1) m = fmaxf(m, __shfl_xor(m, o));
    float p = (lane < 31) ? __expf(myE - m) : 0.f;
    float s = wred(p);
    if (lane < 32) attw[wv][lane] = p / s;
  }
  __syncthreads();
  {
    float acc = 0.f;
    for (int n = 0; n < 31; n++)
      acc = fmaf(attw[wv][n], ldf(af, ((long)n*4096 + b)*64 + lane, fl), acc);
    mixbuf[b*160 + lane] = f2bf(acc);
  }
  __syncthreads();

  // ---- enemies (65 dims) ----
  float qe = gsh[wv][65 + lane];
  float qe64 = gsh[wv][129];
  float se = gsh[wv][130];
  myE = -1e30f;
  for (int n = 0; n < 32; n++){
    long base = ((long)n*4096 + b)*65;
    float prod = ldf(ef, base + lane, fl) * qe;
    if (lane == 0) prod = fmaf(ldf(ef, base + 64, fl), qe64, prod);
    float e = (wred(prod) + se) * rsA;
    if (lane == n) myE = e;
  }
  {
    float m = myE;
    for (int o = 32; o; o >>= 1) m = fmaxf(m, __shfl_xor(m, o));
    float p = (lane < 32) ? __expf(myE - m) : 0.f;
    float s = wred(p);
    if (lane < 32) attw[wv][lane] = p / s;
  }
  __syncthreads();
  {
    float acc = 0.f, acc64 = 0.f;
    for (int n = 0; n < 32; n++){
      long base = ((long)n*4096 + b)*65;
      float w = attw[wv][n];
      acc = fmaf(w, ldf(ef, base + lane, fl), acc);
      if (lane == 0) acc64 = fmaf(w, ldf(ef, base + 64, fl), acc64);
    }
    mixbuf[b*160 + 64 + lane] = f2bf(acc);
    if (lane == 0) mixbuf[b*160 + 128] = f2bf(acc64);
    if (lane >= 1 && lane < 32) mixbuf[b*160 + 128 + lane] = 0;
  }
}

// ---------------------------------------------------------------------------
// GRU: block = 128 batch rows x 64 hidden cols (512 thr); h (f32) -> d_out.
__global__ __launch_bounds__(512) void gru_kernel(
    const u16* __restrict__ tot, const void* __restrict__ hprev,
    const void* __restrict__ w_ih, const void* __restrict__ w_hh,
    const void* __restrict__ b_ih, const void* __restrict__ b_hh,
    float* __restrict__ h_out, const int* __restrict__ flg)
{
  const int fl = *flg;
  __shared__ __align__(16) short At[128*32], Ah[128*32];
  __shared__ __align__(16) short Bi[3][64*32], Bh[3][64*32];
  const int t = threadIdx.x, lane = t & 63, w = t >> 6;
  const int b0 = blockIdx.x*128, j0 = blockIdx.y*64;
  floatx4 ai[3][4] = {}; floatx4 ah[3][4] = {};
  const int row = t >> 2, seg = t & 3;
  for (int kt = 0; kt < 768; kt += 32){
    __syncthreads();
    *(short8*)(At + row*32 + seg*8) = *(const short8*)(tot + (long)(b0 + row)*768 + kt + seg*8);
    if (kt < 512)
      *(short8*)(Ah + row*32 + seg*8) = ld8m(hprev, (long)(b0 + row)*512 + kt + seg*8, 1, fl);
    if (t < 256){
      int rb = t >> 2, sb = t & 3;
      #pragma unroll
      for (int p = 0; p < 3; p++)
        *(short8*)(Bi[p] + rb*32 + sb*8) = ld8m(w_ih, (long)(p*512 + j0 + rb)*768 + kt + sb*8, 1, fl);
    } else if (kt < 512){
      int t2 = t - 256, rb = t2 >> 2, sb = t2 & 3;
      #pragma unroll
      for (int p = 0; p < 3; p++)
        *(short8*)(Bh[p] + rb*32 + sb*8) = ld8m(w_hh, (long)(p*512 + j0 + rb)*512 + kt + sb*8, 1, fl);
    }
    __syncthreads();
    short8 a = *(const short8*)(At + (w*16 + (lane & 15))*32 + ((lane >> 4)*8));
    #pragma unroll
    for (int p = 0; p < 3; p++){
      #pragma unroll
      for (int nt = 0; nt < 4; nt++){
        short8 b = *(const short8*)(Bi[p] + (nt*16 + (lane & 15))*32 + ((lane >> 4)*8));
        ai[p][nt] = MFMA(a, b, ai[p][nt]);
      }
    }
    if (kt < 512){
      short8 a2 = *(const short8*)(Ah + (w*16 + (lane & 15))*32 + ((lane >> 4)*8));
      #pragma unroll
      for (int p = 0; p < 3; p++){
        #pragma unroll
        for (int nt = 0; nt < 4; nt++){
          short8 b = *(const short8*)(Bh[p] + (nt*16 + (lane & 15))*32 + ((lane >> 4)*8));
          ah[p][nt] = MFMA(a2, b, ah[p][nt]);
        }
      }
    }
  }
  #pragma unroll
  for (int nt = 0; nt < 4; nt++){
    int colH = j0 + nt*16 + (lane & 15);
    float bir = ldf(b_ih, colH, fl),        bhr = ldf(b_hh, colH, fl);
    float biz = ldf(b_ih, 512 + colH, fl),  bhz = ldf(b_hh, 512 + colH, fl);
    float bin = ldf(b_ih, 1024 + colH, fl), bhn = ldf(b_hh, 1024 + colH, fl);
    #pragma unroll
    for (int i = 0; i < 4; i++){
      int r = b0 + w*16 + (lane >> 4)*4 + i;
      float rg = sigmf(ai[0][nt][i] + bir + ah[0][nt][i] + bhr);
      float zg = sigmf(ai[1][nt][i] + biz + ah[1][nt][i] + bhz);
      float ng = tanhfast(ai[2][nt][i] + bin + rg*(ah[2][nt][i] + bhn));
      float hp = ldf(hprev, (long)r*512 + colH, fl);
      h_out[(long)r*512 + colH] = (1.f - zg)*ng + zg*hp;
    }
  }
}

// ---------------------------------------------------------------------------
// Head: block = (64 b-rows, TWO enemies) — the measured-best R0 structure
// (154.5us, 1 block/CU, 2 waves/SIMD). Three rounds proved the one-enemy /
// forced-occupancy variants regress (compiler can't fit 128 unified regs
// without spilling; unified VGPR+AGPR file: 120 arch + 128 acc = 248).
// Micro-fixes kept from R1-R3 (correctness-proven): ph1 swapped-operand MFMA
// -> packed ds_write_b64 into XOR-swizzled r1s (was 4 scattered b16 writes),
// efl padded 96->100 shorts (kills staging-read bank alias), staging loop
// unrolled. blockIdx.y==16 runs the (ex-)wo_kernel branch: same 64-row
// decomposition, saves a serial launch.
__global__ __launch_bounds__(512) void head_kernel(
    const void* __restrict__ ef_g, const u16* __restrict__ We1T,
    const void* __restrict__ be1, const u16* __restrict__ WcT,
    const u16* __restrict__ u_b, const void* __restrict__ wa2,
    const void* __restrict__ ba2, const float* __restrict__ h,
    const void* __restrict__ Wwo, const void* __restrict__ bwo,
    float* __restrict__ out, const int* __restrict__ flg)
{
  const int fl = *flg;
  __shared__ __align__(16) short r1s[2][64*512]; // XOR-swizzled: (row, chunk^(row&7))
  __shared__ __align__(16) char pool[64*100*2];  // efl [64][100] / part [2][64][9] / red [64][8][6]
  const int t = threadIdx.x, lane = t & 63, w = t >> 6;
  const int m = lane & 15, q = lane >> 4;
  const int b0 = blockIdx.x*64;

  if (blockIdx.y == 16){
    // ---- fused wo: out[:,0:6] = h @ Wwo + bwo for rows b0..b0+63 ----
    float (*red)[8][6] = (float(*)[8][6])pool;   // 12288 B
    const int r = t >> 3, kq = t & 7;
    const long b = b0 + r;
    float acc[6] = {};
    for (int k = kq*64; k < kq*64 + 64; k++){
      float hv = h[b*512 + k];
      #pragma unroll
      for (int j = 0; j < 6; j++) acc[j] = fmaf(hv, ldf(Wwo, (long)k*6 + j, fl), acc[j]);
    }
    #pragma unroll
    for (int j = 0; j < 6; j++) red[r][kq][j] = acc[j];
    __syncthreads();
    if (kq == 0){
      #pragma unroll
      for (int j = 0; j < 6; j++){
        float s = ldf(bwo, j, fl);
        #pragma unroll
        for (int kk = 0; kk < 8; kk++) s += red[r][kk][j];
        out[b*38 + j] = s;
      }
    }
    return;
  }

  const int n0 = blockIdx.y*2;
  short* efl = (short*)pool;                     // [64][100] = 12800 B
  float (*part)[64][9] = (float(*)[64][9])pool;  // 4608 B (after efl dead)

  // ---- phase 1: r1[e] = relu(ef @ We1^T + be1), enemies staged sequentially
  for (int e = 0; e < 2; e++){
    const int n = n0 + e;
    __syncthreads();   // protect efl from previous enemy's readers
    #pragma unroll
    for (int it = 0; it < 13; it++){
      int idx = t + it*512;
      if (idx < 6400){
        int r = idx / 100, d = idx - r*100;
        u16 v = 0;
        if (d < 65) v = f2bf(ldf(ef_g, ((long)n*4096 + b0 + r)*65 + d, fl));
        efl[idx] = (short)v;
      }
    }
    __syncthreads();
    // Swapped operands: lane (m,q) owns r1 row rt*16+m, cols cb+q*4..+3
    // -> single packed b64 write into the swizzled buffer.
    #pragma unroll
    for (int jt4 = 0; jt4 < 4; jt4++){
      const int cb = (w*4 + jt4)*16;
      short8 bfr[3];
      #pragma unroll
      for (int k3 = 0; k3 < 3; k3++)
        bfr[k3] = *(const short8*)(We1T + (cb + m)*96 + k3*32 + q*8);
      float be[4];
      #pragma unroll
      for (int i = 0; i < 4; i++) be[i] = ldf(be1, cb + q*4 + i, fl);
      #pragma unroll
      for (int rt = 0; rt < 4; rt++){
        floatx4 acc = {0.f, 0.f, 0.f, 0.f};
        #pragma unroll
        for (int k3 = 0; k3 < 3; k3++){
          short8 a = *(const short8*)(efl + (rt*16 + m)*100 + k3*32 + q*8);
          acc = MFMA(bfr[k3], a, acc);
        }
        const int row = rt*16 + m;
        const int cbl = cb + q*4;
        shortv4 pk;
        #pragma unroll
        for (int i = 0; i < 4; i++){
          float v = acc[i] + be[i];
          pk[i] = (short)f2bf(v > 0.f ? v : 0.f);
        }
        *(shortv4*)(r1s[e] + row*512 + ((((cbl >> 3) ^ (row & 7)) << 3) | (cbl & 7))) = pk;
      }
    }
  }
  __syncthreads();

  // ---- phase 2: wave w -> output cols [w*64, +64); each B-frag used 8x (2e x 4rt)
  floatx4 acc[2][4][4] = {};
  for (int kt = 0; kt < 512; kt += 32){
    short8 b[4];
    #pragma unroll
    for (int js = 0; js < 4; js++)
      b[js] = *(const short8*)(WcT + (long)(w*64 + js*16 + m)*512 + kt + q*8);
    const int ch = (((kt >> 3) + q) ^ (m & 7)) << 3;
    #pragma unroll
    for (int e = 0; e < 2; e++){
      #pragma unroll
      for (int rt = 0; rt < 4; rt++){
        short8 a = *(const short8*)(r1s[e] + (rt*16 + m)*512 + ch);
        #pragma unroll
        for (int js = 0; js < 4; js++)
          acc[e][rt][js] = MFMA(a, b[js], acc[e][rt][js]);
      }
    }
  }

  // ---- epilogue: u_b loaded once, shared across both enemies
  float pr[2][4][4] = {};
  #pragma unroll
  for (int js = 0; js < 4; js++){
    int col = w*64 + js*16 + m;
    float wv = ldf(wa2, col, fl);
    #pragma unroll
    for (int rt = 0; rt < 4; rt++){
      #pragma unroll
      for (int i = 0; i < 4; i++){
        int grow = b0 + rt*16 + q*4 + i;
        float u = bf2f(u_b[(long)grow*512 + col]);
        #pragma unroll
        for (int e = 0; e < 2; e++){
          float s = acc[e][rt][js][i] + u;
          pr[e][rt][i] += (s > 0.f ? s : 0.f) * wv;
        }
      }
    }
  }
  #pragma unroll
  for (int o = 1; o < 16; o <<= 1){
    #pragma unroll
    for (int e = 0; e < 2; e++)
      #pragma unroll
      for (int rt = 0; rt < 4; rt++)
        #pragma unroll
        for (int i = 0; i < 4; i++)
          pr[e][rt][i] += __shfl_xor(pr[e][rt][i], o);
  }
  if (m == 0){
    #pragma unroll
    for (int e = 0; e < 2; e++)
      #pragma unroll
      for (int rt = 0; rt < 4; rt++)
        #pragma unroll
        for (int i = 0; i < 4; i++)
          part[e][rt*16 + q*4 + i][w] = pr[e][rt][i];
  }
  __syncthreads();
  if (t < 128){
    int e = t >> 6, r = t & 63;
    float s = ldf(ba2, 0, fl);
    #pragma unroll
    for (int ww = 0; ww < 8; ww++) s += part[e][r][ww];
    out[(long)(b0 + r)*38 + 6 + n0 + e] = s;
  }
}

// ---------------------------------------------------------------------------
extern "C" void kernel_launch(void* const* d_in, const int* in_sizes, int n_in,
                              void* d_out, int out_size, void* d_ws, size_t ws_size,
                              hipStream_t stream)
{
  (void)in_sizes; (void)n_in; (void)out_size; (void)ws_size;
  const void* own  = d_in[0];
  const void* af   = d_in[1];
  const void* ef   = d_in[2];
  const void* hid  = d_in[3];
  const void* Wq   = d_in[4];
  const void* bq   = d_in[5];
  const void* Wak  = d_in[6];
  const void* bak  = d_in[7];
  const void* Wav  = d_in[8];
  const void* Wek  = d_in[10];
  const void* bek  = d_in[11];
  const void* Wev  = d_in[12];
  const void* Wov  = d_in[14];
  const void* w_ih = d_in[16];
  const void* w_hh = d_in[17];
  const void* b_ih = d_in[18];
  const void* b_hh = d_in[19];
  const void* Wwo  = d_in[20];
  const void* bwo  = d_in[21];
  const void* We1  = d_in[22];
  const void* be1  = d_in[23];
  const void* We2  = d_in[24];
  const void* be2  = d_in[25];
  const void* Wa1  = d_in[26];
  const void* ba1  = d_in[27];
  const void* Wa2  = d_in[28];
  const void* ba2  = d_in[29];
  float* out   = (float*)d_out;                 // q [4096,38] f32
  float* h_out = out + (long)4096*38;           // h [4096,512] f32

  // ---- workspace (7.76 MB peak, time-phased aliasing) ----
  char* ws = (char*)d_ws;
  u16*   tot    = (u16*)(ws + 0);               // [4096,768] bf16 = 6,291,456
  u16*   G      = (u16*)(ws + 0);               // [4096,192] bf16 (alias, dead before tot)
  u16*   u_b    = (u16*)(ws + 0);               // [4096,512] bf16 = 4 MB (alias, after gru)
  u16*   Wa1tT  = (u16*)(ws + 4194304);         // [512,512] bf16 (tot region tail, post-gru)
  char*  mz     = ws + 6291456;                 // 1,310,720 multi-phase zone
  u16*   mixbuf = (u16*)mz;                     // [4096,160] bf16 (attention phase)
  u16*   U      = (u16*)mz;                     // [192,128] bf16 (prep phase)
  u16*   WGT    = (u16*)(mz + 49152);           // [192,128] bf16 (prep phase)
  u16*   Wa1bT  = (u16*)mz;                     // [512,512] bf16 (post-gru phase)
  u16*   WcT    = (u16*)(mz + 524288);          // [512,512] bf16 (post-u phase)
  u16*   We1T   = (u16*)(mz + 1048576);         // [512,96]  bf16 (post-gru phase)
  char*  P      = ws + 7602176;                 // persistent small zone
  u16*   WovT   = (u16*)(P + 0);                // [256,128] bf16
  u16*   WavT   = (u16*)(P + 65536);            // [256,64]  bf16
  u16*   WevT   = (u16*)(P + 98304);            // [256,96]  bf16
  float* bc     = (float*)(P + 147456);         // [512] f32
  float* bG     = (float*)(P + 149504);         // [192] f32
  int*   flg    = (int*)(P + 150528);

  detect_kernel<<<1, 256, 0, stream>>>((const u16*)w_ih, flg);

  // prep: fused V-projection transposes + fused U/bG + parallel bc
  transpose3a_kernel<<<dim3(8, 9), 256, 0, stream>>>(Wov, Wav, Wev, WovT, WavT, WevT, flg);
  build_u_bg_kernel<<<192, 128, 0, stream>>>(Wak, bak, Wek, bek, bq, U, bG, flg);
  bc_kernel<<<32, 256, 0, stream>>>(Wa1, be2, ba1, bc, flg);
  // WGT[c,d] = sum_a U[c,a] * Wq[d,a]
  gemm_nk_kernel<<<dim3(3, 2), 256, 0, stream>>>(U, 128, Wq, nullptr, WGT, 128, 0, 128, flg, 0, 1);
  // G = own @ WGT^T + bG   [4096,192]
  gemm_nk_kernel<<<dim3(64, 3), 256, 0, stream>>>(own, 128, WGT, bG, G, 192, 0, 128, flg, 1, 0);
  // attention -> mixbuf (clobbers U/WGT; G still live in tot region)
  attn_kernel<<<1024, 256, 0, stream>>>(G, af, ef, mixbuf, flg);
  // tot = [own@Wov | mix_a@Wav | mix_e@Wev]  (one launch; overwrites G)
  gemm_tot_kernel<<<dim3(64, 4, 3), 256, 0, stream>>>(own, mixbuf, WovT, WavT, WevT, tot, flg);
  // GRU -> h (f32 in d_out)
  gru_kernel<<<dim3(32, 8), 512, 0, stream>>>(tot, hid, w_ih, w_hh, b_ih, b_hh, h_out, flg);
  // fused late transposes (tot + mixbuf dead): Wa1bT@mz, Wa1tT@ws+4MB, We1T
  transpose3b_kernel<<<dim3(16, 35), 256, 0, stream>>>(Wa1, We1, Wa1bT, Wa1tT, We1T, flg);
  // u = h @ Wa1_bot + bc -> u_b (overwrites tot[0:4MB]; Wa1tT at 4MB+ untouched)
  gemm_nk_kernel<<<dim3(64, 8), 256, 0, stream>>>(h_out, 512, Wa1bT, bc, u_b, 512, 0, 512, flg, 2, 0);
  // Wc = We2 @ Wa1_top
  gemm_nk_kernel<<<dim3(8, 8), 256, 0, stream>>>(Wa1tT, 512, We2, nullptr, WcT, 512, 0, 512, flg, 0, 1);
  // heads (y==16 branch = fused wo)
  head_kernel<<<dim3(64, 17), 512, 0, stream>>>(ef, We1T, be1, WcT, u_b, Wa2, ba2,
                                                h_out, Wwo, bwo, out, flg);
}

// Round 5
// 552.881 us; speedup vs baseline: 1.3574x; 1.0300x over previous
//
#include <hip/hip_runtime.h>

typedef unsigned short u16;
typedef __attribute__((ext_vector_type(8))) short short8;
typedef __attribute__((ext_vector_type(4))) float floatx4;

__device__ inline float bf2f(u16 v){ union { unsigned int i; float f; } u; u.i = ((unsigned int)v) << 16; return u.f; }
__device__ inline u16 f2bf(float f){ union { float ff; unsigned int i; } u; u.ff = f; unsigned int r = u.i + 0x7fffu + ((u.i >> 16) & 1u); return (u16)(r >> 16); }
__device__ inline float sigmf(float x){ return 1.f/(1.f + __expf(-x)); }
__device__ inline float tanhfast(float x){ float e = __expf(-2.f*fabsf(x)); float t = (1.f-e)/(1.f+e); return x>=0.f? t : -t; }
__device__ inline float wred(float x){ for (int o = 32; o; o >>= 1) x += __shfl_xor(x, o); return x; }

// dual-dtype scalar load: fl==1 -> buffer is float32, else bf16(u16)
__device__ inline float ldf(const void* p, long i, int fl){
  return fl ? ((const float*)p)[i] : bf2f(((const u16*)p)[i]);
}
// 8-element load -> bf16 frag. mode: 0=bf16 buffer, 1=follow fl, 2=f32 buffer
__device__ inline short8 ld8m(const void* p, long i, int mode, int fl){
  int isf = (mode == 2) || (mode == 1 && fl);
  if (!isf) return *(const short8*)((const u16*)p + i);
  const float* f = (const float*)p + i;
  float4 x = *(const float4*)f;
  float4 y = *(const float4*)(f + 4);
  short8 r;
  r[0]=(short)f2bf(x.x); r[1]=(short)f2bf(x.y); r[2]=(short)f2bf(x.z); r[3]=(short)f2bf(x.w);
  r[4]=(short)f2bf(y.x); r[5]=(short)f2bf(y.y); r[6]=(short)f2bf(y.z); r[7]=(short)f2bf(y.w);
  return r;
}

#define MFMA(a,b,c) __builtin_amdgcn_mfma_f32_16x16x32_bf16(a,b,c,0,0,0)

// ---------------------------------------------------------------------------
__global__ void detect_kernel(const u16* __restrict__ w, int* __restrict__ flag){
  __shared__ int cnt[256];
  int t = threadIdx.x, c = 0;
  for (int i = t; i < 4096; i += 256){ u16 v = w[i]; if ((v & 0x7fff) >= 0x4200) c++; }
  cnt[t] = c; __syncthreads();
  for (int s = 128; s; s >>= 1){ if (t < s) cnt[t] += cnt[t + s]; __syncthreads(); }
  if (t == 0) *flag = (cnt[0] > 16) ? 1 : 0;
}

// ---------------------------------------------------------------------------
// shared transpose tile body: out[n][k] = (k<K)? in[ro+k][n] : 0
__device__ inline void tbody(float (*tile)[33], const void* in, int ldin, int ro,
                             int K, int N, int Kpad, u16* out, int fl, int k0, int n0)
{
  int tx = threadIdx.x & 31, ty = threadIdx.x >> 5;   // 32 x 8
  for (int i = ty; i < 32; i += 8){
    int k = k0 + i, n = n0 + tx;
    tile[i][tx] = (k < K && n < N) ? ldf(in, (long)(ro + k)*ldin + n, fl) : 0.f;
  }
  __syncthreads();
  for (int i = ty; i < 32; i += 8){
    int n = n0 + i, k = k0 + tx;
    if (n < N && k < Kpad) out[(long)n*Kpad + k] = f2bf(tile[tx][i]);
  }
}

// early fused transpose: Wov (y<4), Wav (y<6), Wev (else). grid (8,9)
__global__ __launch_bounds__(256) void transpose3a_kernel(
    const void* __restrict__ Wov, const void* __restrict__ Wav, const void* __restrict__ Wev,
    u16* __restrict__ WovT, u16* __restrict__ WavT, u16* __restrict__ WevT,
    const int* __restrict__ flg)
{
  const int fl = *flg;
  __shared__ float tile[32][33];
  int y = blockIdx.y, n0 = blockIdx.x*32;
  if (y < 4)      tbody(tile, Wov, 256, 0, 128, 256, 128, WovT, fl, y*32, n0);
  else if (y < 6) tbody(tile, Wav, 256, 0,  64, 256,  64, WavT, fl, (y-4)*32, n0);
  else            tbody(tile, Wev, 256, 0,  65, 256,  96, WevT, fl, (y-6)*32, n0);
}

// late fused transpose: Wa1 bottom (y<16), Wa1 top (y<32), We1 (else). grid (16,35)
__global__ __launch_bounds__(256) void transpose3b_kernel(
    const void* __restrict__ Wa1, const void* __restrict__ We1,
    u16* __restrict__ Wa1bT, u16* __restrict__ Wa1tT, u16* __restrict__ We1T,
    const int* __restrict__ flg)
{
  const int fl = *flg;
  __shared__ float tile[32][33];
  int y = blockIdx.y, n0 = blockIdx.x*32;
  if (y < 16)      tbody(tile, Wa1, 512, 512, 512, 512, 512, Wa1bT, fl, y*32, n0);
  else if (y < 32) tbody(tile, Wa1, 512, 0,   512, 512, 512, Wa1tT, fl, (y-16)*32, n0);
  else             tbody(tile, We1, 512, 0,    65, 512,  96, We1T,  fl, (y-32)*32, n0);
}

// ---------------------------------------------------------------------------
// U [192,128] bf16 rows: 0..63=Wak, 64=bak, 65..129=Wek, 130=bek, rest 0.
// Fused bG[c] = bq . U[c,:] reduction (same bf16-rounded values as before).
// grid 192 x 128 thr.
__global__ __launch_bounds__(128) void build_u_bg_kernel(
    const void* __restrict__ Wak, const void* __restrict__ bak,
    const void* __restrict__ Wek, const void* __restrict__ bek,
    const void* __restrict__ bq, u16* __restrict__ U, float* __restrict__ bG,
    const int* __restrict__ flg)
{
  const int fl = *flg;
  __shared__ float pp[2];
  int c = blockIdx.x, a = threadIdx.x;
  float v = 0.f;
  if (c < 64)       v = ldf(Wak, (long)c*128 + a, fl);
  else if (c == 64) v = ldf(bak, a, fl);
  else if (c < 130) v = ldf(Wek, (long)(c-65)*128 + a, fl);
  else if (c == 130) v = ldf(bek, a, fl);
  u16 vb = f2bf(v);
  U[c*128 + a] = vb;
  float p = ldf(bq, a, fl) * bf2f(vb);   // match original bg numerics (rounded U)
  p = wred(p);
  if ((a & 63) == 0) pp[a >> 6] = p;
  __syncthreads();
  if (a == 0) bG[c] = pp[0] + pp[1];
}

// bc[j] = ba1[j] + sum_c be2[c] * Wa1[c, j]  (top half of Wa1)
// 32 blocks x 256 thr: block owns 16 j-cols, 16-way c-slice reduction.
__global__ __launch_bounds__(256) void bc_kernel(
    const void* __restrict__ Wa1, const void* __restrict__ be2,
    const void* __restrict__ ba1, float* __restrict__ bc,
    const int* __restrict__ flg)
{
  const int fl = *flg;
  __shared__ float red[16][17];
  const int t = threadIdx.x;
  const int jj = t & 15, cs = t >> 4;
  const int j = blockIdx.x*16 + jj;
  float acc = 0.f;
  for (int c = cs*32; c < cs*32 + 32; c++)
    acc = fmaf(ldf(be2, c, fl), ldf(Wa1, (long)c*512 + j, fl), acc);
  red[jj][cs] = acc;
  __syncthreads();
  if (t < 16){
    float s = ldf(ba1, blockIdx.x*16 + t, fl);
    #pragma unroll
    for (int k = 0; k < 16; k++) s += red[t][k];
    bc[blockIdx.x*16 + t] = s;
  }
}

// ---------------------------------------------------------------------------
// Generic MFMA GEMM: out[r, ocol+col] = A[M,K(lda)] @ B[N,K]^T + bias, bf16 out
__global__ __launch_bounds__(256) void gemm_nk_kernel(
    const void* __restrict__ A, int lda, const void* __restrict__ Bm,
    const float* __restrict__ bias, u16* __restrict__ outp, int ldout, int ocol,
    int K, const int* __restrict__ flg, int amode, int bmode)
{
  const int fl = *flg;
  __shared__ __align__(16) short Al[64*32];
  __shared__ __align__(16) short Bl[64*32];
  const int t = threadIdx.x, lane = t & 63, w = t >> 6;
  const int m0 = blockIdx.x*64, n0 = blockIdx.y*64;
  floatx4 acc[4] = {};
  const int row = t >> 2, seg = t & 3;
  for (int kt = 0; kt < K; kt += 32){
    __syncthreads();
    *(short8*)(Al + row*32 + seg*8) = ld8m(A,  (long)(m0 + row)*lda + kt + seg*8, amode, fl);
    *(short8*)(Bl + row*32 + seg*8) = ld8m(Bm, (long)(n0 + row)*K   + kt + seg*8, bmode, fl);
    __syncthreads();
    short8 a = *(const short8*)(Al + (w*16 + (lane & 15))*32 + ((lane >> 4)*8));
    #pragma unroll
    for (int nt = 0; nt < 4; nt++){
      short8 b = *(const short8*)(Bl + (nt*16 + (lane & 15))*32 + ((lane >> 4)*8));
      acc[nt] = MFMA(a, b, acc[nt]);
    }
  }
  #pragma unroll
  for (int nt = 0; nt < 4; nt++){
    int col = n0 + nt*16 + (lane & 15);
    float bb = bias ? bias[col] : 0.f;
    #pragma unroll
    for (int i = 0; i < 4; i++){
      int r = m0 + w*16 + (lane >> 4)*4 + i;
      outp[(long)r*ldout + ocol + col] = f2bf(acc[nt][i] + bb);
    }
  }
}

// fused tot builder: z=0 own@WovT (K=128), z=1 mixa@WavT (K=64), z=2 mixe@WevT (K=96)
// grid (64,4,3); saves 2 serial launches and overlaps tails.
__global__ __launch_bounds__(256) void gemm_tot_kernel(
    const void* __restrict__ own, const u16* __restrict__ mixbuf,
    const u16* __restrict__ WovT, const u16* __restrict__ WavT, const u16* __restrict__ WevT,
    u16* __restrict__ tot, const int* __restrict__ flg)
{
  const int fl = *flg;
  __shared__ __align__(16) short Al[64*32];
  __shared__ __align__(16) short Bl[64*32];
  const void* A; const u16* Bm; int lda, K, ocol, amode;
  if (blockIdx.z == 0){ A = own;         lda = 128; Bm = WovT; K = 128; ocol = 0;   amode = 1; }
  else if (blockIdx.z == 1){ A = mixbuf; lda = 160; Bm = WavT; K = 64;  ocol = 256; amode = 0; }
  else { A = mixbuf + 64;                lda = 160; Bm = WevT; K = 96;  ocol = 512; amode = 0; }
  const int t = threadIdx.x, lane = t & 63, w = t >> 6;
  const int m0 = blockIdx.x*64, n0 = blockIdx.y*64;
  floatx4 acc[4] = {};
  const int row = t >> 2, seg = t & 3;
  for (int kt = 0; kt < K; kt += 32){
    __syncthreads();
    *(short8*)(Al + row*32 + seg*8) = ld8m(A,  (long)(m0 + row)*lda + kt + seg*8, amode, fl);
    *(short8*)(Bl + row*32 + seg*8) = *(const short8*)(Bm + (long)(n0 + row)*K + kt + seg*8);
    __syncthreads();
    short8 a = *(const short8*)(Al + (w*16 + (lane & 15))*32 + ((lane >> 4)*8));
    #pragma unroll
    for (int nt = 0; nt < 4; nt++){
      short8 b = *(const short8*)(Bl + (nt*16 + (lane & 15))*32 + ((lane >> 4)*8));
      acc[nt] = MFMA(a, b, acc[nt]);
    }
  }
  #pragma unroll
  for (int nt = 0; nt < 4; nt++){
    int col = n0 + nt*16 + (lane & 15);
    #pragma unroll
    for (int i = 0; i < 4; i++){
      int r = m0 + w*16 + (lane >> 4)*4 + i;
      tot[(long)r*768 + ocol + col] = f2bf(acc[nt][i]);
    }
  }
}

// ---------------------------------------------------------------------------
// Attention: one wave per batch row. G[b,0:64]=qka, 64=sa, 65:130=qke, 130=se.
__global__ __launch_bounds__(256) void attn_kernel(
    const u16* __restrict__ G, const void* __restrict__ af, const void* __restrict__ ef,
    u16* __restrict__ mixbuf, const int* __restrict__ flg)
{
  const int fl = *flg;
  __shared__ float gsh[4][192];
  __shared__ float attw[4][32];
  const int lane = threadIdx.x & 63, wv = threadIdx.x >> 6;
  const long b = blockIdx.x*4 + wv;
  const float rsA = 0.08838834764831845f;  // 1/sqrt(128)

  for (int c = lane; c < 192; c += 64) gsh[wv][c] = bf2f(G[b*192 + c]);
  __syncthreads();

  // ---- allies ----
  float qa = gsh[wv][lane];
  float sa = gsh[wv][64];
  float myE = -1e30f;
  for (int n = 0; n < 31; n++){
    float e = wred(ldf(af, ((long)n*4096 + b)*64 + lane, fl) * qa);
    e = (e + sa) * rsA;
    if (lane == n) myE = e;
  }
  {
    float m = myE;
    for (int o = 32; o; o >>= 1) m = fmaxf(m, __shfl_xor(m, o));
    float p = (lane < 31) ? __expf(myE - m) : 0.f;
    float s = wred(p);
    if (lane < 32) attw[wv][lane] = p / s;
  }
  __syncthreads();
  {
    float acc = 0.f;
    for (int n = 0; n < 31; n++)
      acc = fmaf(attw[wv][n], ldf(af, ((long)n*4096 + b)*64 + lane, fl), acc);
    mixbuf[b*160 + lane] = f2bf(acc);
  }
  __syncthreads();

  // ---- enemies (65 dims) ----
  float qe = gsh[wv][65 + lane];
  float qe64 = gsh[wv][129];
  float se = gsh[wv][130];
  myE = -1e30f;
  for (int n = 0; n < 32; n++){
    long base = ((long)n*4096 + b)*65;
    float prod = ldf(ef, base + lane, fl) * qe;
    if (lane == 0) prod = fmaf(ldf(ef, base + 64, fl), qe64, prod);
    float e = (wred(prod) + se) * rsA;
    if (lane == n) myE = e;
  }
  {
    float m = myE;
    for (int o = 32; o; o >>= 1) m = fmaxf(m, __shfl_xor(m, o));
    float p = (lane < 32) ? __expf(myE - m) : 0.f;
    float s = wred(p);
    if (lane < 32) attw[wv][lane] = p / s;
  }
  __syncthreads();
  {
    float acc = 0.f, acc64 = 0.f;
    for (int n = 0; n < 32; n++){
      long base = ((long)n*4096 + b)*65;
      float w = attw[wv][n];
      acc = fmaf(w, ldf(ef, base + lane, fl), acc);
      if (lane == 0) acc64 = fmaf(w, ldf(ef, base + 64, fl), acc64);
    }
    mixbuf[b*160 + 64 + lane] = f2bf(acc);
    if (lane == 0) mixbuf[b*160 + 128] = f2bf(acc64);
    if (lane >= 1 && lane < 32) mixbuf[b*160 + 128 + lane] = 0;
  }
}

// ---------------------------------------------------------------------------
// GRU: block = 128 batch rows x 64 hidden cols (512 thr); h (f32) -> d_out.
__global__ __launch_bounds__(512) void gru_kernel(
    const u16* __restrict__ tot, const void* __restrict__ hprev,
    const void* __restrict__ w_ih, const void* __restrict__ w_hh,
    const void* __restrict__ b_ih, const void* __restrict__ b_hh,
    float* __restrict__ h_out, const int* __restrict__ flg)
{
  const int fl = *flg;
  __shared__ __align__(16) short At[128*32], Ah[128*32];
  __shared__ __align__(16) short Bi[3][64*32], Bh[3][64*32];
  const int t = threadIdx.x, lane = t & 63, w = t >> 6;
  const int b0 = blockIdx.x*128, j0 = blockIdx.y*64;
  floatx4 ai[3][4] = {}; floatx4 ah[3][4] = {};
  const int row = t >> 2, seg = t & 3;
  for (int kt = 0; kt < 768; kt += 32){
    __syncthreads();
    *(short8*)(At + row*32 + seg*8) = *(const short8*)(tot + (long)(b0 + row)*768 + kt + seg*8);
    if (kt < 512)
      *(short8*)(Ah + row*32 + seg*8) = ld8m(hprev, (long)(b0 + row)*512 + kt + seg*8, 1, fl);
    if (t < 256){
      int rb = t >> 2, sb = t & 3;
      #pragma unroll
      for (int p = 0; p < 3; p++)
        *(short8*)(Bi[p] + rb*32 + sb*8) = ld8m(w_ih, (long)(p*512 + j0 + rb)*768 + kt + sb*8, 1, fl);
    } else if (kt < 512){
      int t2 = t - 256, rb = t2 >> 2, sb = t2 & 3;
      #pragma unroll
      for (int p = 0; p < 3; p++)
        *(short8*)(Bh[p] + rb*32 + sb*8) = ld8m(w_hh, (long)(p*512 + j0 + rb)*512 + kt + sb*8, 1, fl);
    }
    __syncthreads();
    short8 a = *(const short8*)(At + (w*16 + (lane & 15))*32 + ((lane >> 4)*8));
    #pragma unroll
    for (int p = 0; p < 3; p++){
      #pragma unroll
      for (int nt = 0; nt < 4; nt++){
        short8 b = *(const short8*)(Bi[p] + (nt*16 + (lane & 15))*32 + ((lane >> 4)*8));
        ai[p][nt] = MFMA(a, b, ai[p][nt]);
      }
    }
    if (kt < 512){
      short8 a2 = *(const short8*)(Ah + (w*16 + (lane & 15))*32 + ((lane >> 4)*8));
      #pragma unroll
      for (int p = 0; p < 3; p++){
        #pragma unroll
        for (int nt = 0; nt < 4; nt++){
          short8 b = *(const short8*)(Bh[p] + (nt*16 + (lane & 15))*32 + ((lane >> 4)*8));
          ah[p][nt] = MFMA(a2, b, ah[p][nt]);
        }
      }
    }
  }
  #pragma unroll
  for (int nt = 0; nt < 4; nt++){
    int colH = j0 + nt*16 + (lane & 15);
    float bir = ldf(b_ih, colH, fl),        bhr = ldf(b_hh, colH, fl);
    float biz = ldf(b_ih, 512 + colH, fl),  bhz = ldf(b_hh, 512 + colH, fl);
    float bin = ldf(b_ih, 1024 + colH, fl), bhn = ldf(b_hh, 1024 + colH, fl);
    #pragma unroll
    for (int i = 0; i < 4; i++){
      int r = b0 + w*16 + (lane >> 4)*4 + i;
      float rg = sigmf(ai[0][nt][i] + bir + ah[0][nt][i] + bhr);
      float zg = sigmf(ai[1][nt][i] + biz + ah[1][nt][i] + bhz);
      float ng = tanhfast(ai[2][nt][i] + bin + rg*(ah[2][nt][i] + bhn));
      float hp = ldf(hprev, (long)r*512 + colH, fl);
      h_out[(long)r*512 + colH] = (1.f - zg)*ng + zg*hp;
    }
  }
}

// ---------------------------------------------------------------------------
// wo_q = h @ Wwo + bwo -> out[:, 0:6]   (h f32 in d_out)
__global__ __launch_bounds__(256) void wo_kernel(
    const float* __restrict__ h, const void* __restrict__ Wwo,
    const void* __restrict__ bwo, float* __restrict__ out, const int* __restrict__ flg)
{
  const int fl = *flg;
  __shared__ float red[64][4][6];
  const int t = threadIdx.x, r = t >> 2, kq = t & 3;
  const int b = blockIdx.x*64 + r;
  float acc[6] = {};
  for (int k = kq*128; k < kq*128 + 128; k++){
    float hv = h[(long)b*512 + k];
    #pragma unroll
    for (int j = 0; j < 6; j++) acc[j] = fmaf(hv, ldf(Wwo, (long)k*6 + j, fl), acc[j]);
  }
  #pragma unroll
  for (int j = 0; j < 6; j++) red[r][kq][j] = acc[j];
  __syncthreads();
  if (kq == 0){
    #pragma unroll
    for (int j = 0; j < 6; j++)
      out[(long)b*38 + j] = red[r][0][j] + red[r][1][j] + red[r][2][j] + red[r][3][j] + ldf(bwo, j, fl);
  }
}

// ---------------------------------------------------------------------------
// Head: EXACT R0 body (measured 154.5us). Block = (64 b-rows, TWO enemies
// n0,n0+1). r1 for both enemies in XOR-swizzled LDS; phase 2 streams each
// WcT B-frag once and uses it for both enemies; u_b loaded once per output
// element and shared across enemies. R4's phase-1 rewrite bundle (swapped
// MFMA + packed writes + efl repad + unrolled staging + wo fusion) made the
// per-block time +36% despite fewer bank conflicts — reverted wholesale.
__global__ __launch_bounds__(512) void head_kernel(
    const void* __restrict__ ef_g, const u16* __restrict__ We1T,
    const void* __restrict__ be1, const u16* __restrict__ WcT,
    const u16* __restrict__ u_b, const void* __restrict__ wa2,
    const void* __restrict__ ba2, float* __restrict__ out, const int* __restrict__ flg)
{
  const int fl = *flg;
  __shared__ __align__(16) short r1s[2][64*512];  // XOR-swizzled: (row, chunk^(row&7))
  __shared__ __align__(16) short efl[64*96];
  __shared__ float part[2][64][9];
  const int t = threadIdx.x, lane = t & 63, w = t >> 6;
  const int m = lane & 15, q = lane >> 4;
  const int n0 = blockIdx.y*2, b0 = blockIdx.x*64;

  // phase 1: r1[e][64][512]; enemies staged sequentially through one efl buffer
  for (int e = 0; e < 2; e++){
    const int n = n0 + e;
    __syncthreads();   // protect efl from previous enemy's readers
    for (int idx = t; idx < 64*96; idx += 512){
      int r = idx / 96, d = idx - r*96;
      u16 v = 0;
      if (d < 65) v = f2bf(ldf(ef_g, ((long)n*4096 + b0 + r)*65 + d, fl));
      efl[idx] = (short)v;
    }
    __syncthreads();
    #pragma unroll
    for (int jt4 = 0; jt4 < 4; jt4++){
      const int coln = (w*4 + jt4)*16 + m;
      short8 bfr[3];
      #pragma unroll
      for (int k3 = 0; k3 < 3; k3++)
        bfr[k3] = *(const short8*)(We1T + coln*96 + k3*32 + q*8);
      float be = ldf(be1, coln, fl);
      const int chunk = coln >> 3, sub = coln & 7;
      #pragma unroll
      for (int rt = 0; rt < 4; rt++){
        floatx4 acc = {0.f, 0.f, 0.f, 0.f};
        #pragma unroll
        for (int k3 = 0; k3 < 3; k3++){
          short8 a = *(const short8*)(efl + (rt*16 + m)*96 + k3*32 + q*8);
          acc = MFMA(a, bfr[k3], acc);
        }
        #pragma unroll
        for (int i = 0; i < 4; i++){
          int row = rt*16 + q*4 + i;
          float v = acc[i] + be;
          r1s[e][row*512 + ((chunk ^ (row & 7)) << 3) + sub] = (short)f2bf(v > 0.f ? v : 0.f);
        }
      }
    }
  }
  __syncthreads();

  // phase 2: wave w -> output cols [w*64, w*64+64); each B-frag used 8x (2e x 4rt)
  floatx4 acc[2][4][4] = {};
  for (int kt = 0; kt < 512; kt += 32){
    short8 b[4];
    #pragma unroll
    for (int js = 0; js < 4; js++)
      b[js] = *(const short8*)(WcT + (long)(w*64 + js*16 + m)*512 + kt + q*8);
    const int ch = (((kt >> 3) + q) ^ (m & 7)) << 3;
    #pragma unroll
    for (int e = 0; e < 2; e++){
      #pragma unroll
      for (int rt = 0; rt < 4; rt++){
        short8 a = *(const short8*)(r1s[e] + (rt*16 + m)*512 + ch);
        #pragma unroll
        for (int js = 0; js < 4; js++)
          acc[e][rt][js] = MFMA(a, b[js], acc[e][rt][js]);
      }
    }
  }

  // epilogue: u_b loaded once, shared across both enemies
  float pr[2][4][4] = {};
  #pragma unroll
  for (int js = 0; js < 4; js++){
    int col = w*64 + js*16 + m;
    float wv = ldf(wa2, col, fl);
    #pragma unroll
    for (int rt = 0; rt < 4; rt++){
      #pragma unroll
      for (int i = 0; i < 4; i++){
        int grow = b0 + rt*16 + q*4 + i;
        float u = bf2f(u_b[(long)grow*512 + col]);
        #pragma unroll
        for (int e = 0; e < 2; e++){
          float s = acc[e][rt][js][i] + u;
          pr[e][rt][i] += (s > 0.f ? s : 0.f) * wv;
        }
      }
    }
  }
  #pragma unroll
  for (int o = 1; o < 16; o <<= 1){
    #pragma unroll
    for (int e = 0; e < 2; e++)
      #pragma unroll
      for (int rt = 0; rt < 4; rt++)
        #pragma unroll
        for (int i = 0; i < 4; i++)
          pr[e][rt][i] += __shfl_xor(pr[e][rt][i], o);
  }
  if (m == 0){
    #pragma unroll
    for (int e = 0; e < 2; e++)
      #pragma unroll
      for (int rt = 0; rt < 4; rt++)
        #pragma unroll
        for (int i = 0; i < 4; i++)
          part[e][rt*16 + q*4 + i][w] = pr[e][rt][i];
  }
  __syncthreads();
  if (t < 128){
    int e = t >> 6, r = t & 63;
    float s = ldf(ba2, 0, fl);
    #pragma unroll
    for (int ww = 0; ww < 8; ww++) s += part[e][r][ww];
    out[(long)(b0 + r)*38 + 6 + n0 + e] = s;
  }
}

// ---------------------------------------------------------------------------
extern "C" void kernel_launch(void* const* d_in, const int* in_sizes, int n_in,
                              void* d_out, int out_size, void* d_ws, size_t ws_size,
                              hipStream_t stream)
{
  (void)in_sizes; (void)n_in; (void)out_size; (void)ws_size;
  const void* own  = d_in[0];
  const void* af   = d_in[1];
  const void* ef   = d_in[2];
  const void* hid  = d_in[3];
  const void* Wq   = d_in[4];
  const void* bq   = d_in[5];
  const void* Wak  = d_in[6];
  const void* bak  = d_in[7];
  const void* Wav  = d_in[8];
  const void* Wek  = d_in[10];
  const void* bek  = d_in[11];
  const void* Wev  = d_in[12];
  const void* Wov  = d_in[14];
  const void* w_ih = d_in[16];
  const void* w_hh = d_in[17];
  const void* b_ih = d_in[18];
  const void* b_hh = d_in[19];
  const void* Wwo  = d_in[20];
  const void* bwo  = d_in[21];
  const void* We1  = d_in[22];
  const void* be1  = d_in[23];
  const void* We2  = d_in[24];
  const void* be2  = d_in[25];
  const void* Wa1  = d_in[26];
  const void* ba1  = d_in[27];
  const void* Wa2  = d_in[28];
  const void* ba2  = d_in[29];
  float* out   = (float*)d_out;                 // q [4096,38] f32
  float* h_out = out + (long)4096*38;           // h [4096,512] f32

  // ---- workspace (7.76 MB peak, time-phased aliasing) ----
  char* ws = (char*)d_ws;
  u16*   tot    = (u16*)(ws + 0);               // [4096,768] bf16 = 6,291,456
  u16*   G      = (u16*)(ws + 0);               // [4096,192] bf16 (alias, dead before tot)
  u16*   u_b    = (u16*)(ws + 0);               // [4096,512] bf16 = 4 MB (alias, after gru)
  u16*   Wa1tT  = (u16*)(ws + 4194304);         // [512,512] bf16 (tot region tail, post-gru)
  char*  mz     = ws + 6291456;                 // 1,310,720 multi-phase zone
  u16*   mixbuf = (u16*)mz;                     // [4096,160] bf16 (attention phase)
  u16*   U      = (u16*)mz;                     // [192,128] bf16 (prep phase)
  u16*   WGT    = (u16*)(mz + 49152);           // [192,128] bf16 (prep phase)
  u16*   Wa1bT  = (u16*)mz;                     // [512,512] bf16 (post-gru phase)
  u16*   WcT    = (u16*)(mz + 524288);          // [512,512] bf16 (post-u phase)
  u16*   We1T   = (u16*)(mz + 1048576);         // [512,96]  bf16 (post-gru phase)
  char*  P      = ws + 7602176;                 // persistent small zone
  u16*   WovT   = (u16*)(P + 0);                // [256,128] bf16
  u16*   WavT   = (u16*)(P + 65536);            // [256,64]  bf16
  u16*   WevT   = (u16*)(P + 98304);            // [256,96]  bf16
  float* bc     = (float*)(P + 147456);         // [512] f32
  float* bG     = (float*)(P + 149504);         // [192] f32
  int*   flg    = (int*)(P + 150528);

  detect_kernel<<<1, 256, 0, stream>>>((const u16*)w_ih, flg);

  // prep: fused V-projection transposes + fused U/bG + parallel bc
  transpose3a_kernel<<<dim3(8, 9), 256, 0, stream>>>(Wov, Wav, Wev, WovT, WavT, WevT, flg);
  build_u_bg_kernel<<<192, 128, 0, stream>>>(Wak, bak, Wek, bek, bq, U, bG, flg);
  bc_kernel<<<32, 256, 0, stream>>>(Wa1, be2, ba1, bc, flg);
  // WGT[c,d] = sum_a U[c,a] * Wq[d,a]
  gemm_nk_kernel<<<dim3(3, 2), 256, 0, stream>>>(U, 128, Wq, nullptr, WGT, 128, 0, 128, flg, 0, 1);
  // G = own @ WGT^T + bG   [4096,192]
  gemm_nk_kernel<<<dim3(64, 3), 256, 0, stream>>>(own, 128, WGT, bG, G, 192, 0, 128, flg, 1, 0);
  // attention -> mixbuf (clobbers U/WGT; G still live in tot region)
  attn_kernel<<<1024, 256, 0, stream>>>(G, af, ef, mixbuf, flg);
  // tot = [own@Wov | mix_a@Wav | mix_e@Wev]  (one launch; overwrites G)
  gemm_tot_kernel<<<dim3(64, 4, 3), 256, 0, stream>>>(own, mixbuf, WovT, WavT, WevT, tot, flg);
  // GRU -> h (f32 in d_out)
  gru_kernel<<<dim3(32, 8), 512, 0, stream>>>(tot, hid, w_ih, w_hh, b_ih, b_hh, h_out, flg);
  // fused late transposes (tot + mixbuf dead): Wa1bT@mz, Wa1tT@ws+4MB, We1T
  transpose3b_kernel<<<dim3(16, 35), 256, 0, stream>>>(Wa1, We1, Wa1bT, Wa1tT, We1T, flg);
  // u = h @ Wa1_bot + bc -> u_b (overwrites tot[0:4MB]; Wa1tT at 4MB+ untouched)
  gemm_nk_kernel<<<dim3(64, 8), 256, 0, stream>>>(h_out, 512, Wa1bT, bc, u_b, 512, 0, 512, flg, 2, 0);
  // Wc = We2 @ Wa1_top
  gemm_nk_kernel<<<dim3(8, 8), 256, 0, stream>>>(Wa1tT, 512, We2, nullptr, WcT, 512, 0, 512, flg, 0, 1);
  // heads
  wo_kernel<<<64, 256, 0, stream>>>(h_out, Wwo, bwo, out, flg);
  head_kernel<<<dim3(64, 16), 512, 0, stream>>>(ef, We1T, be1, WcT, u_b, Wa2, ba2, out, flg);
}

// Round 6
// 536.185 us; speedup vs baseline: 1.3996x; 1.0311x over previous
//
#include <hip/hip_runtime.h>

typedef unsigned short u16;
typedef __attribute__((ext_vector_type(8))) short short8;
typedef __attribute__((ext_vector_type(4))) float floatx4;

__device__ inline float bf2f(u16 v){ union { unsigned int i; float f; } u; u.i = ((unsigned int)v) << 16; return u.f; }
__device__ inline u16 f2bf(float f){ union { float ff; unsigned int i; } u; u.ff = f; unsigned int r = u.i + 0x7fffu + ((u.i >> 16) & 1u); return (u16)(r >> 16); }
__device__ inline float sigmf(float x){ return 1.f/(1.f + __expf(-x)); }
__device__ inline float tanhfast(float x){ float e = __expf(-2.f*fabsf(x)); float t = (1.f-e)/(1.f+e); return x>=0.f? t : -t; }
__device__ inline float wred(float x){ for (int o = 32; o; o >>= 1) x += __shfl_xor(x, o); return x; }

// dual-dtype scalar load: fl==1 -> buffer is float32, else bf16(u16)
__device__ inline float ldf(const void* p, long i, int fl){
  return fl ? ((const float*)p)[i] : bf2f(((const u16*)p)[i]);
}
// 8-element load -> bf16 frag. mode: 0=bf16 buffer, 1=follow fl, 2=f32 buffer
__device__ inline short8 ld8m(const void* p, long i, int mode, int fl){
  int isf = (mode == 2) || (mode == 1 && fl);
  if (!isf) return *(const short8*)((const u16*)p + i);
  const float* f = (const float*)p + i;
  float4 x = *(const float4*)f;
  float4 y = *(const float4*)(f + 4);
  short8 r;
  r[0]=(short)f2bf(x.x); r[1]=(short)f2bf(x.y); r[2]=(short)f2bf(x.z); r[3]=(short)f2bf(x.w);
  r[4]=(short)f2bf(y.x); r[5]=(short)f2bf(y.y); r[6]=(short)f2bf(y.z); r[7]=(short)f2bf(y.w);
  return r;
}

#define MFMA(a,b,c) __builtin_amdgcn_mfma_f32_16x16x32_bf16(a,b,c,0,0,0)

// ---------------------------------------------------------------------------
__global__ void detect_kernel(const u16* __restrict__ w, int* __restrict__ flag){
  __shared__ int cnt[256];
  int t = threadIdx.x, c = 0;
  for (int i = t; i < 4096; i += 256){ u16 v = w[i]; if ((v & 0x7fff) >= 0x4200) c++; }
  cnt[t] = c; __syncthreads();
  for (int s = 128; s; s >>= 1){ if (t < s) cnt[t] += cnt[t + s]; __syncthreads(); }
  if (t == 0) *flag = (cnt[0] > 16) ? 1 : 0;
}

// ---------------------------------------------------------------------------
// shared transpose tile body: out[n][k] = (k<K)? in[ro+k][n] : 0
__device__ inline void tbody(float (*tile)[33], const void* in, int ldin, int ro,
                             int K, int N, int Kpad, u16* out, int fl, int k0, int n0)
{
  int tx = threadIdx.x & 31, ty = threadIdx.x >> 5;   // 32 x 8
  for (int i = ty; i < 32; i += 8){
    int k = k0 + i, n = n0 + tx;
    tile[i][tx] = (k < K && n < N) ? ldf(in, (long)(ro + k)*ldin + n, fl) : 0.f;
  }
  __syncthreads();
  for (int i = ty; i < 32; i += 8){
    int n = n0 + i, k = k0 + tx;
    if (n < N && k < Kpad) out[(long)n*Kpad + k] = f2bf(tile[tx][i]);
  }
}

// early fused transpose: Wov (y<4), Wav (y<6), Wev (else). grid (8,9)
__global__ __launch_bounds__(256) void transpose3a_kernel(
    const void* __restrict__ Wov, const void* __restrict__ Wav, const void* __restrict__ Wev,
    u16* __restrict__ WovT, u16* __restrict__ WavT, u16* __restrict__ WevT,
    const int* __restrict__ flg)
{
  const int fl = *flg;
  __shared__ float tile[32][33];
  int y = blockIdx.y, n0 = blockIdx.x*32;
  if (y < 4)      tbody(tile, Wov, 256, 0, 128, 256, 128, WovT, fl, y*32, n0);
  else if (y < 6) tbody(tile, Wav, 256, 0,  64, 256,  64, WavT, fl, (y-4)*32, n0);
  else            tbody(tile, Wev, 256, 0,  65, 256,  96, WevT, fl, (y-6)*32, n0);
}

// late fused transpose + wo head: Wa1 bottom (y<16), Wa1 top (y<32),
// We1 (y<35), wo out[:,0:6] (y in [35,39)). grid (16,39); runs after gru.
__global__ __launch_bounds__(256) void transpose3b_kernel(
    const void* __restrict__ Wa1, const void* __restrict__ We1,
    u16* __restrict__ Wa1bT, u16* __restrict__ Wa1tT, u16* __restrict__ We1T,
    const float* __restrict__ h, const void* __restrict__ Wwo,
    const void* __restrict__ bwo, float* __restrict__ out,
    const int* __restrict__ flg)
{
  const int fl = *flg;
  __shared__ float tile[32][33];
  int y = blockIdx.y, n0 = blockIdx.x*32;
  if (y < 16)      tbody(tile, Wa1, 512, 512, 512, 512, 512, Wa1bT, fl, y*32, n0);
  else if (y < 32) tbody(tile, Wa1, 512, 0,   512, 512, 512, Wa1tT, fl, (y-16)*32, n0);
  else if (y < 35) tbody(tile, We1, 512, 0,    65, 512,  96, We1T,  fl, (y-32)*32, n0);
  else {
    // ---- fused wo (R0-proven body): out[:,0:6] = h @ Wwo + bwo ----
    __shared__ float red[64][4][6];
    const int t = threadIdx.x, r = t >> 2, kq = t & 3;
    const long b = (long)((y - 35)*16 + blockIdx.x)*64 + r;
    float acc[6] = {};
    for (int k = kq*128; k < kq*128 + 128; k++){
      float hv = h[b*512 + k];
      #pragma unroll
      for (int j = 0; j < 6; j++) acc[j] = fmaf(hv, ldf(Wwo, (long)k*6 + j, fl), acc[j]);
    }
    #pragma unroll
    for (int j = 0; j < 6; j++) red[r][kq][j] = acc[j];
    __syncthreads();
    if (kq == 0){
      #pragma unroll
      for (int j = 0; j < 6; j++)
        out[b*38 + j] = red[r][0][j] + red[r][1][j] + red[r][2][j] + red[r][3][j] + ldf(bwo, j, fl);
    }
  }
}

// ---------------------------------------------------------------------------
// U [192,128] bf16 rows: 0..63=Wak, 64=bak, 65..129=Wek, 130=bek, rest 0.
// Fused bG[c] = bq . U[c,:] reduction (same bf16-rounded values as before).
// grid 192 x 128 thr.
__global__ __launch_bounds__(128) void build_u_bg_kernel(
    const void* __restrict__ Wak, const void* __restrict__ bak,
    const void* __restrict__ Wek, const void* __restrict__ bek,
    const void* __restrict__ bq, u16* __restrict__ U, float* __restrict__ bG,
    const int* __restrict__ flg)
{
  const int fl = *flg;
  __shared__ float pp[2];
  int c = blockIdx.x, a = threadIdx.x;
  float v = 0.f;
  if (c < 64)       v = ldf(Wak, (long)c*128 + a, fl);
  else if (c == 64) v = ldf(bak, a, fl);
  else if (c < 130) v = ldf(Wek, (long)(c-65)*128 + a, fl);
  else if (c == 130) v = ldf(bek, a, fl);
  u16 vb = f2bf(v);
  U[c*128 + a] = vb;
  float p = ldf(bq, a, fl) * bf2f(vb);   // match original bg numerics (rounded U)
  p = wred(p);
  if ((a & 63) == 0) pp[a >> 6] = p;
  __syncthreads();
  if (a == 0) bG[c] = pp[0] + pp[1];
}

// bc[j] = ba1[j] + sum_c be2[c] * Wa1[c, j]  (top half of Wa1)
// 32 blocks x 256 thr: block owns 16 j-cols, 16-way c-slice reduction.
__global__ __launch_bounds__(256) void bc_kernel(
    const void* __restrict__ Wa1, const void* __restrict__ be2,
    const void* __restrict__ ba1, float* __restrict__ bc,
    const int* __restrict__ flg)
{
  const int fl = *flg;
  __shared__ float red[16][17];
  const int t = threadIdx.x;
  const int jj = t & 15, cs = t >> 4;
  const int j = blockIdx.x*16 + jj;
  float acc = 0.f;
  for (int c = cs*32; c < cs*32 + 32; c++)
    acc = fmaf(ldf(be2, c, fl), ldf(Wa1, (long)c*512 + j, fl), acc);
  red[jj][cs] = acc;
  __syncthreads();
  if (t < 16){
    float s = ldf(ba1, blockIdx.x*16 + t, fl);
    #pragma unroll
    for (int k = 0; k < 16; k++) s += red[t][k];
    bc[blockIdx.x*16 + t] = s;
  }
}

// ---------------------------------------------------------------------------
// Generic MFMA GEMM: out[r, ocol+col] = A[M,K(lda)] @ B[N,K]^T + bias, bf16 out
__global__ __launch_bounds__(256) void gemm_nk_kernel(
    const void* __restrict__ A, int lda, const void* __restrict__ Bm,
    const float* __restrict__ bias, u16* __restrict__ outp, int ldout, int ocol,
    int K, const int* __restrict__ flg, int amode, int bmode)
{
  const int fl = *flg;
  __shared__ __align__(16) short Al[64*32];
  __shared__ __align__(16) short Bl[64*32];
  const int t = threadIdx.x, lane = t & 63, w = t >> 6;
  const int m0 = blockIdx.x*64, n0 = blockIdx.y*64;
  floatx4 acc[4] = {};
  const int row = t >> 2, seg = t & 3;
  for (int kt = 0; kt < K; kt += 32){
    __syncthreads();
    *(short8*)(Al + row*32 + seg*8) = ld8m(A,  (long)(m0 + row)*lda + kt + seg*8, amode, fl);
    *(short8*)(Bl + row*32 + seg*8) = ld8m(Bm, (long)(n0 + row)*K   + kt + seg*8, bmode, fl);
    __syncthreads();
    short8 a = *(const short8*)(Al + (w*16 + (lane & 15))*32 + ((lane >> 4)*8));
    #pragma unroll
    for (int nt = 0; nt < 4; nt++){
      short8 b = *(const short8*)(Bl + (nt*16 + (lane & 15))*32 + ((lane >> 4)*8));
      acc[nt] = MFMA(a, b, acc[nt]);
    }
  }
  #pragma unroll
  for (int nt = 0; nt < 4; nt++){
    int col = n0 + nt*16 + (lane & 15);
    float bb = bias ? bias[col] : 0.f;
    #pragma unroll
    for (int i = 0; i < 4; i++){
      int r = m0 + w*16 + (lane >> 4)*4 + i;
      outp[(long)r*ldout + ocol + col] = f2bf(acc[nt][i] + bb);
    }
  }
}

// fused tot builder: z=0 own@WovT (K=128), z=1 mixa@WavT (K=64), z=2 mixe@WevT (K=96)
// grid (64,4,3); saves 2 serial launches and overlaps tails.
__global__ __launch_bounds__(256) void gemm_tot_kernel(
    const void* __restrict__ own, const u16* __restrict__ mixbuf,
    const u16* __restrict__ WovT, const u16* __restrict__ WavT, const u16* __restrict__ WevT,
    u16* __restrict__ tot, const int* __restrict__ flg)
{
  const int fl = *flg;
  __shared__ __align__(16) short Al[64*32];
  __shared__ __align__(16) short Bl[64*32];
  const void* A; const u16* Bm; int lda, K, ocol, amode;
  if (blockIdx.z == 0){ A = own;         lda = 128; Bm = WovT; K = 128; ocol = 0;   amode = 1; }
  else if (blockIdx.z == 1){ A = mixbuf; lda = 160; Bm = WavT; K = 64;  ocol = 256; amode = 0; }
  else { A = mixbuf + 64;                lda = 160; Bm = WevT; K = 96;  ocol = 512; amode = 0; }
  const int t = threadIdx.x, lane = t & 63, w = t >> 6;
  const int m0 = blockIdx.x*64, n0 = blockIdx.y*64;
  floatx4 acc[4] = {};
  const int row = t >> 2, seg = t & 3;
  for (int kt = 0; kt < K; kt += 32){
    __syncthreads();
    *(short8*)(Al + row*32 + seg*8) = ld8m(A,  (long)(m0 + row)*lda + kt + seg*8, amode, fl);
    *(short8*)(Bl + row*32 + seg*8) = *(const short8*)(Bm + (long)(n0 + row)*K + kt + seg*8);
    __syncthreads();
    short8 a = *(const short8*)(Al + (w*16 + (lane & 15))*32 + ((lane >> 4)*8));
    #pragma unroll
    for (int nt = 0; nt < 4; nt++){
      short8 b = *(const short8*)(Bl + (nt*16 + (lane & 15))*32 + ((lane >> 4)*8));
      acc[nt] = MFMA(a, b, acc[nt]);
    }
  }
  #pragma unroll
  for (int nt = 0; nt < 4; nt++){
    int col = n0 + nt*16 + (lane & 15);
    #pragma unroll
    for (int i = 0; i < 4; i++){
      int r = m0 + w*16 + (lane >> 4)*4 + i;
      tot[(long)r*768 + ocol + col] = f2bf(acc[nt][i]);
    }
  }
}

// ---------------------------------------------------------------------------
// Attention: one wave per batch row. G[b,0:64]=qka, 64=sa, 65:130=qke, 130=se.
// af/ef row values register-cached between energy and weighted passes
// (fva[31]/fve[32], fully-unrolled loops -> static reg indices): removes the
// second ~66MB read + its dependent-load chain. Numerics identical.
__global__ __launch_bounds__(256) void attn_kernel(
    const u16* __restrict__ G, const void* __restrict__ af, const void* __restrict__ ef,
    u16* __restrict__ mixbuf, const int* __restrict__ flg)
{
  const int fl = *flg;
  __shared__ float gsh[4][192];
  __shared__ float attw[4][32];
  const int lane = threadIdx.x & 63, wv = threadIdx.x >> 6;
  const long b = blockIdx.x*4 + wv;
  const float rsA = 0.08838834764831845f;  // 1/sqrt(128)

  for (int c = lane; c < 192; c += 64) gsh[wv][c] = bf2f(G[b*192 + c]);
  __syncthreads();

  // ---- allies ----
  float qa = gsh[wv][lane];
  float sa = gsh[wv][64];
  float fva[31];
  float myE = -1e30f;
  #pragma unroll
  for (int n = 0; n < 31; n++){
    fva[n] = ldf(af, ((long)n*4096 + b)*64 + lane, fl);
    float e = wred(fva[n] * qa);
    e = (e + sa) * rsA;
    if (lane == n) myE = e;
  }
  {
    float m = myE;
    for (int o = 32; o; o >>= 1) m = fmaxf(m, __shfl_xor(m, o));
    float p = (lane < 31) ? __expf(myE - m) : 0.f;
    float s = wred(p);
    if (lane < 32) attw[wv][lane] = p / s;
  }
  __syncthreads();
  {
    float acc = 0.f;
    #pragma unroll
    for (int n = 0; n < 31; n++)
      acc = fmaf(attw[wv][n], fva[n], acc);
    mixbuf[b*160 + lane] = f2bf(acc);
  }
  __syncthreads();

  // ---- enemies (65 dims) ----
  float qe = gsh[wv][65 + lane];
  float qe64 = gsh[wv][129];
  float se = gsh[wv][130];
  float fve[32];
  myE = -1e30f;
  #pragma unroll
  for (int n = 0; n < 32; n++){
    long base = ((long)n*4096 + b)*65;
    fve[n] = ldf(ef, base + lane, fl);
    float prod = fve[n] * qe;
    if (lane == 0) prod = fmaf(ldf(ef, base + 64, fl), qe64, prod);
    float e = (wred(prod) + se) * rsA;
    if (lane == n) myE = e;
  }
  {
    float m = myE;
    for (int o = 32; o; o >>= 1) m = fmaxf(m, __shfl_xor(m, o));
    float p = (lane < 32) ? __expf(myE - m) : 0.f;
    float s = wred(p);
    if (lane < 32) attw[wv][lane] = p / s;
  }
  __syncthreads();
  {
    float acc = 0.f, acc64 = 0.f;
    #pragma unroll
    for (int n = 0; n < 32; n++){
      long base = ((long)n*4096 + b)*65;
      float w = attw[wv][n];
      acc = fmaf(w, fve[n], acc);
      if (lane == 0) acc64 = fmaf(w, ldf(ef, base + 64, fl), acc64);
    }
    mixbuf[b*160 + 64 + lane] = f2bf(acc);
    if (lane == 0) mixbuf[b*160 + 128] = f2bf(acc64);
    if (lane >= 1 && lane < 32) mixbuf[b*160 + 128 + lane] = 0;
  }
}

// ---------------------------------------------------------------------------
// GRU: block = 128 batch rows x 64 hidden cols (512 thr); h (f32) -> d_out.
// 1-D grid of 256 with XCD swizzle: j0 = (bid&7)*64 so all blocks sharing a
// j-panel land on one XCD (round-robin %8 dispatch) -> per-XCD weight
// footprint ~1MB (L2-hot) instead of all 7.8MB f32 weights streamed by every
// XCD (natural layout had XCD = b%8: every XCD touched every panel).
__global__ __launch_bounds__(512) void gru_kernel(
    const u16* __restrict__ tot, const void* __restrict__ hprev,
    const void* __restrict__ w_ih, const void* __restrict__ w_hh,
    const void* __restrict__ b_ih, const void* __restrict__ b_hh,
    float* __restrict__ h_out, const int* __restrict__ flg)
{
  const int fl = *flg;
  __shared__ __align__(16) short At[128*32], Ah[128*32];
  __shared__ __align__(16) short Bi[3][64*32], Bh[3][64*32];
  const int t = threadIdx.x, lane = t & 63, w = t >> 6;
  const int bid = blockIdx.x;
  const int b0 = (bid >> 3)*128, j0 = (bid & 7)*64;
  floatx4 ai[3][4] = {}; floatx4 ah[3][4] = {};
  const int row = t >> 2, seg = t & 3;
  for (int kt = 0; kt < 768; kt += 32){
    __syncthreads();
    *(short8*)(At + row*32 + seg*8) = *(const short8*)(tot + (long)(b0 + row)*768 + kt + seg*8);
    if (kt < 512)
      *(short8*)(Ah + row*32 + seg*8) = ld8m(hprev, (long)(b0 + row)*512 + kt + seg*8, 1, fl);
    if (t < 256){
      int rb = t >> 2, sb = t & 3;
      #pragma unroll
      for (int p = 0; p < 3; p++)
        *(short8*)(Bi[p] + rb*32 + sb*8) = ld8m(w_ih, (long)(p*512 + j0 + rb)*768 + kt + sb*8, 1, fl);
    } else if (kt < 512){
      int t2 = t - 256, rb = t2 >> 2, sb = t2 & 3;
      #pragma unroll
      for (int p = 0; p < 3; p++)
        *(short8*)(Bh[p] + rb*32 + sb*8) = ld8m(w_hh, (long)(p*512 + j0 + rb)*512 + kt + sb*8, 1, fl);
    }
    __syncthreads();
    short8 a = *(const short8*)(At + (w*16 + (lane & 15))*32 + ((lane >> 4)*8));
    #pragma unroll
    for (int p = 0; p < 3; p++){
      #pragma unroll
      for (int nt = 0; nt < 4; nt++){
        short8 b = *(const short8*)(Bi[p] + (nt*16 + (lane & 15))*32 + ((lane >> 4)*8));
        ai[p][nt] = MFMA(a, b, ai[p][nt]);
      }
    }
    if (kt < 512){
      short8 a2 = *(const short8*)(Ah + (w*16 + (lane & 15))*32 + ((lane >> 4)*8));
      #pragma unroll
      for (int p = 0; p < 3; p++){
        #pragma unroll
        for (int nt = 0; nt < 4; nt++){
          short8 b = *(const short8*)(Bh[p] + (nt*16 + (lane & 15))*32 + ((lane >> 4)*8));
          ah[p][nt] = MFMA(a2, b, ah[p][nt]);
        }
      }
    }
  }
  #pragma unroll
  for (int nt = 0; nt < 4; nt++){
    int colH = j0 + nt*16 + (lane & 15);
    float bir = ldf(b_ih, colH, fl),        bhr = ldf(b_hh, colH, fl);
    float biz = ldf(b_ih, 512 + colH, fl),  bhz = ldf(b_hh, 512 + colH, fl);
    float bin = ldf(b_ih, 1024 + colH, fl), bhn = ldf(b_hh, 1024 + colH, fl);
    #pragma unroll
    for (int i = 0; i < 4; i++){
      int r = b0 + w*16 + (lane >> 4)*4 + i;
      float rg = sigmf(ai[0][nt][i] + bir + ah[0][nt][i] + bhr);
      float zg = sigmf(ai[1][nt][i] + biz + ah[1][nt][i] + bhz);
      float ng = tanhfast(ai[2][nt][i] + bin + rg*(ah[2][nt][i] + bhn));
      float hp = ldf(hprev, (long)r*512 + colH, fl);
      h_out[(long)r*512 + colH] = (1.f - zg)*ng + zg*hp;
    }
  }
}

// ---------------------------------------------------------------------------
// Head: EXACT R0 body (measured 154.5us). Block = (64 b-rows, TWO enemies
// n0,n0+1). r1 for both enemies in XOR-swizzled LDS; phase 2 streams each
// WcT B-frag once and uses it for both enemies; u_b loaded once per output
// element and shared across enemies. Occupancy is pinned at 2 waves/SIMD by
// the unified reg file (120 arch + 128 acc = 248); R1-R4 proved all
// restructures to raise it regress (spills or lost B-reuse). Do not touch.
__global__ __launch_bounds__(512) void head_kernel(
    const void* __restrict__ ef_g, const u16* __restrict__ We1T,
    const void* __restrict__ be1, const u16* __restrict__ WcT,
    const u16* __restrict__ u_b, const void* __restrict__ wa2,
    const void* __restrict__ ba2, float* __restrict__ out, const int* __restrict__ flg)
{
  const int fl = *flg;
  __shared__ __align__(16) short r1s[2][64*512];  // XOR-swizzled: (row, chunk^(row&7))
  __shared__ __align__(16) short efl[64*96];
  __shared__ float part[2][64][9];
  const int t = threadIdx.x, lane = t & 63, w = t >> 6;
  const int m = lane & 15, q = lane >> 4;
  const int n0 = blockIdx.y*2, b0 = blockIdx.x*64;

  // phase 1: r1[e][64][512]; enemies staged sequentially through one efl buffer
  for (int e = 0; e < 2; e++){
    const int n = n0 + e;
    __syncthreads();   // protect efl from previous enemy's readers
    for (int idx = t; idx < 64*96; idx += 512){
      int r = idx / 96, d = idx - r*96;
      u16 v = 0;
      if (d < 65) v = f2bf(ldf(ef_g, ((long)n*4096 + b0 + r)*65 + d, fl));
      efl[idx] = (short)v;
    }
    __syncthreads();
    #pragma unroll
    for (int jt4 = 0; jt4 < 4; jt4++){
      const int coln = (w*4 + jt4)*16 + m;
      short8 bfr[3];
      #pragma unroll
      for (int k3 = 0; k3 < 3; k3++)
        bfr[k3] = *(const short8*)(We1T + coln*96 + k3*32 + q*8);
      float be = ldf(be1, coln, fl);
      const int chunk = coln >> 3, sub = coln & 7;
      #pragma unroll
      for (int rt = 0; rt < 4; rt++){
        floatx4 acc = {0.f, 0.f, 0.f, 0.f};
        #pragma unroll
        for (int k3 = 0; k3 < 3; k3++){
          short8 a = *(const short8*)(efl + (rt*16 + m)*96 + k3*32 + q*8);
          acc = MFMA(a, bfr[k3], acc);
        }
        #pragma unroll
        for (int i = 0; i < 4; i++){
          int row = rt*16 + q*4 + i;
          float v = acc[i] + be;
          r1s[e][row*512 + ((chunk ^ (row & 7)) << 3) + sub] = (short)f2bf(v > 0.f ? v : 0.f);
        }
      }
    }
  }
  __syncthreads();

  // phase 2: wave w -> output cols [w*64, w*64+64); each B-frag used 8x (2e x 4rt)
  floatx4 acc[2][4][4] = {};
  for (int kt = 0; kt < 512; kt += 32){
    short8 b[4];
    #pragma unroll
    for (int js = 0; js < 4; js++)
      b[js] = *(const short8*)(WcT + (long)(w*64 + js*16 + m)*512 + kt + q*8);
    const int ch = (((kt >> 3) + q) ^ (m & 7)) << 3;
    #pragma unroll
    for (int e = 0; e < 2; e++){
      #pragma unroll
      for (int rt = 0; rt < 4; rt++){
        short8 a = *(const short8*)(r1s[e] + (rt*16 + m)*512 + ch);
        #pragma unroll
        for (int js = 0; js < 4; js++)
          acc[e][rt][js] = MFMA(a, b[js], acc[e][rt][js]);
      }
    }
  }

  // epilogue: u_b loaded once, shared across both enemies
  float pr[2][4][4] = {};
  #pragma unroll
  for (int js = 0; js < 4; js++){
    int col = w*64 + js*16 + m;
    float wv = ldf(wa2, col, fl);
    #pragma unroll
    for (int rt = 0; rt < 4; rt++){
      #pragma unroll
      for (int i = 0; i < 4; i++){
        int grow = b0 + rt*16 + q*4 + i;
        float u = bf2f(u_b[(long)grow*512 + col]);
        #pragma unroll
        for (int e = 0; e < 2; e++){
          float s = acc[e][rt][js][i] + u;
          pr[e][rt][i] += (s > 0.f ? s : 0.f) * wv;
        }
      }
    }
  }
  #pragma unroll
  for (int o = 1; o < 16; o <<= 1){
    #pragma unroll
    for (int e = 0; e < 2; e++)
      #pragma unroll
      for (int rt = 0; rt < 4; rt++)
        #pragma unroll
        for (int i = 0; i < 4; i++)
          pr[e][rt][i] += __shfl_xor(pr[e][rt][i], o);
  }
  if (m == 0){
    #pragma unroll
    for (int e = 0; e < 2; e++)
      #pragma unroll
      for (int rt = 0; rt < 4; rt++)
        #pragma unroll
        for (int i = 0; i < 4; i++)
          part[e][rt*16 + q*4 + i][w] = pr[e][rt][i];
  }
  __syncthreads();
  if (t < 128){
    int e = t >> 6, r = t & 63;
    float s = ldf(ba2, 0, fl);
    #pragma unroll
    for (int ww = 0; ww < 8; ww++) s += part[e][r][ww];
    out[(long)(b0 + r)*38 + 6 + n0 + e] = s;
  }
}

// ---------------------------------------------------------------------------
extern "C" void kernel_launch(void* const* d_in, const int* in_sizes, int n_in,
                              void* d_out, int out_size, void* d_ws, size_t ws_size,
                              hipStream_t stream)
{
  (void)in_sizes; (void)n_in; (void)out_size; (void)ws_size;
  const void* own  = d_in[0];
  const void* af   = d_in[1];
  const void* ef   = d_in[2];
  const void* hid  = d_in[3];
  const void* Wq   = d_in[4];
  const void* bq   = d_in[5];
  const void* Wak  = d_in[6];
  const void* bak  = d_in[7];
  const void* Wav  = d_in[8];
  const void* Wek  = d_in[10];
  const void* bek  = d_in[11];
  const void* Wev  = d_in[12];
  const void* Wov  = d_in[14];
  const void* w_ih = d_in[16];
  const void* w_hh = d_in[17];
  const void* b_ih = d_in[18];
  const void* b_hh = d_in[19];
  const void* Wwo  = d_in[20];
  const void* bwo  = d_in[21];
  const void* We1  = d_in[22];
  const void* be1  = d_in[23];
  const void* We2  = d_in[24];
  const void* be2  = d_in[25];
  const void* Wa1  = d_in[26];
  const void* ba1  = d_in[27];
  const void* Wa2  = d_in[28];
  const void* ba2  = d_in[29];
  float* out   = (float*)d_out;                 // q [4096,38] f32
  float* h_out = out + (long)4096*38;           // h [4096,512] f32

  // ---- workspace (7.76 MB peak, time-phased aliasing) ----
  char* ws = (char*)d_ws;
  u16*   tot    = (u16*)(ws + 0);               // [4096,768] bf16 = 6,291,456
  u16*   G      = (u16*)(ws + 0);               // [4096,192] bf16 (alias, dead before tot)
  u16*   u_b    = (u16*)(ws + 0);               // [4096,512] bf16 = 4 MB (alias, after gru)
  u16*   Wa1tT  = (u16*)(ws + 4194304);         // [512,512] bf16 (tot region tail, post-gru)
  char*  mz     = ws + 6291456;                 // 1,310,720 multi-phase zone
  u16*   mixbuf = (u16*)mz;                     // [4096,160] bf16 (attention phase)
  u16*   U      = (u16*)mz;                     // [192,128] bf16 (prep phase)
  u16*   WGT    = (u16*)(mz + 49152);           // [192,128] bf16 (prep phase)
  u16*   Wa1bT  = (u16*)mz;                     // [512,512] bf16 (post-gru phase)
  u16*   WcT    = (u16*)(mz + 524288);          // [512,512] bf16 (post-u phase)
  u16*   We1T   = (u16*)(mz + 1048576);         // [512,96]  bf16 (post-gru phase)
  char*  P      = ws + 7602176;                 // persistent small zone
  u16*   WovT   = (u16*)(P + 0);                // [256,128] bf16
  u16*   WavT   = (u16*)(P + 65536);            // [256,64]  bf16
  u16*   WevT   = (u16*)(P + 98304);            // [256,96]  bf16
  float* bc     = (float*)(P + 147456);         // [512] f32
  float* bG     = (float*)(P + 149504);         // [192] f32
  int*   flg    = (int*)(P + 150528);

  detect_kernel<<<1, 256, 0, stream>>>((const u16*)w_ih, flg);

  // prep: fused V-projection transposes + fused U/bG + parallel bc
  transpose3a_kernel<<<dim3(8, 9), 256, 0, stream>>>(Wov, Wav, Wev, WovT, WavT, WevT, flg);
  build_u_bg_kernel<<<192, 128, 0, stream>>>(Wak, bak, Wek, bek, bq, U, bG, flg);
  bc_kernel<<<32, 256, 0, stream>>>(Wa1, be2, ba1, bc, flg);
  // WGT[c,d] = sum_a U[c,a] * Wq[d,a]
  gemm_nk_kernel<<<dim3(3, 2), 256, 0, stream>>>(U, 128, Wq, nullptr, WGT, 128, 0, 128, flg, 0, 1);
  // G = own @ WGT^T + bG   [4096,192]
  gemm_nk_kernel<<<dim3(64, 3), 256, 0, stream>>>(own, 128, WGT, bG, G, 192, 0, 128, flg, 1, 0);
  // attention -> mixbuf (clobbers U/WGT; G still live in tot region)
  attn_kernel<<<1024, 256, 0, stream>>>(G, af, ef, mixbuf, flg);
  // tot = [own@Wov | mix_a@Wav | mix_e@Wev]  (one launch; overwrites G)
  gemm_tot_kernel<<<dim3(64, 4, 3), 256, 0, stream>>>(own, mixbuf, WovT, WavT, WevT, tot, flg);
  // GRU -> h (f32 in d_out); 1-D grid, XCD-swizzled (j = bid&7)
  gru_kernel<<<256, 512, 0, stream>>>(tot, hid, w_ih, w_hh, b_ih, b_hh, h_out, flg);
  // fused late transposes + wo head (tot + mixbuf dead): Wa1bT@mz, Wa1tT@ws+4MB, We1T
  transpose3b_kernel<<<dim3(16, 39), 256, 0, stream>>>(Wa1, We1, Wa1bT, Wa1tT, We1T,
                                                       h_out, Wwo, bwo, out, flg);
  // u = h @ Wa1_bot + bc -> u_b (overwrites tot[0:4MB]; Wa1tT at 4MB+ untouched)
  gemm_nk_kernel<<<dim3(64, 8), 256, 0, stream>>>(h_out, 512, Wa1bT, bc, u_b, 512, 0, 512, flg, 2, 0);
  // Wc = We2 @ Wa1_top
  gemm_nk_kernel<<<dim3(8, 8), 256, 0, stream>>>(Wa1tT, 512, We2, nullptr, WcT, 512, 0, 512, flg, 0, 1);
  // heads
  head_kernel<<<dim3(64, 16), 512, 0, stream>>>(ef, We1T, be1, WcT, u_b, Wa2, ba2, out, flg);
}

// Round 7
// 524.944 us; speedup vs baseline: 1.4296x; 1.0214x over previous
//
#include <hip/hip_runtime.h>

typedef unsigned short u16;
typedef __attribute__((ext_vector_type(8))) short short8;
typedef __attribute__((ext_vector_type(4))) float floatx4;

__device__ inline float bf2f(u16 v){ union { unsigned int i; float f; } u; u.i = ((unsigned int)v) << 16; return u.f; }
__device__ inline u16 f2bf(float f){ union { float ff; unsigned int i; } u; u.ff = f; unsigned int r = u.i + 0x7fffu + ((u.i >> 16) & 1u); return (u16)(r >> 16); }
__device__ inline float sigmf(float x){ return 1.f/(1.f + __expf(-x)); }
__device__ inline float tanhfast(float x){ float e = __expf(-2.f*fabsf(x)); float t = (1.f-e)/(1.f+e); return x>=0.f? t : -t; }
__device__ inline float wred(float x){ for (int o = 32; o; o >>= 1) x += __shfl_xor(x, o); return x; }
__device__ inline float hred32(float x){ for (int o = 16; o; o >>= 1) x += __shfl_xor(x, o); return x; }

// dual-dtype scalar load: fl==1 -> buffer is float32, else bf16(u16)
__device__ inline float ldf(const void* p, long i, int fl){
  return fl ? ((const float*)p)[i] : bf2f(((const u16*)p)[i]);
}
// paired load at EVEN index (alignment guaranteed by caller)
__device__ inline float2 ldf2(const void* p, long i, int fl){
  if (fl) return *(const float2*)((const float*)p + i);
  unsigned int v = *(const unsigned int*)((const u16*)p + i);
  float2 r; r.x = bf2f((u16)(v & 0xffffu)); r.y = bf2f((u16)(v >> 16)); return r;
}
// 8-element load -> bf16 frag. mode: 0=bf16 buffer, 1=follow fl, 2=f32 buffer
__device__ inline short8 ld8m(const void* p, long i, int mode, int fl){
  int isf = (mode == 2) || (mode == 1 && fl);
  if (!isf) return *(const short8*)((const u16*)p + i);
  const float* f = (const float*)p + i;
  float4 x = *(const float4*)f;
  float4 y = *(const float4*)(f + 4);
  short8 r;
  r[0]=(short)f2bf(x.x); r[1]=(short)f2bf(x.y); r[2]=(short)f2bf(x.z); r[3]=(short)f2bf(x.w);
  r[4]=(short)f2bf(y.x); r[5]=(short)f2bf(y.y); r[6]=(short)f2bf(y.z); r[7]=(short)f2bf(y.w);
  return r;
}

#define MFMA(a,b,c) __builtin_amdgcn_mfma_f32_16x16x32_bf16(a,b,c,0,0,0)

// ---------------------------------------------------------------------------
__global__ void detect_kernel(const u16* __restrict__ w, int* __restrict__ flag){
  __shared__ int cnt[256];
  int t = threadIdx.x, c = 0;
  for (int i = t; i < 4096; i += 256){ u16 v = w[i]; if ((v & 0x7fff) >= 0x4200) c++; }
  cnt[t] = c; __syncthreads();
  for (int s = 128; s; s >>= 1){ if (t < s) cnt[t] += cnt[t + s]; __syncthreads(); }
  if (t == 0) *flag = (cnt[0] > 16) ? 1 : 0;
}

// ---------------------------------------------------------------------------
// shared transpose tile body: out[n][k] = (k<K)? in[ro+k][n] : 0
__device__ inline void tbody(float (*tile)[33], const void* in, int ldin, int ro,
                             int K, int N, int Kpad, u16* out, int fl, int k0, int n0)
{
  int tx = threadIdx.x & 31, ty = threadIdx.x >> 5;   // 32 x 8
  for (int i = ty; i < 32; i += 8){
    int k = k0 + i, n = n0 + tx;
    tile[i][tx] = (k < K && n < N) ? ldf(in, (long)(ro + k)*ldin + n, fl) : 0.f;
  }
  __syncthreads();
  for (int i = ty; i < 32; i += 8){
    int n = n0 + i, k = k0 + tx;
    if (n < N && k < Kpad) out[(long)n*Kpad + k] = f2bf(tile[tx][i]);
  }
}

// early fused transpose: Wov (y<4), Wav (y<6), Wev (else). grid (8,9)
__global__ __launch_bounds__(256) void transpose3a_kernel(
    const void* __restrict__ Wov, const void* __restrict__ Wav, const void* __restrict__ Wev,
    u16* __restrict__ WovT, u16* __restrict__ WavT, u16* __restrict__ WevT,
    const int* __restrict__ flg)
{
  const int fl = *flg;
  __shared__ float tile[32][33];
  int y = blockIdx.y, n0 = blockIdx.x*32;
  if (y < 4)      tbody(tile, Wov, 256, 0, 128, 256, 128, WovT, fl, y*32, n0);
  else if (y < 6) tbody(tile, Wav, 256, 0,  64, 256,  64, WavT, fl, (y-4)*32, n0);
  else            tbody(tile, Wev, 256, 0,  65, 256,  96, WevT, fl, (y-6)*32, n0);
}

// late fused transpose + wo head: Wa1 bottom (y<16), Wa1 top (y<32),
// We1 (y<35), wo out[:,0:6] (y in [35,39)). grid (16,39); runs after gru.
__global__ __launch_bounds__(256) void transpose3b_kernel(
    const void* __restrict__ Wa1, const void* __restrict__ We1,
    u16* __restrict__ Wa1bT, u16* __restrict__ Wa1tT, u16* __restrict__ We1T,
    const float* __restrict__ h, const void* __restrict__ Wwo,
    const void* __restrict__ bwo, float* __restrict__ out,
    const int* __restrict__ flg)
{
  const int fl = *flg;
  __shared__ float tile[32][33];
  int y = blockIdx.y, n0 = blockIdx.x*32;
  if (y < 16)      tbody(tile, Wa1, 512, 512, 512, 512, 512, Wa1bT, fl, y*32, n0);
  else if (y < 32) tbody(tile, Wa1, 512, 0,   512, 512, 512, Wa1tT, fl, (y-16)*32, n0);
  else if (y < 35) tbody(tile, We1, 512, 0,    65, 512,  96, We1T,  fl, (y-32)*32, n0);
  else {
    // ---- fused wo (R0-proven body): out[:,0:6] = h @ Wwo + bwo ----
    __shared__ float red[64][4][6];
    const int t = threadIdx.x, r = t >> 2, kq = t & 3;
    const long b = (long)((y - 35)*16 + blockIdx.x)*64 + r;
    float acc[6] = {};
    for (int k = kq*128; k < kq*128 + 128; k++){
      float hv = h[b*512 + k];
      #pragma unroll
      for (int j = 0; j < 6; j++) acc[j] = fmaf(hv, ldf(Wwo, (long)k*6 + j, fl), acc[j]);
    }
    #pragma unroll
    for (int j = 0; j < 6; j++) red[r][kq][j] = acc[j];
    __syncthreads();
    if (kq == 0){
      #pragma unroll
      for (int j = 0; j < 6; j++)
        out[b*38 + j] = red[r][0][j] + red[r][1][j] + red[r][2][j] + red[r][3][j] + ldf(bwo, j, fl);
    }
  }
}

// ---------------------------------------------------------------------------
// U [192,128] bf16 rows: 0..63=Wak, 64=bak, 65..129=Wek, 130=bek, rest 0.
// Fused bG[c] = bq . U[c,:] reduction. grid 192 x 128 thr.
__global__ __launch_bounds__(128) void build_u_bg_kernel(
    const void* __restrict__ Wak, const void* __restrict__ bak,
    const void* __restrict__ Wek, const void* __restrict__ bek,
    const void* __restrict__ bq, u16* __restrict__ U, float* __restrict__ bG,
    const int* __restrict__ flg)
{
  const int fl = *flg;
  __shared__ float pp[2];
  int c = blockIdx.x, a = threadIdx.x;
  float v = 0.f;
  if (c < 64)       v = ldf(Wak, (long)c*128 + a, fl);
  else if (c == 64) v = ldf(bak, a, fl);
  else if (c < 130) v = ldf(Wek, (long)(c-65)*128 + a, fl);
  else if (c == 130) v = ldf(bek, a, fl);
  u16 vb = f2bf(v);
  U[c*128 + a] = vb;
  float p = ldf(bq, a, fl) * bf2f(vb);   // match original bg numerics (rounded U)
  p = wred(p);
  if ((a & 63) == 0) pp[a >> 6] = p;
  __syncthreads();
  if (a == 0) bG[c] = pp[0] + pp[1];
}

// bc[j] = ba1[j] + sum_c be2[c] * Wa1[c, j]  (top half of Wa1)
// 32 blocks x 256 thr: block owns 16 j-cols, 16-way c-slice reduction.
__global__ __launch_bounds__(256) void bc_kernel(
    const void* __restrict__ Wa1, const void* __restrict__ be2,
    const void* __restrict__ ba1, float* __restrict__ bc,
    const int* __restrict__ flg)
{
  const int fl = *flg;
  __shared__ float red[16][17];
  const int t = threadIdx.x;
  const int jj = t & 15, cs = t >> 4;
  const int j = blockIdx.x*16 + jj;
  float acc = 0.f;
  for (int c = cs*32; c < cs*32 + 32; c++)
    acc = fmaf(ldf(be2, c, fl), ldf(Wa1, (long)c*512 + j, fl), acc);
  red[jj][cs] = acc;
  __syncthreads();
  if (t < 16){
    float s = ldf(ba1, blockIdx.x*16 + t, fl);
    #pragma unroll
    for (int k = 0; k < 16; k++) s += red[t][k];
    bc[blockIdx.x*16 + t] = s;
  }
}

// ---------------------------------------------------------------------------
// shared MFMA GEMM body: out[r, ocol+col] = A[M,K(lda)] @ B[N,K]^T + bias
__device__ inline void gemm_body(const void* A, int lda, const void* Bm,
    const float* bias, u16* outp, int ldout, int ocol, int K, int fl,
    int amode, int bmode, short* Al, short* Bl)
{
  const int t = threadIdx.x, lane = t & 63, w = t >> 6;
  const int m0 = blockIdx.x*64, n0 = blockIdx.y*64;
  floatx4 acc[4] = {};
  const int row = t >> 2, seg = t & 3;
  for (int kt = 0; kt < K; kt += 32){
    __syncthreads();
    *(short8*)(Al + row*32 + seg*8) = ld8m(A,  (long)(m0 + row)*lda + kt + seg*8, amode, fl);
    *(short8*)(Bl + row*32 + seg*8) = ld8m(Bm, (long)(n0 + row)*K   + kt + seg*8, bmode, fl);
    __syncthreads();
    short8 a = *(const short8*)(Al + (w*16 + (lane & 15))*32 + ((lane >> 4)*8));
    #pragma unroll
    for (int nt = 0; nt < 4; nt++){
      short8 b = *(const short8*)(Bl + (nt*16 + (lane & 15))*32 + ((lane >> 4)*8));
      acc[nt] = MFMA(a, b, acc[nt]);
    }
  }
  #pragma unroll
  for (int nt = 0; nt < 4; nt++){
    int col = n0 + nt*16 + (lane & 15);
    float bb = bias ? bias[col] : 0.f;
    #pragma unroll
    for (int i = 0; i < 4; i++){
      int r = m0 + w*16 + (lane >> 4)*4 + i;
      outp[(long)r*ldout + ocol + col] = f2bf(acc[nt][i] + bb);
    }
  }
}

// Generic MFMA GEMM
__global__ __launch_bounds__(256) void gemm_nk_kernel(
    const void* __restrict__ A, int lda, const void* __restrict__ Bm,
    const float* __restrict__ bias, u16* __restrict__ outp, int ldout, int ocol,
    int K, const int* __restrict__ flg, int amode, int bmode)
{
  const int fl = *flg;
  __shared__ __align__(16) short Al[64*32];
  __shared__ __align__(16) short Bl[64*32];
  gemm_body(A, lda, Bm, bias, outp, ldout, ocol, K, fl, amode, bmode, Al, Bl);
}

// fused tot builder: z=0 own@WovT (K=128), z=1 mixa@WavT (K=64), z=2 mixe@WevT (K=96)
__global__ __launch_bounds__(256) void gemm_tot_kernel(
    const void* __restrict__ own, const u16* __restrict__ mixbuf,
    const u16* __restrict__ WovT, const u16* __restrict__ WavT, const u16* __restrict__ WevT,
    u16* __restrict__ tot, const int* __restrict__ flg)
{
  const int fl = *flg;
  __shared__ __align__(16) short Al[64*32];
  __shared__ __align__(16) short Bl[64*32];
  const void* A; const u16* Bm; int lda, K, ocol, amode;
  if (blockIdx.z == 0){ A = own;         lda = 128; Bm = WovT; K = 128; ocol = 0;   amode = 1; }
  else if (blockIdx.z == 1){ A = mixbuf; lda = 160; Bm = WavT; K = 64;  ocol = 256; amode = 0; }
  else { A = mixbuf + 64;                lda = 160; Bm = WevT; K = 96;  ocol = 512; amode = 0; }
  gemm_body(A, lda, Bm, nullptr, tot, 768, ocol, K, fl, amode, 0, Al, Bl);
}

// fused post-transpose GEMMs: z=0 u = h @ Wa1_bot + bc (64x8 blocks),
// z=1 Wc = We2 @ Wa1_top (8x8 blocks, extra x-blocks return). grid (64,8,2)
__global__ __launch_bounds__(256) void gemm_post_kernel(
    const float* __restrict__ h, const u16* __restrict__ Wa1bT, const float* __restrict__ bc,
    u16* __restrict__ u_b, const u16* __restrict__ Wa1tT, const void* __restrict__ We2,
    u16* __restrict__ WcT, const int* __restrict__ flg)
{
  const int fl = *flg;
  __shared__ __align__(16) short Al[64*32];
  __shared__ __align__(16) short Bl[64*32];
  if (blockIdx.z == 0){
    gemm_body(h, 512, Wa1bT, bc, u_b, 512, 0, 512, fl, 2, 0, Al, Bl);
  } else {
    if (blockIdx.x >= 8) return;
    gemm_body(Wa1tT, 512, We2, nullptr, WcT, 512, 0, 512, fl, 0, 1, Al, Bl);
  }
}

// ---------------------------------------------------------------------------
// Attention: TWO batch rows per wave (32-lane halves). Each half-wave owns one
// b-row; d packed 2/lane (paired load for aligned af; 2 scalars for odd-stride
// ef). Shfl chain 6->5, waves halved vs 1-row/wave. Register-cached af/ef
// between energy and weighted passes. G[b,0:64]=qka, 64=sa, 65:130=qke, 130=se.
__global__ __launch_bounds__(256) void attn_kernel(
    const u16* __restrict__ G, const void* __restrict__ af, const void* __restrict__ ef,
    u16* __restrict__ mixbuf, const int* __restrict__ flg)
{
  const int fl = *flg;
  __shared__ float gsh[8][192];
  __shared__ float attw[8][32];
  const int t = threadIdx.x;
  const int lane = t & 63, wv = t >> 6;
  const int l = lane & 31, hi = lane >> 5;
  const int wr = wv*2 + hi;
  const long b = (long)blockIdx.x*8 + wr;
  const float rsA = 0.08838834764831845f;  // 1/sqrt(128)

  for (int idx = t; idx < 8*192; idx += 256){
    int r = idx / 192, c = idx - r*192;
    gsh[r][c] = bf2f(G[((long)blockIdx.x*8 + r)*192 + c]);
  }
  __syncthreads();

  // ---- allies ----
  float2 qa2; qa2.x = gsh[wr][2*l]; qa2.y = gsh[wr][2*l + 1];
  float sa = gsh[wr][64];
  float2 fva[31];
  float myE = -1e30f;
  #pragma unroll
  for (int n = 0; n < 31; n++){
    fva[n] = ldf2(af, ((long)n*4096 + b)*64 + 2*l, fl);
    float e = hred32(fva[n].x*qa2.x + fva[n].y*qa2.y);
    e = (e + sa) * rsA;
    if (l == n) myE = e;
  }
  {
    float m = myE;
    for (int o = 16; o; o >>= 1) m = fmaxf(m, __shfl_xor(m, o));
    float p = (l < 31) ? __expf(myE - m) : 0.f;
    float s = hred32(p);
    attw[wr][l] = p / s;
  }
  __syncthreads();
  {
    float2 acc = {0.f, 0.f};
    #pragma unroll
    for (int n = 0; n < 31; n++){
      float w = attw[wr][n];
      acc.x = fmaf(w, fva[n].x, acc.x);
      acc.y = fmaf(w, fva[n].y, acc.y);
    }
    unsigned int pk = (unsigned int)f2bf(acc.x) | ((unsigned int)f2bf(acc.y) << 16);
    *(unsigned int*)(mixbuf + b*160 + 2*l) = pk;
  }
  __syncthreads();

  // ---- enemies (65 dims: d=2l,2l+1 per lane; lane 0 adds d=64) ----
  float2 qe2; qe2.x = gsh[wr][65 + 2*l]; qe2.y = gsh[wr][66 + 2*l];
  float qe64 = gsh[wr][129];
  float se = gsh[wr][130];
  float2 fve[32];
  myE = -1e30f;
  #pragma unroll
  for (int n = 0; n < 32; n++){
    long base = ((long)n*4096 + b)*65;
    fve[n].x = ldf(ef, base + 2*l, fl);
    fve[n].y = ldf(ef, base + 2*l + 1, fl);
    float prod = fve[n].x*qe2.x + fve[n].y*qe2.y;
    if (l == 0) prod = fmaf(ldf(ef, base + 64, fl), qe64, prod);
    float e = (hred32(prod) + se) * rsA;
    if (l == n) myE = e;
  }
  {
    float m = myE;
    for (int o = 16; o; o >>= 1) m = fmaxf(m, __shfl_xor(m, o));
    float p = __expf(myE - m);
    float s = hred32(p);
    attw[wr][l] = p / s;
  }
  __syncthreads();
  {
    float2 acc = {0.f, 0.f};
    float acc64 = 0.f;
    #pragma unroll
    for (int n = 0; n < 32; n++){
      long base = ((long)n*4096 + b)*65;
      float w = attw[wr][n];
      acc.x = fmaf(w, fve[n].x, acc.x);
      acc.y = fmaf(w, fve[n].y, acc.y);
      if (l == 0) acc64 = fmaf(w, ldf(ef, base + 64, fl), acc64);
    }
    unsigned int pk = (unsigned int)f2bf(acc.x) | ((unsigned int)f2bf(acc.y) << 16);
    *(unsigned int*)(mixbuf + b*160 + 64 + 2*l) = pk;
    if (l == 0) mixbuf[b*160 + 128] = f2bf(acc64);
    if (l >= 1) mixbuf[b*160 + 128 + l] = 0;
  }
}

// ---------------------------------------------------------------------------
// GRU: block = 128 batch rows x 64 hidden cols (512 thr); h (f32) -> d_out.
// 1-D grid of 256 with XCD swizzle: j0 = (bid&7)*64 -> per-XCD weight
// footprint ~1MB (L2-hot).
__global__ __launch_bounds__(512) void gru_kernel(
    const u16* __restrict__ tot, const void* __restrict__ hprev,
    const void* __restrict__ w_ih, const void* __restrict__ w_hh,
    const void* __restrict__ b_ih, const void* __restrict__ b_hh,
    float* __restrict__ h_out, const int* __restrict__ flg)
{
  const int fl = *flg;
  __shared__ __align__(16) short At[128*32], Ah[128*32];
  __shared__ __align__(16) short Bi[3][64*32], Bh[3][64*32];
  const int t = threadIdx.x, lane = t & 63, w = t >> 6;
  const int bid = blockIdx.x;
  const int b0 = (bid >> 3)*128, j0 = (bid & 7)*64;
  floatx4 ai[3][4] = {}; floatx4 ah[3][4] = {};
  const int row = t >> 2, seg = t & 3;
  for (int kt = 0; kt < 768; kt += 32){
    __syncthreads();
    *(short8*)(At + row*32 + seg*8) = *(const short8*)(tot + (long)(b0 + row)*768 + kt + seg*8);
    if (kt < 512)
      *(short8*)(Ah + row*32 + seg*8) = ld8m(hprev, (long)(b0 + row)*512 + kt + seg*8, 1, fl);
    if (t < 256){
      int rb = t >> 2, sb = t & 3;
      #pragma unroll
      for (int p = 0; p < 3; p++)
        *(short8*)(Bi[p] + rb*32 + sb*8) = ld8m(w_ih, (long)(p*512 + j0 + rb)*768 + kt + sb*8, 1, fl);
    } else if (kt < 512){
      int t2 = t - 256, rb = t2 >> 2, sb = t2 & 3;
      #pragma unroll
      for (int p = 0; p < 3; p++)
        *(short8*)(Bh[p] + rb*32 + sb*8) = ld8m(w_hh, (long)(p*512 + j0 + rb)*512 + kt + sb*8, 1, fl);
    }
    __syncthreads();
    short8 a = *(const short8*)(At + (w*16 + (lane & 15))*32 + ((lane >> 4)*8));
    #pragma unroll
    for (int p = 0; p < 3; p++){
      #pragma unroll
      for (int nt = 0; nt < 4; nt++){
        short8 b = *(const short8*)(Bi[p] + (nt*16 + (lane & 15))*32 + ((lane >> 4)*8));
        ai[p][nt] = MFMA(a, b, ai[p][nt]);
      }
    }
    if (kt < 512){
      short8 a2 = *(const short8*)(Ah + (w*16 + (lane & 15))*32 + ((lane >> 4)*8));
      #pragma unroll
      for (int p = 0; p < 3; p++){
        #pragma unroll
        for (int nt = 0; nt < 4; nt++){
          short8 b = *(const short8*)(Bh[p] + (nt*16 + (lane & 15))*32 + ((lane >> 4)*8));
          ah[p][nt] = MFMA(a2, b, ah[p][nt]);
        }
      }
    }
  }
  #pragma unroll
  for (int nt = 0; nt < 4; nt++){
    int colH = j0 + nt*16 + (lane & 15);
    float bir = ldf(b_ih, colH, fl),        bhr = ldf(b_hh, colH, fl);
    float biz = ldf(b_ih, 512 + colH, fl),  bhz = ldf(b_hh, 512 + colH, fl);
    float bin = ldf(b_ih, 1024 + colH, fl), bhn = ldf(b_hh, 1024 + colH, fl);
    #pragma unroll
    for (int i = 0; i < 4; i++){
      int r = b0 + w*16 + (lane >> 4)*4 + i;
      float rg = sigmf(ai[0][nt][i] + bir + ah[0][nt][i] + bhr);
      float zg = sigmf(ai[1][nt][i] + biz + ah[1][nt][i] + bhz);
      float ng = tanhfast(ai[2][nt][i] + bin + rg*(ah[2][nt][i] + bhn));
      float hp = ldf(hprev, (long)r*512 + colH, fl);
      h_out[(long)r*512 + colH] = (1.f - zg)*ng + zg*hp;
    }
  }
}

// ---------------------------------------------------------------------------
// Head: R0 body (154.5us) + s_setprio(1/0) around the barrier-free phase-2
// MFMA cluster (T5 experiment; waves drift there, so the scheduler has roles
// to arbitrate even at 2 waves/SIMD). Structure frozen per R1-R4 post-mortems.
__global__ __launch_bounds__(512) void head_kernel(
    const void* __restrict__ ef_g, const u16* __restrict__ We1T,
    const void* __restrict__ be1, const u16* __restrict__ WcT,
    const u16* __restrict__ u_b, const void* __restrict__ wa2,
    const void* __restrict__ ba2, float* __restrict__ out, const int* __restrict__ flg)
{
  const int fl = *flg;
  __shared__ __align__(16) short r1s[2][64*512];  // XOR-swizzled: (row, chunk^(row&7))
  __shared__ __align__(16) short efl[64*96];
  __shared__ float part[2][64][9];
  const int t = threadIdx.x, lane = t & 63, w = t >> 6;
  const int m = lane & 15, q = lane >> 4;
  const int n0 = blockIdx.y*2, b0 = blockIdx.x*64;

  // phase 1: r1[e][64][512]; enemies staged sequentially through one efl buffer
  for (int e = 0; e < 2; e++){
    const int n = n0 + e;
    __syncthreads();   // protect efl from previous enemy's readers
    for (int idx = t; idx < 64*96; idx += 512){
      int r = idx / 96, d = idx - r*96;
      u16 v = 0;
      if (d < 65) v = f2bf(ldf(ef_g, ((long)n*4096 + b0 + r)*65 + d, fl));
      efl[idx] = (short)v;
    }
    __syncthreads();
    #pragma unroll
    for (int jt4 = 0; jt4 < 4; jt4++){
      const int coln = (w*4 + jt4)*16 + m;
      short8 bfr[3];
      #pragma unroll
      for (int k3 = 0; k3 < 3; k3++)
        bfr[k3] = *(const short8*)(We1T + coln*96 + k3*32 + q*8);
      float be = ldf(be1, coln, fl);
      const int chunk = coln >> 3, sub = coln & 7;
      #pragma unroll
      for (int rt = 0; rt < 4; rt++){
        floatx4 acc = {0.f, 0.f, 0.f, 0.f};
        #pragma unroll
        for (int k3 = 0; k3 < 3; k3++){
          short8 a = *(const short8*)(efl + (rt*16 + m)*96 + k3*32 + q*8);
          acc = MFMA(a, bfr[k3], acc);
        }
        #pragma unroll
        for (int i = 0; i < 4; i++){
          int row = rt*16 + q*4 + i;
          float v = acc[i] + be;
          r1s[e][row*512 + ((chunk ^ (row & 7)) << 3) + sub] = (short)f2bf(v > 0.f ? v : 0.f);
        }
      }
    }
  }
  __syncthreads();

  // phase 2: wave w -> output cols [w*64, w*64+64); each B-frag used 8x (2e x 4rt)
  floatx4 acc[2][4][4] = {};
  for (int kt = 0; kt < 512; kt += 32){
    short8 b[4];
    #pragma unroll
    for (int js = 0; js < 4; js++)
      b[js] = *(const short8*)(WcT + (long)(w*64 + js*16 + m)*512 + kt + q*8);
    const int ch = (((kt >> 3) + q) ^ (m & 7)) << 3;
    __builtin_amdgcn_s_setprio(1);
    #pragma unroll
    for (int e = 0; e < 2; e++){
      #pragma unroll
      for (int rt = 0; rt < 4; rt++){
        short8 a = *(const short8*)(r1s[e] + (rt*16 + m)*512 + ch);
        #pragma unroll
        for (int js = 0; js < 4; js++)
          acc[e][rt][js] = MFMA(a, b[js], acc[e][rt][js]);
      }
    }
    __builtin_amdgcn_s_setprio(0);
  }

  // epilogue: u_b loaded once, shared across both enemies
  float pr[2][4][4] = {};
  #pragma unroll
  for (int js = 0; js < 4; js++){
    int col = w*64 + js*16 + m;
    float wv = ldf(wa2, col, fl);
    #pragma unroll
    for (int rt = 0; rt < 4; rt++){
      #pragma unroll
      for (int i = 0; i < 4; i++){
        int grow = b0 + rt*16 + q*4 + i;
        float u = bf2f(u_b[(long)grow*512 + col]);
        #pragma unroll
        for (int e = 0; e < 2; e++){
          float s = acc[e][rt][js][i] + u;
          pr[e][rt][i] += (s > 0.f ? s : 0.f) * wv;
        }
      }
    }
  }
  #pragma unroll
  for (int o = 1; o < 16; o <<= 1){
    #pragma unroll
    for (int e = 0; e < 2; e++)
      #pragma unroll
      for (int rt = 0; rt < 4; rt++)
        #pragma unroll
        for (int i = 0; i < 4; i++)
          pr[e][rt][i] += __shfl_xor(pr[e][rt][i], o);
  }
  if (m == 0){
    #pragma unroll
    for (int e = 0; e < 2; e++)
      #pragma unroll
      for (int rt = 0; rt < 4; rt++)
        #pragma unroll
        for (int i = 0; i < 4; i++)
          part[e][rt*16 + q*4 + i][w] = pr[e][rt][i];
  }
  __syncthreads();
  if (t < 128){
    int e = t >> 6, r = t & 63;
    float s = ldf(ba2, 0, fl);
    #pragma unroll
    for (int ww = 0; ww < 8; ww++) s += part[e][r][ww];
    out[(long)(b0 + r)*38 + 6 + n0 + e] = s;
  }
}

// ---------------------------------------------------------------------------
extern "C" void kernel_launch(void* const* d_in, const int* in_sizes, int n_in,
                              void* d_out, int out_size, void* d_ws, size_t ws_size,
                              hipStream_t stream)
{
  (void)in_sizes; (void)n_in; (void)out_size; (void)ws_size;
  const void* own  = d_in[0];
  const void* af   = d_in[1];
  const void* ef   = d_in[2];
  const void* hid  = d_in[3];
  const void* Wq   = d_in[4];
  const void* bq   = d_in[5];
  const void* Wak  = d_in[6];
  const void* bak  = d_in[7];
  const void* Wav  = d_in[8];
  const void* Wek  = d_in[10];
  const void* bek  = d_in[11];
  const void* Wev  = d_in[12];
  const void* Wov  = d_in[14];
  const void* w_ih = d_in[16];
  const void* w_hh = d_in[17];
  const void* b_ih = d_in[18];
  const void* b_hh = d_in[19];
  const void* Wwo  = d_in[20];
  const void* bwo  = d_in[21];
  const void* We1  = d_in[22];
  const void* be1  = d_in[23];
  const void* We2  = d_in[24];
  const void* be2  = d_in[25];
  const void* Wa1  = d_in[26];
  const void* ba1  = d_in[27];
  const void* Wa2  = d_in[28];
  const void* ba2  = d_in[29];
  float* out   = (float*)d_out;                 // q [4096,38] f32
  float* h_out = out + (long)4096*38;           // h [4096,512] f32

  // ---- workspace (7.76 MB peak, time-phased aliasing) ----
  char* ws = (char*)d_ws;
  u16*   tot    = (u16*)(ws + 0);               // [4096,768] bf16 = 6,291,456
  u16*   G      = (u16*)(ws + 0);               // [4096,192] bf16 (alias, dead before tot)
  u16*   u_b    = (u16*)(ws + 0);               // [4096,512] bf16 = 4 MB (alias, after gru)
  u16*   Wa1tT  = (u16*)(ws + 4194304);         // [512,512] bf16 (tot region tail, post-gru)
  char*  mz     = ws + 6291456;                 // 1,310,720 multi-phase zone
  u16*   mixbuf = (u16*)mz;                     // [4096,160] bf16 (attention phase)
  u16*   U      = (u16*)mz;                     // [192,128] bf16 (prep phase)
  u16*   WGT    = (u16*)(mz + 49152);           // [192,128] bf16 (prep phase)
  u16*   Wa1bT  = (u16*)mz;                     // [512,512] bf16 (post-gru phase)
  u16*   WcT    = (u16*)(mz + 524288);          // [512,512] bf16 (post-u phase)
  u16*   We1T   = (u16*)(mz + 1048576);         // [512,96]  bf16 (post-gru phase)
  char*  P      = ws + 7602176;                 // persistent small zone
  u16*   WovT   = (u16*)(P + 0);                // [256,128] bf16
  u16*   WavT   = (u16*)(P + 65536);            // [256,64]  bf16
  u16*   WevT   = (u16*)(P + 98304);            // [256,96]  bf16
  float* bc     = (float*)(P + 147456);         // [512] f32
  float* bG     = (float*)(P + 149504);         // [192] f32
  int*   flg    = (int*)(P + 150528);

  detect_kernel<<<1, 256, 0, stream>>>((const u16*)w_ih, flg);

  // prep: fused V-projection transposes + fused U/bG + parallel bc
  transpose3a_kernel<<<dim3(8, 9), 256, 0, stream>>>(Wov, Wav, Wev, WovT, WavT, WevT, flg);
  build_u_bg_kernel<<<192, 128, 0, stream>>>(Wak, bak, Wek, bek, bq, U, bG, flg);
  bc_kernel<<<32, 256, 0, stream>>>(Wa1, be2, ba1, bc, flg);
  // WGT[c,d] = sum_a U[c,a] * Wq[d,a]
  gemm_nk_kernel<<<dim3(3, 2), 256, 0, stream>>>(U, 128, Wq, nullptr, WGT, 128, 0, 128, flg, 0, 1);
  // G = own @ WGT^T + bG   [4096,192]
  gemm_nk_kernel<<<dim3(64, 3), 256, 0, stream>>>(own, 128, WGT, bG, G, 192, 0, 128, flg, 1, 0);
  // attention -> mixbuf (clobbers U/WGT; G still live in tot region)
  attn_kernel<<<512, 256, 0, stream>>>(G, af, ef, mixbuf, flg);
  // tot = [own@Wov | mix_a@Wav | mix_e@Wev]  (one launch; overwrites G)
  gemm_tot_kernel<<<dim3(64, 4, 3), 256, 0, stream>>>(own, mixbuf, WovT, WavT, WevT, tot, flg);
  // GRU -> h (f32 in d_out); 1-D grid, XCD-swizzled (j = bid&7)
  gru_kernel<<<256, 512, 0, stream>>>(tot, hid, w_ih, w_hh, b_ih, b_hh, h_out, flg);
  // fused late transposes + wo head (tot + mixbuf dead): Wa1bT@mz, Wa1tT@ws+4MB, We1T
  transpose3b_kernel<<<dim3(16, 39), 256, 0, stream>>>(Wa1, We1, Wa1bT, Wa1tT, We1T,
                                                       h_out, Wwo, bwo, out, flg);
  // u = h @ Wa1_bot + bc -> u_b  ||  Wc = We2 @ Wa1_top  (one z-fused launch)
  gemm_post_kernel<<<dim3(64, 8, 2), 256, 0, stream>>>(h_out, Wa1bT, bc, u_b,
                                                       Wa1tT, We2, WcT, flg);
  // heads
  head_kernel<<<dim3(64, 16), 512, 0, stream>>>(ef, We1T, be1, WcT, u_b, Wa2, ba2, out, flg);
}

// Round 8
// 523.940 us; speedup vs baseline: 1.4323x; 1.0019x over previous
//
#include <hip/hip_runtime.h>

typedef unsigned short u16;
typedef __attribute__((ext_vector_type(8))) short short8;
typedef __attribute__((ext_vector_type(4))) float floatx4;

__device__ inline float bf2f(u16 v){ union { unsigned int i; float f; } u; u.i = ((unsigned int)v) << 16; return u.f; }
__device__ inline u16 f2bf(float f){ union { float ff; unsigned int i; } u; u.ff = f; unsigned int r = u.i + 0x7fffu + ((u.i >> 16) & 1u); return (u16)(r >> 16); }
__device__ inline float sigmf(float x){ return 1.f/(1.f + __expf(-x)); }
__device__ inline float tanhfast(float x){ float e = __expf(-2.f*fabsf(x)); float t = (1.f-e)/(1.f+e); return x>=0.f? t : -t; }
__device__ inline float wred(float x){ for (int o = 32; o; o >>= 1) x += __shfl_xor(x, o); return x; }
__device__ inline float hred32(float x){ for (int o = 16; o; o >>= 1) x += __shfl_xor(x, o); return x; }

// dual-dtype scalar load: fl==1 -> buffer is float32, else bf16(u16)
__device__ inline float ldf(const void* p, long i, int fl){
  return fl ? ((const float*)p)[i] : bf2f(((const u16*)p)[i]);
}
// paired load at EVEN index (alignment guaranteed by caller)
__device__ inline float2 ldf2(const void* p, long i, int fl){
  if (fl) return *(const float2*)((const float*)p + i);
  unsigned int v = *(const unsigned int*)((const u16*)p + i);
  float2 r; r.x = bf2f((u16)(v & 0xffffu)); r.y = bf2f((u16)(v >> 16)); return r;
}
// 8-element load -> bf16 frag. mode: 0=bf16 buffer, 1=follow fl, 2=f32 buffer
__device__ inline short8 ld8m(const void* p, long i, int mode, int fl){
  int isf = (mode == 2) || (mode == 1 && fl);
  if (!isf) return *(const short8*)((const u16*)p + i);
  const float* f = (const float*)p + i;
  float4 x = *(const float4*)f;
  float4 y = *(const float4*)(f + 4);
  short8 r;
  r[0]=(short)f2bf(x.x); r[1]=(short)f2bf(x.y); r[2]=(short)f2bf(x.z); r[3]=(short)f2bf(x.w);
  r[4]=(short)f2bf(y.x); r[5]=(short)f2bf(y.y); r[6]=(short)f2bf(y.z); r[7]=(short)f2bf(y.w);
  return r;
}

#define MFMA(a,b,c) __builtin_amdgcn_mfma_f32_16x16x32_bf16(a,b,c,0,0,0)

// ---------------------------------------------------------------------------
__global__ void detect_kernel(const u16* __restrict__ w, int* __restrict__ flag){
  __shared__ int cnt[256];
  int t = threadIdx.x, c = 0;
  for (int i = t; i < 4096; i += 256){ u16 v = w[i]; if ((v & 0x7fff) >= 0x4200) c++; }
  cnt[t] = c; __syncthreads();
  for (int s = 128; s; s >>= 1){ if (t < s) cnt[t] += cnt[t + s]; __syncthreads(); }
  if (t == 0) *flag = (cnt[0] > 16) ? 1 : 0;
}

// ---------------------------------------------------------------------------
// shared transpose tile body: out[n][k] = (k<K)? in[ro+k][n] : 0
__device__ inline void tbody(float (*tile)[33], const void* in, int ldin, int ro,
                             int K, int N, int Kpad, u16* out, int fl, int k0, int n0)
{
  int tx = threadIdx.x & 31, ty = threadIdx.x >> 5;   // 32 x 8
  for (int i = ty; i < 32; i += 8){
    int k = k0 + i, n = n0 + tx;
    tile[i][tx] = (k < K && n < N) ? ldf(in, (long)(ro + k)*ldin + n, fl) : 0.f;
  }
  __syncthreads();
  for (int i = ty; i < 32; i += 8){
    int n = n0 + i, k = k0 + tx;
    if (n < N && k < Kpad) out[(long)n*Kpad + k] = f2bf(tile[tx][i]);
  }
}

// early fused transpose: Wov (y<4), Wav (y<6), Wev (else). grid (8,9)
__global__ __launch_bounds__(256) void transpose3a_kernel(
    const void* __restrict__ Wov, const void* __restrict__ Wav, const void* __restrict__ Wev,
    u16* __restrict__ WovT, u16* __restrict__ WavT, u16* __restrict__ WevT,
    const int* __restrict__ flg)
{
  const int fl = *flg;
  __shared__ float tile[32][33];
  int y = blockIdx.y, n0 = blockIdx.x*32;
  if (y < 4)      tbody(tile, Wov, 256, 0, 128, 256, 128, WovT, fl, y*32, n0);
  else if (y < 6) tbody(tile, Wav, 256, 0,  64, 256,  64, WavT, fl, (y-4)*32, n0);
  else            tbody(tile, Wev, 256, 0,  65, 256,  96, WevT, fl, (y-6)*32, n0);
}

// late fused transpose + wo head: Wa1 bottom (y<16), Wa1 top (y<32),
// We1 (y<35), wo out[:,0:6] (y in [35,39)). grid (16,39); runs after gru.
__global__ __launch_bounds__(256) void transpose3b_kernel(
    const void* __restrict__ Wa1, const void* __restrict__ We1,
    u16* __restrict__ Wa1bT, u16* __restrict__ Wa1tT, u16* __restrict__ We1T,
    const float* __restrict__ h, const void* __restrict__ Wwo,
    const void* __restrict__ bwo, float* __restrict__ out,
    const int* __restrict__ flg)
{
  const int fl = *flg;
  __shared__ float tile[32][33];
  int y = blockIdx.y, n0 = blockIdx.x*32;
  if (y < 16)      tbody(tile, Wa1, 512, 512, 512, 512, 512, Wa1bT, fl, y*32, n0);
  else if (y < 32) tbody(tile, Wa1, 512, 0,   512, 512, 512, Wa1tT, fl, (y-16)*32, n0);
  else if (y < 35) tbody(tile, We1, 512, 0,    65, 512,  96, We1T,  fl, (y-32)*32, n0);
  else {
    // ---- fused wo (R0-proven body): out[:,0:6] = h @ Wwo + bwo ----
    __shared__ float red[64][4][6];
    const int t = threadIdx.x, r = t >> 2, kq = t & 3;
    const long b = (long)((y - 35)*16 + blockIdx.x)*64 + r;
    float acc[6] = {};
    for (int k = kq*128; k < kq*128 + 128; k++){
      float hv = h[b*512 + k];
      #pragma unroll
      for (int j = 0; j < 6; j++) acc[j] = fmaf(hv, ldf(Wwo, (long)k*6 + j, fl), acc[j]);
    }
    #pragma unroll
    for (int j = 0; j < 6; j++) red[r][kq][j] = acc[j];
    __syncthreads();
    if (kq == 0){
      #pragma unroll
      for (int j = 0; j < 6; j++)
        out[b*38 + j] = red[r][0][j] + red[r][1][j] + red[r][2][j] + red[r][3][j] + ldf(bwo, j, fl);
    }
  }
}

// ---------------------------------------------------------------------------
// U [192,128] bf16 rows: 0..63=Wak, 64=bak, 65..129=Wek, 130=bek, rest 0.
// Fused bG[c] = bq . U[c,:] reduction. grid 192 x 128 thr.
__global__ __launch_bounds__(128) void build_u_bg_kernel(
    const void* __restrict__ Wak, const void* __restrict__ bak,
    const void* __restrict__ Wek, const void* __restrict__ bek,
    const void* __restrict__ bq, u16* __restrict__ U, float* __restrict__ bG,
    const int* __restrict__ flg)
{
  const int fl = *flg;
  __shared__ float pp[2];
  int c = blockIdx.x, a = threadIdx.x;
  float v = 0.f;
  if (c < 64)       v = ldf(Wak, (long)c*128 + a, fl);
  else if (c == 64) v = ldf(bak, a, fl);
  else if (c < 130) v = ldf(Wek, (long)(c-65)*128 + a, fl);
  else if (c == 130) v = ldf(bek, a, fl);
  u16 vb = f2bf(v);
  U[c*128 + a] = vb;
  float p = ldf(bq, a, fl) * bf2f(vb);   // match original bg numerics (rounded U)
  p = wred(p);
  if ((a & 63) == 0) pp[a >> 6] = p;
  __syncthreads();
  if (a == 0) bG[c] = pp[0] + pp[1];
}

// bc[j] = ba1[j] + sum_c be2[c] * Wa1[c, j]  (top half of Wa1)
// 32 blocks x 256 thr: block owns 16 j-cols, 16-way c-slice reduction.
__global__ __launch_bounds__(256) void bc_kernel(
    const void* __restrict__ Wa1, const void* __restrict__ be2,
    const void* __restrict__ ba1, float* __restrict__ bc,
    const int* __restrict__ flg)
{
  const int fl = *flg;
  __shared__ float red[16][17];
  const int t = threadIdx.x;
  const int jj = t & 15, cs = t >> 4;
  const int j = blockIdx.x*16 + jj;
  float acc = 0.f;
  for (int c = cs*32; c < cs*32 + 32; c++)
    acc = fmaf(ldf(be2, c, fl), ldf(Wa1, (long)c*512 + j, fl), acc);
  red[jj][cs] = acc;
  __syncthreads();
  if (t < 16){
    float s = ldf(ba1, blockIdx.x*16 + t, fl);
    #pragma unroll
    for (int k = 0; k < 16; k++) s += red[t][k];
    bc[blockIdx.x*16 + t] = s;
  }
}

// ---------------------------------------------------------------------------
// shared MFMA GEMM body: out[r, ocol+col] = A[M,K(lda)] @ B[N,K]^T + bias
__device__ inline void gemm_body(const void* A, int lda, const void* Bm,
    const float* bias, u16* outp, int ldout, int ocol, int K, int fl,
    int amode, int bmode, short* Al, short* Bl)
{
  const int t = threadIdx.x, lane = t & 63, w = t >> 6;
  const int m0 = blockIdx.x*64, n0 = blockIdx.y*64;
  floatx4 acc[4] = {};
  const int row = t >> 2, seg = t & 3;
  for (int kt = 0; kt < K; kt += 32){
    __syncthreads();
    *(short8*)(Al + row*32 + seg*8) = ld8m(A,  (long)(m0 + row)*lda + kt + seg*8, amode, fl);
    *(short8*)(Bl + row*32 + seg*8) = ld8m(Bm, (long)(n0 + row)*K   + kt + seg*8, bmode, fl);
    __syncthreads();
    short8 a = *(const short8*)(Al + (w*16 + (lane & 15))*32 + ((lane >> 4)*8));
    #pragma unroll
    for (int nt = 0; nt < 4; nt++){
      short8 b = *(const short8*)(Bl + (nt*16 + (lane & 15))*32 + ((lane >> 4)*8));
      acc[nt] = MFMA(a, b, acc[nt]);
    }
  }
  #pragma unroll
  for (int nt = 0; nt < 4; nt++){
    int col = n0 + nt*16 + (lane & 15);
    float bb = bias ? bias[col] : 0.f;
    #pragma unroll
    for (int i = 0; i < 4; i++){
      int r = m0 + w*16 + (lane >> 4)*4 + i;
      outp[(long)r*ldout + ocol + col] = f2bf(acc[nt][i] + bb);
    }
  }
}

// Generic MFMA GEMM
__global__ __launch_bounds__(256) void gemm_nk_kernel(
    const void* __restrict__ A, int lda, const void* __restrict__ Bm,
    const float* __restrict__ bias, u16* __restrict__ outp, int ldout, int ocol,
    int K, const int* __restrict__ flg, int amode, int bmode)
{
  const int fl = *flg;
  __shared__ __align__(16) short Al[64*32];
  __shared__ __align__(16) short Bl[64*32];
  gemm_body(A, lda, Bm, bias, outp, ldout, ocol, K, fl, amode, bmode, Al, Bl);
}

// fused tot builder: z=0 own@WovT (K=128), z=1 mixa@WavT (K=64), z=2 mixe@WevT (K=96)
__global__ __launch_bounds__(256) void gemm_tot_kernel(
    const void* __restrict__ own, const u16* __restrict__ mixbuf,
    const u16* __restrict__ WovT, const u16* __restrict__ WavT, const u16* __restrict__ WevT,
    u16* __restrict__ tot, const int* __restrict__ flg)
{
  const int fl = *flg;
  __shared__ __align__(16) short Al[64*32];
  __shared__ __align__(16) short Bl[64*32];
  const void* A; const u16* Bm; int lda, K, ocol, amode;
  if (blockIdx.z == 0){ A = own;         lda = 128; Bm = WovT; K = 128; ocol = 0;   amode = 1; }
  else if (blockIdx.z == 1){ A = mixbuf; lda = 160; Bm = WavT; K = 64;  ocol = 256; amode = 0; }
  else { A = mixbuf + 64;                lda = 160; Bm = WevT; K = 96;  ocol = 512; amode = 0; }
  gemm_body(A, lda, Bm, nullptr, tot, 768, ocol, K, fl, amode, 0, Al, Bl);
}

// fused post-transpose GEMMs: z=0 u = h @ Wa1_bot + bc (64x8 blocks),
// z=1 Wc = We2 @ Wa1_top (8x8 blocks, extra x-blocks return). grid (64,8,2)
__global__ __launch_bounds__(256) void gemm_post_kernel(
    const float* __restrict__ h, const u16* __restrict__ Wa1bT, const float* __restrict__ bc,
    u16* __restrict__ u_b, const u16* __restrict__ Wa1tT, const void* __restrict__ We2,
    u16* __restrict__ WcT, const int* __restrict__ flg)
{
  const int fl = *flg;
  __shared__ __align__(16) short Al[64*32];
  __shared__ __align__(16) short Bl[64*32];
  if (blockIdx.z == 0){
    gemm_body(h, 512, Wa1bT, bc, u_b, 512, 0, 512, fl, 2, 0, Al, Bl);
  } else {
    if (blockIdx.x >= 8) return;
    gemm_body(Wa1tT, 512, We2, nullptr, WcT, 512, 0, 512, fl, 0, 1, Al, Bl);
  }
}

// ---------------------------------------------------------------------------
// Attention: TWO batch rows per wave (32-lane halves). Each half-wave owns one
// b-row; d packed 2/lane. Register-cached af/ef between passes.
__global__ __launch_bounds__(256) void attn_kernel(
    const u16* __restrict__ G, const void* __restrict__ af, const void* __restrict__ ef,
    u16* __restrict__ mixbuf, const int* __restrict__ flg)
{
  const int fl = *flg;
  __shared__ float gsh[8][192];
  __shared__ float attw[8][32];
  const int t = threadIdx.x;
  const int lane = t & 63, wv = t >> 6;
  const int l = lane & 31, hi = lane >> 5;
  const int wr = wv*2 + hi;
  const long b = (long)blockIdx.x*8 + wr;
  const float rsA = 0.08838834764831845f;  // 1/sqrt(128)

  for (int idx = t; idx < 8*192; idx += 256){
    int r = idx / 192, c = idx - r*192;
    gsh[r][c] = bf2f(G[((long)blockIdx.x*8 + r)*192 + c]);
  }
  __syncthreads();

  // ---- allies ----
  float2 qa2; qa2.x = gsh[wr][2*l]; qa2.y = gsh[wr][2*l + 1];
  float sa = gsh[wr][64];
  float2 fva[31];
  float myE = -1e30f;
  #pragma unroll
  for (int n = 0; n < 31; n++){
    fva[n] = ldf2(af, ((long)n*4096 + b)*64 + 2*l, fl);
    float e = hred32(fva[n].x*qa2.x + fva[n].y*qa2.y);
    e = (e + sa) * rsA;
    if (l == n) myE = e;
  }
  {
    float m = myE;
    for (int o = 16; o; o >>= 1) m = fmaxf(m, __shfl_xor(m, o));
    float p = (l < 31) ? __expf(myE - m) : 0.f;
    float s = hred32(p);
    attw[wr][l] = p / s;
  }
  __syncthreads();
  {
    float2 acc = {0.f, 0.f};
    #pragma unroll
    for (int n = 0; n < 31; n++){
      float w = attw[wr][n];
      acc.x = fmaf(w, fva[n].x, acc.x);
      acc.y = fmaf(w, fva[n].y, acc.y);
    }
    unsigned int pk = (unsigned int)f2bf(acc.x) | ((unsigned int)f2bf(acc.y) << 16);
    *(unsigned int*)(mixbuf + b*160 + 2*l) = pk;
  }
  __syncthreads();

  // ---- enemies (65 dims: d=2l,2l+1 per lane; lane 0 adds d=64) ----
  float2 qe2; qe2.x = gsh[wr][65 + 2*l]; qe2.y = gsh[wr][66 + 2*l];
  float qe64 = gsh[wr][129];
  float se = gsh[wr][130];
  float2 fve[32];
  myE = -1e30f;
  #pragma unroll
  for (int n = 0; n < 32; n++){
    long base = ((long)n*4096 + b)*65;
    fve[n].x = ldf(ef, base + 2*l, fl);
    fve[n].y = ldf(ef, base + 2*l + 1, fl);
    float prod = fve[n].x*qe2.x + fve[n].y*qe2.y;
    if (l == 0) prod = fmaf(ldf(ef, base + 64, fl), qe64, prod);
    float e = (hred32(prod) + se) * rsA;
    if (l == n) myE = e;
  }
  {
    float m = myE;
    for (int o = 16; o; o >>= 1) m = fmaxf(m, __shfl_xor(m, o));
    float p = __expf(myE - m);
    float s = hred32(p);
    attw[wr][l] = p / s;
  }
  __syncthreads();
  {
    float2 acc = {0.f, 0.f};
    float acc64 = 0.f;
    #pragma unroll
    for (int n = 0; n < 32; n++){
      long base = ((long)n*4096 + b)*65;
      float w = attw[wr][n];
      acc.x = fmaf(w, fve[n].x, acc.x);
      acc.y = fmaf(w, fve[n].y, acc.y);
      if (l == 0) acc64 = fmaf(w, ldf(ef, base + 64, fl), acc64);
    }
    unsigned int pk = (unsigned int)f2bf(acc.x) | ((unsigned int)f2bf(acc.y) << 16);
    *(unsigned int*)(mixbuf + b*160 + 64 + 2*l) = pk;
    if (l == 0) mixbuf[b*160 + 128] = f2bf(acc64);
    if (l >= 1) mixbuf[b*160 + 128 + l] = 0;
  }
}

// ---------------------------------------------------------------------------
// GRU: block = 128 batch rows x 64 hidden cols (512 thr); h (f32) -> d_out.
// 1-D grid of 256 with XCD swizzle: j0 = (bid&7)*64 -> per-XCD weight
// footprint ~1MB (L2-hot).
__global__ __launch_bounds__(512) void gru_kernel(
    const u16* __restrict__ tot, const void* __restrict__ hprev,
    const void* __restrict__ w_ih, const void* __restrict__ w_hh,
    const void* __restrict__ b_ih, const void* __restrict__ b_hh,
    float* __restrict__ h_out, const int* __restrict__ flg)
{
  const int fl = *flg;
  __shared__ __align__(16) short At[128*32], Ah[128*32];
  __shared__ __align__(16) short Bi[3][64*32], Bh[3][64*32];
  const int t = threadIdx.x, lane = t & 63, w = t >> 6;
  const int bid = blockIdx.x;
  const int b0 = (bid >> 3)*128, j0 = (bid & 7)*64;
  floatx4 ai[3][4] = {}; floatx4 ah[3][4] = {};
  const int row = t >> 2, seg = t & 3;
  for (int kt = 0; kt < 768; kt += 32){
    __syncthreads();
    *(short8*)(At + row*32 + seg*8) = *(const short8*)(tot + (long)(b0 + row)*768 + kt + seg*8);
    if (kt < 512)
      *(short8*)(Ah + row*32 + seg*8) = ld8m(hprev, (long)(b0 + row)*512 + kt + seg*8, 1, fl);
    if (t < 256){
      int rb = t >> 2, sb = t & 3;
      #pragma unroll
      for (int p = 0; p < 3; p++)
        *(short8*)(Bi[p] + rb*32 + sb*8) = ld8m(w_ih, (long)(p*512 + j0 + rb)*768 + kt + sb*8, 1, fl);
    } else if (kt < 512){
      int t2 = t - 256, rb = t2 >> 2, sb = t2 & 3;
      #pragma unroll
      for (int p = 0; p < 3; p++)
        *(short8*)(Bh[p] + rb*32 + sb*8) = ld8m(w_hh, (long)(p*512 + j0 + rb)*512 + kt + sb*8, 1, fl);
    }
    __syncthreads();
    short8 a = *(const short8*)(At + (w*16 + (lane & 15))*32 + ((lane >> 4)*8));
    #pragma unroll
    for (int p = 0; p < 3; p++){
      #pragma unroll
      for (int nt = 0; nt < 4; nt++){
        short8 b = *(const short8*)(Bi[p] + (nt*16 + (lane & 15))*32 + ((lane >> 4)*8));
        ai[p][nt] = MFMA(a, b, ai[p][nt]);
      }
    }
    if (kt < 512){
      short8 a2 = *(const short8*)(Ah + (w*16 + (lane & 15))*32 + ((lane >> 4)*8));
      #pragma unroll
      for (int p = 0; p < 3; p++){
        #pragma unroll
        for (int nt = 0; nt < 4; nt++){
          short8 b = *(const short8*)(Bh[p] + (nt*16 + (lane & 15))*32 + ((lane >> 4)*8));
          ah[p][nt] = MFMA(a2, b, ah[p][nt]);
        }
      }
    }
  }
  #pragma unroll
  for (int nt = 0; nt < 4; nt++){
    int colH = j0 + nt*16 + (lane & 15);
    float bir = ldf(b_ih, colH, fl),        bhr = ldf(b_hh, colH, fl);
    float biz = ldf(b_ih, 512 + colH, fl),  bhz = ldf(b_hh, 512 + colH, fl);
    float bin = ldf(b_ih, 1024 + colH, fl), bhn = ldf(b_hh, 1024 + colH, fl);
    #pragma unroll
    for (int i = 0; i < 4; i++){
      int r = b0 + w*16 + (lane >> 4)*4 + i;
      float rg = sigmf(ai[0][nt][i] + bir + ah[0][nt][i] + bhr);
      float zg = sigmf(ai[1][nt][i] + biz + ah[1][nt][i] + bhz);
      float ng = tanhfast(ai[2][nt][i] + bin + rg*(ah[2][nt][i] + bhn));
      float hp = ldf(hprev, (long)r*512 + colH, fl);
      h_out[(long)r*512 + colH] = (1.f - zg)*ng + zg*hp;
    }
  }
}

// ---------------------------------------------------------------------------
// Head: R0 structure (frozen per R1-R4) + phase-2 2-stage B-prefetch pipeline.
// setprio removed (R7 A/B: null-to-negative). Phase-2 theory: 1 block/CU
// (LDS-pinned, 2 waves/SIMD) cannot hide the ~200cy L2 latency of the 4 WcT
// loads issued-and-consumed in the same kt iteration; prefetching next kt's
// B-frags under the current 32-MFMA cluster removes that serial wait.
// +16 VGPR (136+128acc=264<512), occupancy unchanged (LDS is the limiter).
__global__ __launch_bounds__(512) void head_kernel(
    const void* __restrict__ ef_g, const u16* __restrict__ We1T,
    const void* __restrict__ be1, const u16* __restrict__ WcT,
    const u16* __restrict__ u_b, const void* __restrict__ wa2,
    const void* __restrict__ ba2, float* __restrict__ out, const int* __restrict__ flg)
{
  const int fl = *flg;
  __shared__ __align__(16) short r1s[2][64*512];  // XOR-swizzled: (row, chunk^(row&7))
  __shared__ __align__(16) short efl[64*96];
  __shared__ float part[2][64][9];
  const int t = threadIdx.x, lane = t & 63, w = t >> 6;
  const int m = lane & 15, q = lane >> 4;
  const int n0 = blockIdx.y*2, b0 = blockIdx.x*64;

  // phase 1: r1[e][64][512]; enemies staged sequentially through one efl buffer
  for (int e = 0; e < 2; e++){
    const int n = n0 + e;
    __syncthreads();   // protect efl from previous enemy's readers
    for (int idx = t; idx < 64*96; idx += 512){
      int r = idx / 96, d = idx - r*96;
      u16 v = 0;
      if (d < 65) v = f2bf(ldf(ef_g, ((long)n*4096 + b0 + r)*65 + d, fl));
      efl[idx] = (short)v;
    }
    __syncthreads();
    #pragma unroll
    for (int jt4 = 0; jt4 < 4; jt4++){
      const int coln = (w*4 + jt4)*16 + m;
      short8 bfr[3];
      #pragma unroll
      for (int k3 = 0; k3 < 3; k3++)
        bfr[k3] = *(const short8*)(We1T + coln*96 + k3*32 + q*8);
      float be = ldf(be1, coln, fl);
      const int chunk = coln >> 3, sub = coln & 7;
      #pragma unroll
      for (int rt = 0; rt < 4; rt++){
        floatx4 acc = {0.f, 0.f, 0.f, 0.f};
        #pragma unroll
        for (int k3 = 0; k3 < 3; k3++){
          short8 a = *(const short8*)(efl + (rt*16 + m)*96 + k3*32 + q*8);
          acc = MFMA(a, bfr[k3], acc);
        }
        #pragma unroll
        for (int i = 0; i < 4; i++){
          int row = rt*16 + q*4 + i;
          float v = acc[i] + be;
          r1s[e][row*512 + ((chunk ^ (row & 7)) << 3) + sub] = (short)f2bf(v > 0.f ? v : 0.f);
        }
      }
    }
  }
  __syncthreads();

  // phase 2: wave w -> output cols [w*64, +64); B-frag used 8x (2e x 4rt);
  // 2-deep software pipeline on the WcT B-frag loads.
  floatx4 acc[2][4][4] = {};
  short8 bA[4], bB[4];
  #pragma unroll
  for (int js = 0; js < 4; js++)
    bA[js] = *(const short8*)(WcT + (long)(w*64 + js*16 + m)*512 + q*8);
  for (int kt = 0; kt < 512; kt += 64){
    #pragma unroll
    for (int js = 0; js < 4; js++)
      bB[js] = *(const short8*)(WcT + (long)(w*64 + js*16 + m)*512 + kt + 32 + q*8);
    {
      const int ch = (((kt >> 3) + q) ^ (m & 7)) << 3;
      #pragma unroll
      for (int e = 0; e < 2; e++){
        #pragma unroll
        for (int rt = 0; rt < 4; rt++){
          short8 a = *(const short8*)(r1s[e] + (rt*16 + m)*512 + ch);
          #pragma unroll
          for (int js = 0; js < 4; js++)
            acc[e][rt][js] = MFMA(a, bA[js], acc[e][rt][js]);
        }
      }
    }
    if (kt + 64 < 512){
      #pragma unroll
      for (int js = 0; js < 4; js++)
        bA[js] = *(const short8*)(WcT + (long)(w*64 + js*16 + m)*512 + kt + 64 + q*8);
    }
    {
      const int ch = ((((kt + 32) >> 3) + q) ^ (m & 7)) << 3;
      #pragma unroll
      for (int e = 0; e < 2; e++){
        #pragma unroll
        for (int rt = 0; rt < 4; rt++){
          short8 a = *(const short8*)(r1s[e] + (rt*16 + m)*512 + ch);
          #pragma unroll
          for (int js = 0; js < 4; js++)
            acc[e][rt][js] = MFMA(a, bB[js], acc[e][rt][js]);
        }
      }
    }
  }

  // epilogue: u_b loaded once, shared across both enemies
  float pr[2][4][4] = {};
  #pragma unroll
  for (int js = 0; js < 4; js++){
    int col = w*64 + js*16 + m;
    float wv = ldf(wa2, col, fl);
    #pragma unroll
    for (int rt = 0; rt < 4; rt++){
      #pragma unroll
      for (int i = 0; i < 4; i++){
        int grow = b0 + rt*16 + q*4 + i;
        float u = bf2f(u_b[(long)grow*512 + col]);
        #pragma unroll
        for (int e = 0; e < 2; e++){
          float s = acc[e][rt][js][i] + u;
          pr[e][rt][i] += (s > 0.f ? s : 0.f) * wv;
        }
      }
    }
  }
  #pragma unroll
  for (int o = 1; o < 16; o <<= 1){
    #pragma unroll
    for (int e = 0; e < 2; e++)
      #pragma unroll
      for (int rt = 0; rt < 4; rt++)
        #pragma unroll
        for (int i = 0; i < 4; i++)
          pr[e][rt][i] += __shfl_xor(pr[e][rt][i], o);
  }
  if (m == 0){
    #pragma unroll
    for (int e = 0; e < 2; e++)
      #pragma unroll
      for (int rt = 0; rt < 4; rt++)
        #pragma unroll
        for (int i = 0; i < 4; i++)
          part[e][rt*16 + q*4 + i][w] = pr[e][rt][i];
  }
  __syncthreads();
  if (t < 128){
    int e = t >> 6, r = t & 63;
    float s = ldf(ba2, 0, fl);
    #pragma unroll
    for (int ww = 0; ww < 8; ww++) s += part[e][r][ww];
    out[(long)(b0 + r)*38 + 6 + n0 + e] = s;
  }
}

// ---------------------------------------------------------------------------
extern "C" void kernel_launch(void* const* d_in, const int* in_sizes, int n_in,
                              void* d_out, int out_size, void* d_ws, size_t ws_size,
                              hipStream_t stream)
{
  (void)in_sizes; (void)n_in; (void)out_size; (void)ws_size;
  const void* own  = d_in[0];
  const void* af   = d_in[1];
  const void* ef   = d_in[2];
  const void* hid  = d_in[3];
  const void* Wq   = d_in[4];
  const void* bq   = d_in[5];
  const void* Wak  = d_in[6];
  const void* bak  = d_in[7];
  const void* Wav  = d_in[8];
  const void* Wek  = d_in[10];
  const void* bek  = d_in[11];
  const void* Wev  = d_in[12];
  const void* Wov  = d_in[14];
  const void* w_ih = d_in[16];
  const void* w_hh = d_in[17];
  const void* b_ih = d_in[18];
  const void* b_hh = d_in[19];
  const void* Wwo  = d_in[20];
  const void* bwo  = d_in[21];
  const void* We1  = d_in[22];
  const void* be1  = d_in[23];
  const void* We2  = d_in[24];
  const void* be2  = d_in[25];
  const void* Wa1  = d_in[26];
  const void* ba1  = d_in[27];
  const void* Wa2  = d_in[28];
  const void* ba2  = d_in[29];
  float* out   = (float*)d_out;                 // q [4096,38] f32
  float* h_out = out + (long)4096*38;           // h [4096,512] f32

  // ---- workspace (7.76 MB peak, time-phased aliasing) ----
  char* ws = (char*)d_ws;
  u16*   tot    = (u16*)(ws + 0);               // [4096,768] bf16 = 6,291,456
  u16*   G      = (u16*)(ws + 0);               // [4096,192] bf16 (alias, dead before tot)
  u16*   u_b    = (u16*)(ws + 0);               // [4096,512] bf16 = 4 MB (alias, after gru)
  u16*   Wa1tT  = (u16*)(ws + 4194304);         // [512,512] bf16 (tot region tail, post-gru)
  char*  mz     = ws + 6291456;                 // 1,310,720 multi-phase zone
  u16*   mixbuf = (u16*)mz;                     // [4096,160] bf16 (attention phase)
  u16*   U      = (u16*)mz;                     // [192,128] bf16 (prep phase)
  u16*   WGT    = (u16*)(mz + 49152);           // [192,128] bf16 (prep phase)
  u16*   Wa1bT  = (u16*)mz;                     // [512,512] bf16 (post-gru phase)
  u16*   WcT    = (u16*)(mz + 524288);          // [512,512] bf16 (post-u phase)
  u16*   We1T   = (u16*)(mz + 1048576);         // [512,96]  bf16 (post-gru phase)
  char*  P      = ws + 7602176;                 // persistent small zone
  u16*   WovT   = (u16*)(P + 0);                // [256,128] bf16
  u16*   WavT   = (u16*)(P + 65536);            // [256,64]  bf16
  u16*   WevT   = (u16*)(P + 98304);            // [256,96]  bf16
  float* bc     = (float*)(P + 147456);         // [512] f32
  float* bG     = (float*)(P + 149504);         // [192] f32
  int*   flg    = (int*)(P + 150528);

  detect_kernel<<<1, 256, 0, stream>>>((const u16*)w_ih, flg);

  // prep: fused V-projection transposes + fused U/bG + parallel bc
  transpose3a_kernel<<<dim3(8, 9), 256, 0, stream>>>(Wov, Wav, Wev, WovT, WavT, WevT, flg);
  build_u_bg_kernel<<<192, 128, 0, stream>>>(Wak, bak, Wek, bek, bq, U, bG, flg);
  bc_kernel<<<32, 256, 0, stream>>>(Wa1, be2, ba1, bc, flg);
  // WGT[c,d] = sum_a U[c,a] * Wq[d,a]
  gemm_nk_kernel<<<dim3(3, 2), 256, 0, stream>>>(U, 128, Wq, nullptr, WGT, 128, 0, 128, flg, 0, 1);
  // G = own @ WGT^T + bG   [4096,192]
  gemm_nk_kernel<<<dim3(64, 3), 256, 0, stream>>>(own, 128, WGT, bG, G, 192, 0, 128, flg, 1, 0);
  // attention -> mixbuf (clobbers U/WGT; G still live in tot region)
  attn_kernel<<<512, 256, 0, stream>>>(G, af, ef, mixbuf, flg);
  // tot = [own@Wov | mix_a@Wav | mix_e@Wev]  (one launch; overwrites G)
  gemm_tot_kernel<<<dim3(64, 4, 3), 256, 0, stream>>>(own, mixbuf, WovT, WavT, WevT, tot, flg);
  // GRU -> h (f32 in d_out); 1-D grid, XCD-swizzled (j = bid&7)
  gru_kernel<<<256, 512, 0, stream>>>(tot, hid, w_ih, w_hh, b_ih, b_hh, h_out, flg);
  // fused late transposes + wo head (tot + mixbuf dead): Wa1bT@mz, Wa1tT@ws+4MB, We1T
  transpose3b_kernel<<<dim3(16, 39), 256, 0, stream>>>(Wa1, We1, Wa1bT, Wa1tT, We1T,
                                                       h_out, Wwo, bwo, out, flg);
  // u = h @ Wa1_bot + bc -> u_b  ||  Wc = We2 @ Wa1_top  (one z-fused launch)
  gemm_post_kernel<<<dim3(64, 8, 2), 256, 0, stream>>>(h_out, Wa1bT, bc, u_b,
                                                       Wa1tT, We2, WcT, flg);
  // heads
  head_kernel<<<dim3(64, 16), 512, 0, stream>>>(ef, We1T, be1, WcT, u_b, Wa2, ba2, out, flg);
}

// Round 9
// 520.528 us; speedup vs baseline: 1.4417x; 1.0066x over previous
//
#include <hip/hip_runtime.h>

typedef unsigned short u16;
typedef __attribute__((ext_vector_type(8))) short short8;
typedef __attribute__((ext_vector_type(4))) float floatx4;

__device__ inline float bf2f(u16 v){ union { unsigned int i; float f; } u; u.i = ((unsigned int)v) << 16; return u.f; }
// RNE f32->bf16 via compiler cast: lowers to v_cvt_pk_bf16_f32 pairs on gfx950
// (bit-identical to the integer round-half-even trick, ~10x fewer VALU ops).
__device__ inline u16 f2bf(float f){ union { __bf16 b; u16 s; } u; u.b = (__bf16)f; return u.s; }
__device__ inline float sigmf(float x){ return 1.f/(1.f + __expf(-x)); }
__device__ inline float tanhfast(float x){ float e = __expf(-2.f*fabsf(x)); float t = (1.f-e)/(1.f+e); return x>=0.f? t : -t; }
__device__ inline float wred(float x){ for (int o = 32; o; o >>= 1) x += __shfl_xor(x, o); return x; }
__device__ inline float hred32(float x){ for (int o = 16; o; o >>= 1) x += __shfl_xor(x, o); return x; }

// dual-dtype scalar load: fl==1 -> buffer is float32, else bf16(u16)
__device__ inline float ldf(const void* p, long i, int fl){
  return fl ? ((const float*)p)[i] : bf2f(((const u16*)p)[i]);
}
// paired load at EVEN index (alignment guaranteed by caller)
__device__ inline float2 ldf2(const void* p, long i, int fl){
  if (fl) return *(const float2*)((const float*)p + i);
  unsigned int v = *(const unsigned int*)((const u16*)p + i);
  float2 r; r.x = bf2f((u16)(v & 0xffffu)); r.y = bf2f((u16)(v >> 16)); return r;
}
// 8-element load -> bf16 frag. mode: 0=bf16 buffer, 1=follow fl, 2=f32 buffer
__device__ inline short8 ld8m(const void* p, long i, int mode, int fl){
  int isf = (mode == 2) || (mode == 1 && fl);
  if (!isf) return *(const short8*)((const u16*)p + i);
  const float* f = (const float*)p + i;
  float4 x = *(const float4*)f;
  float4 y = *(const float4*)(f + 4);
  short8 r;
  r[0]=(short)f2bf(x.x); r[1]=(short)f2bf(x.y); r[2]=(short)f2bf(x.z); r[3]=(short)f2bf(x.w);
  r[4]=(short)f2bf(y.x); r[5]=(short)f2bf(y.y); r[6]=(short)f2bf(y.z); r[7]=(short)f2bf(y.w);
  return r;
}

#define MFMA(a,b,c) __builtin_amdgcn_mfma_f32_16x16x32_bf16(a,b,c,0,0,0)
#define LDW 40   // LDS tile row stride in shorts (80B): breaks the 64B-stride 8-way bank alias

// ---------------------------------------------------------------------------
__global__ void detect_kernel(const u16* __restrict__ w, int* __restrict__ flag){
  __shared__ int cnt[256];
  int t = threadIdx.x, c = 0;
  for (int i = t; i < 4096; i += 256){ u16 v = w[i]; if ((v & 0x7fff) >= 0x4200) c++; }
  cnt[t] = c; __syncthreads();
  for (int s = 128; s; s >>= 1){ if (t < s) cnt[t] += cnt[t + s]; __syncthreads(); }
  if (t == 0) *flag = (cnt[0] > 16) ? 1 : 0;
}

// ---------------------------------------------------------------------------
// shared transpose tile body: out[n][k] = (k<K)? in[ro+k][n] : 0
__device__ inline void tbody(float (*tile)[33], const void* in, int ldin, int ro,
                             int K, int N, int Kpad, u16* out, int fl, int k0, int n0)
{
  int tx = threadIdx.x & 31, ty = threadIdx.x >> 5;   // 32 x 8
  for (int i = ty; i < 32; i += 8){
    int k = k0 + i, n = n0 + tx;
    tile[i][tx] = (k < K && n < N) ? ldf(in, (long)(ro + k)*ldin + n, fl) : 0.f;
  }
  __syncthreads();
  for (int i = ty; i < 32; i += 8){
    int n = n0 + i, k = k0 + tx;
    if (n < N && k < Kpad) out[(long)n*Kpad + k] = f2bf(tile[tx][i]);
  }
}

// early fused transpose: Wov (y<4), Wav (y<6), Wev (else). grid (8,9)
__global__ __launch_bounds__(256) void transpose3a_kernel(
    const void* __restrict__ Wov, const void* __restrict__ Wav, const void* __restrict__ Wev,
    u16* __restrict__ WovT, u16* __restrict__ WavT, u16* __restrict__ WevT,
    const int* __restrict__ flg)
{
  const int fl = *flg;
  __shared__ float tile[32][33];
  int y = blockIdx.y, n0 = blockIdx.x*32;
  if (y < 4)      tbody(tile, Wov, 256, 0, 128, 256, 128, WovT, fl, y*32, n0);
  else if (y < 6) tbody(tile, Wav, 256, 0,  64, 256,  64, WavT, fl, (y-4)*32, n0);
  else            tbody(tile, Wev, 256, 0,  65, 256,  96, WevT, fl, (y-6)*32, n0);
}

// late fused transpose + wo head: Wa1 bottom (y<16), Wa1 top (y<32),
// We1 (y<35), wo out[:,0:6] (y in [35,39)). grid (16,39); runs after gru.
__global__ __launch_bounds__(256) void transpose3b_kernel(
    const void* __restrict__ Wa1, const void* __restrict__ We1,
    u16* __restrict__ Wa1bT, u16* __restrict__ Wa1tT, u16* __restrict__ We1T,
    const float* __restrict__ h, const void* __restrict__ Wwo,
    const void* __restrict__ bwo, float* __restrict__ out,
    const int* __restrict__ flg)
{
  const int fl = *flg;
  __shared__ float tile[32][33];
  int y = blockIdx.y, n0 = blockIdx.x*32;
  if (y < 16)      tbody(tile, Wa1, 512, 512, 512, 512, 512, Wa1bT, fl, y*32, n0);
  else if (y < 32) tbody(tile, Wa1, 512, 0,   512, 512, 512, Wa1tT, fl, (y-16)*32, n0);
  else if (y < 35) tbody(tile, We1, 512, 0,    65, 512,  96, We1T,  fl, (y-32)*32, n0);
  else {
    // ---- fused wo (R0-proven body): out[:,0:6] = h @ Wwo + bwo ----
    __shared__ float red[64][4][6];
    const int t = threadIdx.x, r = t >> 2, kq = t & 3;
    const long b = (long)((y - 35)*16 + blockIdx.x)*64 + r;
    float acc[6] = {};
    for (int k = kq*128; k < kq*128 + 128; k++){
      float hv = h[b*512 + k];
      #pragma unroll
      for (int j = 0; j < 6; j++) acc[j] = fmaf(hv, ldf(Wwo, (long)k*6 + j, fl), acc[j]);
    }
    #pragma unroll
    for (int j = 0; j < 6; j++) red[r][kq][j] = acc[j];
    __syncthreads();
    if (kq == 0){
      #pragma unroll
      for (int j = 0; j < 6; j++)
        out[b*38 + j] = red[r][0][j] + red[r][1][j] + red[r][2][j] + red[r][3][j] + ldf(bwo, j, fl);
    }
  }
}

// ---------------------------------------------------------------------------
// U [192,128] bf16 rows: 0..63=Wak, 64=bak, 65..129=Wek, 130=bek, rest 0.
// Fused bG[c] = bq . U[c,:] reduction. grid 192 x 128 thr.
__global__ __launch_bounds__(128) void build_u_bg_kernel(
    const void* __restrict__ Wak, const void* __restrict__ bak,
    const void* __restrict__ Wek, const void* __restrict__ bek,
    const void* __restrict__ bq, u16* __restrict__ U, float* __restrict__ bG,
    const int* __restrict__ flg)
{
  const int fl = *flg;
  __shared__ float pp[2];
  int c = blockIdx.x, a = threadIdx.x;
  float v = 0.f;
  if (c < 64)       v = ldf(Wak, (long)c*128 + a, fl);
  else if (c == 64) v = ldf(bak, a, fl);
  else if (c < 130) v = ldf(Wek, (long)(c-65)*128 + a, fl);
  else if (c == 130) v = ldf(bek, a, fl);
  u16 vb = f2bf(v);
  U[c*128 + a] = vb;
  float p = ldf(bq, a, fl) * bf2f(vb);   // match original bg numerics (rounded U)
  p = wred(p);
  if ((a & 63) == 0) pp[a >> 6] = p;
  __syncthreads();
  if (a == 0) bG[c] = pp[0] + pp[1];
}

// bc[j] = ba1[j] + sum_c be2[c] * Wa1[c, j]  (top half of Wa1)
// 32 blocks x 256 thr: block owns 16 j-cols, 16-way c-slice reduction.
__global__ __launch_bounds__(256) void bc_kernel(
    const void* __restrict__ Wa1, const void* __restrict__ be2,
    const void* __restrict__ ba1, float* __restrict__ bc,
    const int* __restrict__ flg)
{
  const int fl = *flg;
  __shared__ float red[16][17];
  const int t = threadIdx.x;
  const int jj = t & 15, cs = t >> 4;
  const int j = blockIdx.x*16 + jj;
  float acc = 0.f;
  for (int c = cs*32; c < cs*32 + 32; c++)
    acc = fmaf(ldf(be2, c, fl), ldf(Wa1, (long)c*512 + j, fl), acc);
  red[jj][cs] = acc;
  __syncthreads();
  if (t < 16){
    float s = ldf(ba1, blockIdx.x*16 + t, fl);
    #pragma unroll
    for (int k = 0; k < 16; k++) s += red[t][k];
    bc[blockIdx.x*16 + t] = s;
  }
}

// ---------------------------------------------------------------------------
// shared MFMA GEMM body: out[r, ocol+col] = A[M,K(lda)] @ B[N,K]^T + bias.
// LDS tiles padded to LDW=40 shorts/row (was 32): the 64B row stride made
// every ds_read_b128 fragment read an ~8-way bank conflict.
__device__ inline void gemm_body(const void* A, int lda, const void* Bm,
    const float* bias, u16* outp, int ldout, int ocol, int K, int fl,
    int amode, int bmode, short* Al, short* Bl)
{
  const int t = threadIdx.x, lane = t & 63, w = t >> 6;
  const int m0 = blockIdx.x*64, n0 = blockIdx.y*64;
  floatx4 acc[4] = {};
  const int row = t >> 2, seg = t & 3;
  for (int kt = 0; kt < K; kt += 32){
    __syncthreads();
    *(short8*)(Al + row*LDW + seg*8) = ld8m(A,  (long)(m0 + row)*lda + kt + seg*8, amode, fl);
    *(short8*)(Bl + row*LDW + seg*8) = ld8m(Bm, (long)(n0 + row)*K   + kt + seg*8, bmode, fl);
    __syncthreads();
    short8 a = *(const short8*)(Al + (w*16 + (lane & 15))*LDW + ((lane >> 4)*8));
    #pragma unroll
    for (int nt = 0; nt < 4; nt++){
      short8 b = *(const short8*)(Bl + (nt*16 + (lane & 15))*LDW + ((lane >> 4)*8));
      acc[nt] = MFMA(a, b, acc[nt]);
    }
  }
  #pragma unroll
  for (int nt = 0; nt < 4; nt++){
    int col = n0 + nt*16 + (lane & 15);
    float bb = bias ? bias[col] : 0.f;
    #pragma unroll
    for (int i = 0; i < 4; i++){
      int r = m0 + w*16 + (lane >> 4)*4 + i;
      outp[(long)r*ldout + ocol + col] = f2bf(acc[nt][i] + bb);
    }
  }
}

// Generic MFMA GEMM
__global__ __launch_bounds__(256) void gemm_nk_kernel(
    const void* __restrict__ A, int lda, const void* __restrict__ Bm,
    const float* __restrict__ bias, u16* __restrict__ outp, int ldout, int ocol,
    int K, const int* __restrict__ flg, int amode, int bmode)
{
  const int fl = *flg;
  __shared__ __align__(16) short Al[64*LDW];
  __shared__ __align__(16) short Bl[64*LDW];
  gemm_body(A, lda, Bm, bias, outp, ldout, ocol, K, fl, amode, bmode, Al, Bl);
}

// fused tot builder: z=0 own@WovT (K=128), z=1 mixa@WavT (K=64), z=2 mixe@WevT (K=96)
__global__ __launch_bounds__(256) void gemm_tot_kernel(
    const void* __restrict__ own, const u16* __restrict__ mixbuf,
    const u16* __restrict__ WovT, const u16* __restrict__ WavT, const u16* __restrict__ WevT,
    u16* __restrict__ tot, const int* __restrict__ flg)
{
  const int fl = *flg;
  __shared__ __align__(16) short Al[64*LDW];
  __shared__ __align__(16) short Bl[64*LDW];
  const void* A; const u16* Bm; int lda, K, ocol, amode;
  if (blockIdx.z == 0){ A = own;         lda = 128; Bm = WovT; K = 128; ocol = 0;   amode = 1; }
  else if (blockIdx.z == 1){ A = mixbuf; lda = 160; Bm = WavT; K = 64;  ocol = 256; amode = 0; }
  else { A = mixbuf + 64;                lda = 160; Bm = WevT; K = 96;  ocol = 512; amode = 0; }
  gemm_body(A, lda, Bm, nullptr, tot, 768, ocol, K, fl, amode, 0, Al, Bl);
}

// fused post-transpose GEMMs: z=0 u = h @ Wa1_bot + bc (64x8 blocks),
// z=1 Wc = We2 @ Wa1_top (8x8 blocks, extra x-blocks return). grid (64,8,2)
__global__ __launch_bounds__(256) void gemm_post_kernel(
    const float* __restrict__ h, const u16* __restrict__ Wa1bT, const float* __restrict__ bc,
    u16* __restrict__ u_b, const u16* __restrict__ Wa1tT, const void* __restrict__ We2,
    u16* __restrict__ WcT, const int* __restrict__ flg)
{
  const int fl = *flg;
  __shared__ __align__(16) short Al[64*LDW];
  __shared__ __align__(16) short Bl[64*LDW];
  if (blockIdx.z == 0){
    gemm_body(h, 512, Wa1bT, bc, u_b, 512, 0, 512, fl, 2, 0, Al, Bl);
  } else {
    if (blockIdx.x >= 8) return;
    gemm_body(Wa1tT, 512, We2, nullptr, WcT, 512, 0, 512, fl, 0, 1, Al, Bl);
  }
}

// ---------------------------------------------------------------------------
// Attention: TWO batch rows per wave (32-lane halves). Each half-wave owns one
// b-row; d packed 2/lane. Register-cached af/ef between passes.
__global__ __launch_bounds__(256) void attn_kernel(
    const u16* __restrict__ G, const void* __restrict__ af, const void* __restrict__ ef,
    u16* __restrict__ mixbuf, const int* __restrict__ flg)
{
  const int fl = *flg;
  __shared__ float gsh[8][192];
  __shared__ float attw[8][32];
  const int t = threadIdx.x;
  const int lane = t & 63, wv = t >> 6;
  const int l = lane & 31, hi = lane >> 5;
  const int wr = wv*2 + hi;
  const long b = (long)blockIdx.x*8 + wr;
  const float rsA = 0.08838834764831845f;  // 1/sqrt(128)

  for (int idx = t; idx < 8*192; idx += 256){
    int r = idx / 192, c = idx - r*192;
    gsh[r][c] = bf2f(G[((long)blockIdx.x*8 + r)*192 + c]);
  }
  __syncthreads();

  // ---- allies ----
  float2 qa2; qa2.x = gsh[wr][2*l]; qa2.y = gsh[wr][2*l + 1];
  float sa = gsh[wr][64];
  float2 fva[31];
  float myE = -1e30f;
  #pragma unroll
  for (int n = 0; n < 31; n++){
    fva[n] = ldf2(af, ((long)n*4096 + b)*64 + 2*l, fl);
    float e = hred32(fva[n].x*qa2.x + fva[n].y*qa2.y);
    e = (e + sa) * rsA;
    if (l == n) myE = e;
  }
  {
    float m = myE;
    for (int o = 16; o; o >>= 1) m = fmaxf(m, __shfl_xor(m, o));
    float p = (l < 31) ? __expf(myE - m) : 0.f;
    float s = hred32(p);
    attw[wr][l] = p / s;
  }
  __syncthreads();
  {
    float2 acc = {0.f, 0.f};
    #pragma unroll
    for (int n = 0; n < 31; n++){
      float w = attw[wr][n];
      acc.x = fmaf(w, fva[n].x, acc.x);
      acc.y = fmaf(w, fva[n].y, acc.y);
    }
    unsigned int pk = (unsigned int)f2bf(acc.x) | ((unsigned int)f2bf(acc.y) << 16);
    *(unsigned int*)(mixbuf + b*160 + 2*l) = pk;
  }
  __syncthreads();

  // ---- enemies (65 dims: d=2l,2l+1 per lane; lane 0 adds d=64) ----
  float2 qe2; qe2.x = gsh[wr][65 + 2*l]; qe2.y = gsh[wr][66 + 2*l];
  float qe64 = gsh[wr][129];
  float se = gsh[wr][130];
  float2 fve[32];
  myE = -1e30f;
  #pragma unroll
  for (int n = 0; n < 32; n++){
    long base = ((long)n*4096 + b)*65;
    fve[n].x = ldf(ef, base + 2*l, fl);
    fve[n].y = ldf(ef, base + 2*l + 1, fl);
    float prod = fve[n].x*qe2.x + fve[n].y*qe2.y;
    if (l == 0) prod = fmaf(ldf(ef, base + 64, fl), qe64, prod);
    float e = (hred32(prod) + se) * rsA;
    if (l == n) myE = e;
  }
  {
    float m = myE;
    for (int o = 16; o; o >>= 1) m = fmaxf(m, __shfl_xor(m, o));
    float p = __expf(myE - m);
    float s = hred32(p);
    attw[wr][l] = p / s;
  }
  __syncthreads();
  {
    float2 acc = {0.f, 0.f};
    float acc64 = 0.f;
    #pragma unroll
    for (int n = 0; n < 32; n++){
      long base = ((long)n*4096 + b)*65;
      float w = attw[wr][n];
      acc.x = fmaf(w, fve[n].x, acc.x);
      acc.y = fmaf(w, fve[n].y, acc.y);
      if (l == 0) acc64 = fmaf(w, ldf(ef, base + 64, fl), acc64);
    }
    unsigned int pk = (unsigned int)f2bf(acc.x) | ((unsigned int)f2bf(acc.y) << 16);
    *(unsigned int*)(mixbuf + b*160 + 64 + 2*l) = pk;
    if (l == 0) mixbuf[b*160 + 128] = f2bf(acc64);
    if (l >= 1) mixbuf[b*160 + 128 + l] = 0;
  }
}

// ---------------------------------------------------------------------------
// GRU: block = 128 batch rows x 64 hidden cols (512 thr); h (f32) -> d_out.
// 1-D grid of 256 with XCD swizzle: j0 = (bid&7)*64 -> per-XCD weight
// footprint ~1MB (L2-hot). LDS tiles padded to LDW=40 (bank-conflict fix).
__global__ __launch_bounds__(512) void gru_kernel(
    const u16* __restrict__ tot, const void* __restrict__ hprev,
    const void* __restrict__ w_ih, const void* __restrict__ w_hh,
    const void* __restrict__ b_ih, const void* __restrict__ b_hh,
    float* __restrict__ h_out, const int* __restrict__ flg)
{
  const int fl = *flg;
  __shared__ __align__(16) short At[128*LDW], Ah[128*LDW];
  __shared__ __align__(16) short Bi[3][64*LDW], Bh[3][64*LDW];
  const int t = threadIdx.x, lane = t & 63, w = t >> 6;
  const int bid = blockIdx.x;
  const int b0 = (bid >> 3)*128, j0 = (bid & 7)*64;
  floatx4 ai[3][4] = {}; floatx4 ah[3][4] = {};
  const int row = t >> 2, seg = t & 3;
  for (int kt = 0; kt < 768; kt += 32){
    __syncthreads();
    *(short8*)(At + row*LDW + seg*8) = *(const short8*)(tot + (long)(b0 + row)*768 + kt + seg*8);
    if (kt < 512)
      *(short8*)(Ah + row*LDW + seg*8) = ld8m(hprev, (long)(b0 + row)*512 + kt + seg*8, 1, fl);
    if (t < 256){
      int rb = t >> 2, sb = t & 3;
      #pragma unroll
      for (int p = 0; p < 3; p++)
        *(short8*)(Bi[p] + rb*LDW + sb*8) = ld8m(w_ih, (long)(p*512 + j0 + rb)*768 + kt + sb*8, 1, fl);
    } else if (kt < 512){
      int t2 = t - 256, rb = t2 >> 2, sb = t2 & 3;
      #pragma unroll
      for (int p = 0; p < 3; p++)
        *(short8*)(Bh[p] + rb*LDW + sb*8) = ld8m(w_hh, (long)(p*512 + j0 + rb)*512 + kt + sb*8, 1, fl);
    }
    __syncthreads();
    short8 a = *(const short8*)(At + (w*16 + (lane & 15))*LDW + ((lane >> 4)*8));
    #pragma unroll
    for (int p = 0; p < 3; p++){
      #pragma unroll
      for (int nt = 0; nt < 4; nt++){
        short8 b = *(const short8*)(Bi[p] + (nt*16 + (lane & 15))*LDW + ((lane >> 4)*8));
        ai[p][nt] = MFMA(a, b, ai[p][nt]);
      }
    }
    if (kt < 512){
      short8 a2 = *(const short8*)(Ah + (w*16 + (lane & 15))*LDW + ((lane >> 4)*8));
      #pragma unroll
      for (int p = 0; p < 3; p++){
        #pragma unroll
        for (int nt = 0; nt < 4; nt++){
          short8 b = *(const short8*)(Bh[p] + (nt*16 + (lane & 15))*LDW + ((lane >> 4)*8));
          ah[p][nt] = MFMA(a2, b, ah[p][nt]);
        }
      }
    }
  }
  #pragma unroll
  for (int nt = 0; nt < 4; nt++){
    int colH = j0 + nt*16 + (lane & 15);
    float bir = ldf(b_ih, colH, fl),        bhr = ldf(b_hh, colH, fl);
    float biz = ldf(b_ih, 512 + colH, fl),  bhz = ldf(b_hh, 512 + colH, fl);
    float bin = ldf(b_ih, 1024 + colH, fl), bhn = ldf(b_hh, 1024 + colH, fl);
    #pragma unroll
    for (int i = 0; i < 4; i++){
      int r = b0 + w*16 + (lane >> 4)*4 + i;
      float rg = sigmf(ai[0][nt][i] + bir + ah[0][nt][i] + bhr);
      float zg = sigmf(ai[1][nt][i] + biz + ah[1][nt][i] + bhz);
      float ng = tanhfast(ai[2][nt][i] + bin + rg*(ah[2][nt][i] + bhn));
      float hp = ldf(hprev, (long)r*512 + colH, fl);
      h_out[(long)r*512 + colH] = (1.f - zg)*ng + zg*hp;
    }
  }
}

// ---------------------------------------------------------------------------
// Head: EXACT R0 structure+phase2 (154.5us proven; 6 structural edits all
// null/regressed — frozen). Only change: f2bf now lowers to cvt_pk (identical
// RNE bits, fewer VALU ops in the 128 r1s-writes/lane and staging).
__global__ __launch_bounds__(512) void head_kernel(
    const void* __restrict__ ef_g, const u16* __restrict__ We1T,
    const void* __restrict__ be1, const u16* __restrict__ WcT,
    const u16* __restrict__ u_b, const void* __restrict__ wa2,
    const void* __restrict__ ba2, float* __restrict__ out, const int* __restrict__ flg)
{
  const int fl = *flg;
  __shared__ __align__(16) short r1s[2][64*512];  // XOR-swizzled: (row, chunk^(row&7))
  __shared__ __align__(16) short efl[64*96];
  __shared__ float part[2][64][9];
  const int t = threadIdx.x, lane = t & 63, w = t >> 6;
  const int m = lane & 15, q = lane >> 4;
  const int n0 = blockIdx.y*2, b0 = blockIdx.x*64;

  // phase 1: r1[e][64][512]; enemies staged sequentially through one efl buffer
  for (int e = 0; e < 2; e++){
    const int n = n0 + e;
    __syncthreads();   // protect efl from previous enemy's readers
    for (int idx = t; idx < 64*96; idx += 512){
      int r = idx / 96, d = idx - r*96;
      u16 v = 0;
      if (d < 65) v = f2bf(ldf(ef_g, ((long)n*4096 + b0 + r)*65 + d, fl));
      efl[idx] = (short)v;
    }
    __syncthreads();
    #pragma unroll
    for (int jt4 = 0; jt4 < 4; jt4++){
      const int coln = (w*4 + jt4)*16 + m;
      short8 bfr[3];
      #pragma unroll
      for (int k3 = 0; k3 < 3; k3++)
        bfr[k3] = *(const short8*)(We1T + coln*96 + k3*32 + q*8);
      float be = ldf(be1, coln, fl);
      const int chunk = coln >> 3, sub = coln & 7;
      #pragma unroll
      for (int rt = 0; rt < 4; rt++){
        floatx4 acc = {0.f, 0.f, 0.f, 0.f};
        #pragma unroll
        for (int k3 = 0; k3 < 3; k3++){
          short8 a = *(const short8*)(efl + (rt*16 + m)*96 + k3*32 + q*8);
          acc = MFMA(a, bfr[k3], acc);
        }
        #pragma unroll
        for (int i = 0; i < 4; i++){
          int row = rt*16 + q*4 + i;
          float v = acc[i] + be;
          r1s[e][row*512 + ((chunk ^ (row & 7)) << 3) + sub] = (short)f2bf(v > 0.f ? v : 0.f);
        }
      }
    }
  }
  __syncthreads();

  // phase 2: wave w -> output cols [w*64, w*64+64); each B-frag used 8x (2e x 4rt)
  floatx4 acc[2][4][4] = {};
  for (int kt = 0; kt < 512; kt += 32){
    short8 b[4];
    #pragma unroll
    for (int js = 0; js < 4; js++)
      b[js] = *(const short8*)(WcT + (long)(w*64 + js*16 + m)*512 + kt + q*8);
    const int ch = (((kt >> 3) + q) ^ (m & 7)) << 3;
    #pragma unroll
    for (int e = 0; e < 2; e++){
      #pragma unroll
      for (int rt = 0; rt < 4; rt++){
        short8 a = *(const short8*)(r1s[e] + (rt*16 + m)*512 + ch);
        #pragma unroll
        for (int js = 0; js < 4; js++)
          acc[e][rt][js] = MFMA(a, b[js], acc[e][rt][js]);
      }
    }
  }

  // epilogue: u_b loaded once, shared across both enemies
  float pr[2][4][4] = {};
  #pragma unroll
  for (int js = 0; js < 4; js++){
    int col = w*64 + js*16 + m;
    float wv = ldf(wa2, col, fl);
    #pragma unroll
    for (int rt = 0; rt < 4; rt++){
      #pragma unroll
      for (int i = 0; i < 4; i++){
        int grow = b0 + rt*16 + q*4 + i;
        float u = bf2f(u_b[(long)grow*512 + col]);
        #pragma unroll
        for (int e = 0; e < 2; e++){
          float s = acc[e][rt][js][i] + u;
          pr[e][rt][i] += (s > 0.f ? s : 0.f) * wv;
        }
      }
    }
  }
  #pragma unroll
  for (int o = 1; o < 16; o <<= 1){
    #pragma unroll
    for (int e = 0; e < 2; e++)
      #pragma unroll
      for (int rt = 0; rt < 4; rt++)
        #pragma unroll
        for (int i = 0; i < 4; i++)
          pr[e][rt][i] += __shfl_xor(pr[e][rt][i], o);
  }
  if (m == 0){
    #pragma unroll
    for (int e = 0; e < 2; e++)
      #pragma unroll
      for (int rt = 0; rt < 4; rt++)
        #pragma unroll
        for (int i = 0; i < 4; i++)
          part[e][rt*16 + q*4 + i][w] = pr[e][rt][i];
  }
  __syncthreads();
  if (t < 128){
    int e = t >> 6, r = t & 63;
    float s = ldf(ba2, 0, fl);
    #pragma unroll
    for (int ww = 0; ww < 8; ww++) s += part[e][r][ww];
    out[(long)(b0 + r)*38 + 6 + n0 + e] = s;
  }
}

// ---------------------------------------------------------------------------
extern "C" void kernel_launch(void* const* d_in, const int* in_sizes, int n_in,
                              void* d_out, int out_size, void* d_ws, size_t ws_size,
                              hipStream_t stream)
{
  (void)in_sizes; (void)n_in; (void)out_size; (void)ws_size;
  const void* own  = d_in[0];
  const void* af   = d_in[1];
  const void* ef   = d_in[2];
  const void* hid  = d_in[3];
  const void* Wq   = d_in[4];
  const void* bq   = d_in[5];
  const void* Wak  = d_in[6];
  const void* bak  = d_in[7];
  const void* Wav  = d_in[8];
  const void* Wek  = d_in[10];
  const void* bek  = d_in[11];
  const void* Wev  = d_in[12];
  const void* Wov  = d_in[14];
  const void* w_ih = d_in[16];
  const void* w_hh = d_in[17];
  const void* b_ih = d_in[18];
  const void* b_hh = d_in[19];
  const void* Wwo  = d_in[20];
  const void* bwo  = d_in[21];
  const void* We1  = d_in[22];
  const void* be1  = d_in[23];
  const void* We2  = d_in[24];
  const void* be2  = d_in[25];
  const void* Wa1  = d_in[26];
  const void* ba1  = d_in[27];
  const void* Wa2  = d_in[28];
  const void* ba2  = d_in[29];
  float* out   = (float*)d_out;                 // q [4096,38] f32
  float* h_out = out + (long)4096*38;           // h [4096,512] f32

  // ---- workspace (7.76 MB peak, time-phased aliasing) ----
  char* ws = (char*)d_ws;
  u16*   tot    = (u16*)(ws + 0);               // [4096,768] bf16 = 6,291,456
  u16*   G      = (u16*)(ws + 0);               // [4096,192] bf16 (alias, dead before tot)
  u16*   u_b    = (u16*)(ws + 0);               // [4096,512] bf16 = 4 MB (alias, after gru)
  u16*   Wa1tT  = (u16*)(ws + 4194304);         // [512,512] bf16 (tot region tail, post-gru)
  char*  mz     = ws + 6291456;                 // 1,310,720 multi-phase zone
  u16*   mixbuf = (u16*)mz;                     // [4096,160] bf16 (attention phase)
  u16*   U      = (u16*)mz;                     // [192,128] bf16 (prep phase)
  u16*   WGT    = (u16*)(mz + 49152);           // [192,128] bf16 (prep phase)
  u16*   Wa1bT  = (u16*)mz;                     // [512,512] bf16 (post-gru phase)
  u16*   WcT    = (u16*)(mz + 524288);          // [512,512] bf16 (post-u phase)
  u16*   We1T   = (u16*)(mz + 1048576);         // [512,96]  bf16 (post-gru phase)
  char*  P      = ws + 7602176;                 // persistent small zone
  u16*   WovT   = (u16*)(P + 0);                // [256,128] bf16
  u16*   WavT   = (u16*)(P + 65536);            // [256,64]  bf16
  u16*   WevT   = (u16*)(P + 98304);            // [256,96]  bf16
  float* bc     = (float*)(P + 147456);         // [512] f32
  float* bG     = (float*)(P + 149504);         // [192] f32
  int*   flg    = (int*)(P + 150528);

  detect_kernel<<<1, 256, 0, stream>>>((const u16*)w_ih, flg);

  // prep: fused V-projection transposes + fused U/bG + parallel bc
  transpose3a_kernel<<<dim3(8, 9), 256, 0, stream>>>(Wov, Wav, Wev, WovT, WavT, WevT, flg);
  build_u_bg_kernel<<<192, 128, 0, stream>>>(Wak, bak, Wek, bek, bq, U, bG, flg);
  bc_kernel<<<32, 256, 0, stream>>>(Wa1, be2, ba1, bc, flg);
  // WGT[c,d] = sum_a U[c,a] * Wq[d,a]
  gemm_nk_kernel<<<dim3(3, 2), 256, 0, stream>>>(U, 128, Wq, nullptr, WGT, 128, 0, 128, flg, 0, 1);
  // G = own @ WGT^T + bG   [4096,192]
  gemm_nk_kernel<<<dim3(64, 3), 256, 0, stream>>>(own, 128, WGT, bG, G, 192, 0, 128, flg, 1, 0);
  // attention -> mixbuf (clobbers U/WGT; G still live in tot region)
  attn_kernel<<<512, 256, 0, stream>>>(G, af, ef, mixbuf, flg);
  // tot = [own@Wov | mix_a@Wav | mix_e@Wev]  (one launch; overwrites G)
  gemm_tot_kernel<<<dim3(64, 4, 3), 256, 0, stream>>>(own, mixbuf, WovT, WavT, WevT, tot, flg);
  // GRU -> h (f32 in d_out); 1-D grid, XCD-swizzled (j = bid&7)
  gru_kernel<<<256, 512, 0, stream>>>(tot, hid, w_ih, w_hh, b_ih, b_hh, h_out, flg);
  // fused late transposes + wo head (tot + mixbuf dead): Wa1bT@mz, Wa1tT@ws+4MB, We1T
  transpose3b_kernel<<<dim3(16, 39), 256, 0, stream>>>(Wa1, We1, Wa1bT, Wa1tT, We1T,
                                                       h_out, Wwo, bwo, out, flg);
  // u = h @ Wa1_bot + bc -> u_b  ||  Wc = We2 @ Wa1_top  (one z-fused launch)
  gemm_post_kernel<<<dim3(64, 8, 2), 256, 0, stream>>>(h_out, Wa1bT, bc, u_b,
                                                       Wa1tT, We2, WcT, flg);
  // heads
  head_kernel<<<dim3(64, 16), 512, 0, stream>>>(ef, We1T, be1, WcT, u_b, Wa2, ba2, out, flg);
}